// Round 13
// baseline (900.447 us; speedup 1.0000x reference)
//
#include <hip/hip_runtime.h>
#include <cstddef>
#include <utility>

// ---------------- problem constants ----------------
constexpr int N0  = 4096;
constexpr int E   = 65536;
constexpr int DIN = 128;
constexpr int HD  = 256;   // H
constexpr int NC  = 10;
constexpr int UHD = 64;    // UH
constexpr int K1  = 3277;  // ceil(0.8*4096)
constexpr int K2  = 656;   // ceil(0.2*3277)
constexpr int PMN = K2 * K2; // 430336

// expm(A): A = 2^s*B, RUNTIME s = clamp(ceil(log2(||A||_1/1.4)),1,5) (R12)
// and RUNTIME Taylor degree (R13): deg 11 if ||B||>0.43, deg 8 if >0.11,
// else deg 5 — degree lowering = starting the PS Horner chain one/two
// levels down (combo3 emits D2/D1 coeffs; Horner slots gate off).
constexpr int SQ_SLOTS = 4;  // max explicit squarings

// MFMA plane geometry: 656 -> padded 704 = 11*64 = 22*32.
constexpr int PLD = 704;
constexpr size_t PPS = (size_t)PLD * PLD;

// Split-K: CSPLIT=8, z = blockIdx.x -> one k-slice per XCD (R8/R9).
constexpr int CSPLIT = 8;

// ---------------- workspace layout ----------------
#define F4(n) ((size_t)(n) * 4)
constexpr size_t O_H1    = 0;
constexpr size_t O_OUT1  = O_H1    + F4(N0 * HD);
constexpr size_t O_DEG1  = O_OUT1  + F4(N0 * HD);
constexpr size_t O_DIS1  = O_DEG1  + F4(N0);
constexpr size_t O_SC1   = O_DIS1  + F4(N0);
constexpr size_t O_PERM1 = O_SC1   + F4(N0);
constexpr size_t O_MAP1  = O_PERM1 + F4(N0);
constexpr size_t O_H1P   = O_MAP1  + F4(N0);
constexpr size_t O_SRC2  = O_H1P   + F4(K1 * HD);
constexpr size_t O_DST2  = O_SRC2  + F4(E);
constexpr size_t O_EM2   = O_DST2  + F4(E);
constexpr size_t O_H2    = O_EM2   + F4(E);
constexpr size_t O_OUT2  = O_H2    + F4(K1 * HD);
constexpr size_t O_DEG2  = O_OUT2  + F4(K1 * HD);
constexpr size_t O_DIS2  = O_DEG2  + F4(N0);
constexpr size_t O_SC2   = O_DIS2  + F4(N0);
constexpr size_t O_PERM2 = O_SC2   + F4(N0);
constexpr size_t O_MAP2  = O_PERM2 + F4(N0);
constexpr size_t O_H2P   = O_MAP2  + F4(N0);
constexpr size_t O_SRC3  = O_H2P   + F4(K2 * HD);
constexpr size_t O_DST3  = O_SRC3  + F4(E);
constexpr size_t O_EM3   = O_DST3  + F4(E);
constexpr size_t O_XR    = O_EM3   + F4(E);
constexpr size_t O_XI    = O_XR    + F4(K2 * HD);
constexpr size_t O_DEG3  = O_XI    + F4(K2 * HD);
constexpr size_t O_DIS3  = O_DEG3  + F4(1024);
constexpr size_t O_SCOEF = O_DIS3  + F4(1024);
constexpr size_t O_XG1   = O_SCOEF + F4(1024);
constexpr size_t O_XG2H  = O_XG1   + F4(K2 * UHD);
constexpr size_t O_XG2   = O_XG2H  + F4(K2 * UHD);
constexpr size_t O_EMB   = O_XG2   + F4(K2 * UHD);
constexpr size_t O_T1    = O_EMB   + F4(64);
constexpr size_t O_T2    = O_T1    + F4(64);
constexpr size_t O_NORM  = O_T2    + F4(64);   // [0..1] pool norms, [2] ANRM bits,
                                               // [3] S_DEV, [4] SCALE, [5] DEGF
constexpr size_t O_PM    = O_NORM  + F4(64);
constexpr size_t O_BM    = O_PM    + F4(PMN);          // float2
constexpr size_t O_P0    = O_BM    + F4(PMN) * 2;      // float2 (unused)
constexpr size_t O_P1    = O_P0    + F4(PMN) * 2;      // float2 (unused)
constexpr size_t O_XRT   = O_P1    + F4(PMN) * 2;
constexpr size_t O_XIT   = O_XRT   + F4(K2 * HD);
constexpr size_t O_XC    = O_XIT   + F4(K2 * HD);      // float2
constexpr size_t O_EVO   = O_XC    + F4(K2 * HD) * 2;  // float2
constexpr size_t O_AGG0  = O_EVO   + F4(K2 * HD) * 2;  // float2
constexpr size_t O_WC    = O_AGG0  + F4(K2 * HD) * 2;  // float2 256x256
constexpr size_t O_AGG1  = O_WC    + F4(HD * HD) * 2;  // float2 (unused now)
constexpr size_t O_MAG   = O_AGG1  + F4(K2 * HD) * 2;
constexpr size_t O_PH    = O_MAG   + F4(K2 * HD);
constexpr size_t O_GM    = O_PH    + F4(K2 * HD);
constexpr size_t O_GP    = O_GM    + F4(256);
constexpr size_t O_HM    = O_GP    + F4(256);
constexpr size_t O_HP    = O_HM    + F4(256);
constexpr size_t O_LM    = O_HP    + F4(256);
constexpr size_t O_LP    = O_LM    + F4(64);
constexpr size_t WS_NEED = O_LP    + F4(64);

// SA/ST bf16 plane sets in the dead stage-A/B region (below O_SRC3).
constexpr size_t O_SA = 0;
constexpr size_t O_ST = O_SA + PPS * 2 * 4;
static_assert(O_ST + PPS * 2 * 4 <= O_SRC3, "SA/ST must fit in dead region");

// B2 fp32 (only fp32 PS power re-read as epilogue input) aliases XRT region.
constexpr size_t O_B2 = O_XRT;
static_assert(O_B2 + F4(PMN) * 2 <= O_MAG, "B2 must fit in XRT..AGG1 region");

// CSR slot in the MAG/PH region.
constexpr size_t O_CSR_OFF = O_MAG;                 // (N0+1) ints
constexpr size_t O_CSR_CUR = O_CSR_OFF + F4(4104);
constexpr size_t O_CSR_SRC = O_CSR_CUR + F4(4104);  // E ints
constexpr size_t O_CSR_CF  = O_CSR_SRC + F4(E);     // E floats
static_assert(O_CSR_CF + F4(E) <= O_GM, "CSR must fit in MAG/PH region");

// Extension region past WS_NEED (harness ws_size ~268 MB; runtime-guarded).
constexpr size_t O_PARTX  = (WS_NEED + 255) & ~(size_t)255;
constexpr size_t PART_SZ  = (size_t)CSPLIT * PMN * 8;   // 27.5 MB
constexpr size_t WS_TOTAL = O_PARTX + PART_SZ;

// ---------------- bf16 helpers ----------------
typedef __attribute__((ext_vector_type(8))) short s8v;   // 8 bf16 (4 VGPRs)
typedef __attribute__((ext_vector_type(4))) float f4v;   // MFMA acc

__device__ inline unsigned short f2bf(float x) {
  unsigned u = __float_as_uint(x);
  u += 0x7FFFu + ((u >> 16) & 1u);
  return (unsigned short)(u >> 16);
}
__device__ inline float bf2f(unsigned short h) {
  return __uint_as_float(((unsigned)h) << 16);
}
__device__ inline void split4(float re, float im, unsigned short* out,
                              size_t ps, size_t o) {
  unsigned short rh = f2bf(re);
  unsigned short rl = f2bf(re - bf2f(rh));
  unsigned short ih = f2bf(im);
  unsigned short il = f2bf(im - bf2f(ih));
  out[o] = rh; out[ps + o] = rl; out[2 * ps + o] = ih; out[3 * ps + o] = il;
}

// ---------------- kernels ----------------

// real GEMM fp32 (pool-score path stays fp32 for exact top-k ordering).
template <int ACT>
__global__ void rmm64(const float* __restrict__ A, const float* __restrict__ B,
                      const float* __restrict__ bias, float* __restrict__ C,
                      int M, int N, int K, int CS, int CO) {
  __shared__ float As[64][17];
  __shared__ float Bs[16][64];
  int t  = threadIdx.x;
  int tx = t & 15, ty = t >> 4;
  int bm = blockIdx.y * 64, bn = blockIdx.x * 64;
  float acc[4][4] = {};
  for (int kt = 0; kt < K; kt += 16) {
#pragma unroll
    for (int i = 0; i < 4; i++) {
      int l = t + i * 256;
      int kk = l & 15, mm = l >> 4;
      int gr = bm + mm;
      As[mm][kk] = (gr < M) ? A[(size_t)gr * K + kt + kk] : 0.f;
    }
#pragma unroll
    for (int i = 0; i < 4; i++) {
      int l = t + i * 256;
      int cc = l & 63, kk = l >> 6;
      int gc = bn + cc;
      Bs[kk][cc] = (gc < N) ? B[(size_t)(kt + kk) * N + gc] : 0.f;
    }
    __syncthreads();
#pragma unroll
    for (int kk = 0; kk < 16; kk++) {
      float a[4], b[4];
#pragma unroll
      for (int i = 0; i < 4; i++) a[i] = As[ty + 16 * i][kk];
#pragma unroll
      for (int j = 0; j < 4; j++) b[j] = Bs[kk][tx + 16 * j];
#pragma unroll
      for (int i = 0; i < 4; i++)
#pragma unroll
        for (int j = 0; j < 4; j++) acc[i][j] += a[i] * b[j];
    }
    __syncthreads();
  }
#pragma unroll
  for (int i = 0; i < 4; i++) {
    int r = bm + ty + 16 * i;
    if (r >= M) continue;
#pragma unroll
    for (int j = 0; j < 4; j++) {
      int c = bn + tx + 16 * j;
      if (c >= N) continue;
      float v = acc[i][j] + (bias ? bias[c] : 0.f);
      if (ACT == 1) v = fmaxf(v, 0.f);
      C[((size_t)r * N + c) * CS + CO] = v;
    }
  }
}

// Dual rmm64: blockIdx.z selects operand set.
template <int ACT>
__global__ void rmm64_dual(const float* __restrict__ A0, const float* __restrict__ A1,
                           const float* __restrict__ B0, const float* __restrict__ B1,
                           const float* __restrict__ b0, const float* __restrict__ b1,
                           float* __restrict__ C0, float* __restrict__ C1,
                           int M, int N, int K, int CS) {
  const float* A = blockIdx.z ? A1 : A0;
  const float* B = blockIdx.z ? B1 : B0;
  const float* bias = blockIdx.z ? b1 : b0;
  float* C = blockIdx.z ? C1 : C0;
  __shared__ float As[64][17];
  __shared__ float Bs[16][64];
  int t  = threadIdx.x;
  int tx = t & 15, ty = t >> 4;
  int bm = blockIdx.y * 64, bn = blockIdx.x * 64;
  float acc[4][4] = {};
  for (int kt = 0; kt < K; kt += 16) {
#pragma unroll
    for (int i = 0; i < 4; i++) {
      int l = t + i * 256;
      int kk = l & 15, mm = l >> 4;
      int gr = bm + mm;
      As[mm][kk] = (gr < M) ? A[(size_t)gr * K + kt + kk] : 0.f;
    }
#pragma unroll
    for (int i = 0; i < 4; i++) {
      int l = t + i * 256;
      int cc = l & 63, kk = l >> 6;
      int gc = bn + cc;
      Bs[kk][cc] = (gc < N) ? B[(size_t)(kt + kk) * N + gc] : 0.f;
    }
    __syncthreads();
#pragma unroll
    for (int kk = 0; kk < 16; kk++) {
      float a[4], b[4];
#pragma unroll
      for (int i = 0; i < 4; i++) a[i] = As[ty + 16 * i][kk];
#pragma unroll
      for (int j = 0; j < 4; j++) b[j] = Bs[kk][tx + 16 * j];
#pragma unroll
      for (int i = 0; i < 4; i++)
#pragma unroll
        for (int j = 0; j < 4; j++) acc[i][j] += a[i] * b[j];
    }
    __syncthreads();
  }
#pragma unroll
  for (int i = 0; i < 4; i++) {
    int r = bm + ty + 16 * i;
    if (r >= M) continue;
#pragma unroll
    for (int j = 0; j < 4; j++) {
      int c = bn + tx + 16 * j;
      if (c >= N) continue;
      float v = acc[i][j] + (bias ? bias[c] : 0.f);
      if (ACT == 1) v = fmaxf(v, 0.f);
      C[((size_t)r * N + c) * CS] = v;
    }
  }
}

// Transposed split: out[n*ld + k] = split(in[k][n]); tiled via LDS.
__global__ void split_planesT(const float2* __restrict__ in, int inM, int inN,
                              unsigned short* __restrict__ out, int padR, int ld,
                              size_t ps) {
  __shared__ float2 tile[32][33];
  int tx = threadIdx.x & 31, ty = threadIdx.x >> 5;   // 32 x 8
  int k0 = blockIdx.x * 32, n0 = blockIdx.y * 32;
  for (int i = ty; i < 32; i += 8) {
    int k = k0 + i, n = n0 + tx;
    tile[i][tx] = (k < inM && n < inN) ? in[(size_t)k * inN + n]
                                       : make_float2(0.f, 0.f);
  }
  __syncthreads();
  for (int i = ty; i < 32; i += 8) {
    int n = n0 + i, k = k0 + tx;
    if (n < padR && k < ld)
      split4(tile[tx][i].x, tile[tx][i].y, out, ps, (size_t)n * ld + k);
  }
}

// Transposed split from two real fp32 matrices (re, im): W = re + i*im.
__global__ void split_planesT2(const float* __restrict__ re, const float* __restrict__ im,
                               int inM, int inN, unsigned short* __restrict__ out,
                               int padR, int ld, size_t ps) {
  __shared__ float2 tile[32][33];
  int tx = threadIdx.x & 31, ty = threadIdx.x >> 5;
  int k0 = blockIdx.x * 32, n0 = blockIdx.y * 32;
  for (int i = ty; i < 32; i += 8) {
    int k = k0 + i, n = n0 + tx;
    tile[i][tx] = (k < inM && n < inN)
        ? make_float2(re[(size_t)k * inN + n], im[(size_t)k * inN + n])
        : make_float2(0.f, 0.f);
  }
  __syncthreads();
  for (int i = ty; i < 32; i += 8) {
    int n = n0 + i, k = k0 + tx;
    if (n < padR && k < ld)
      split4(tile[tx][i].x, tile[tx][i].y, out, ps, (size_t)n * ld + k);
  }
}

// Split-K complex MFMA GEMM with register double-buffer prefetch.
// gate/slot: squaring gate (inactive if slot >= *gate-1).
// dgate/dslot: degree gate (inactive if *dgate > dslot).  [R13]
__global__ __launch_bounds__(256, 2) void cmm_bf16_sk(
    const unsigned short* __restrict__ SA, size_t psA, int ldA,
    const unsigned short* __restrict__ ST, size_t psT, int ldT,
    float2* __restrict__ Part, int M, int N, int Kp, int chunk,
    const int* __restrict__ gate, int slot,
    const int* __restrict__ dgate, int dslot) {
  if (gate && slot >= *gate - 1) return;
  if (dgate && *dgate > dslot) return;
  int k0 = blockIdx.x * chunk;
  int kend = min(Kp, k0 + chunk);
  int t = threadIdx.x;
  int wave = t >> 6, lane = t & 63;
  int quad = lane >> 4, mn = lane & 15;
  int rowA = blockIdx.z * 64 + wave * 16 + mn;
  int bn = blockIdx.y * 64;
  const unsigned short* a0 = SA + (size_t)rowA * ldA;
  f4v accR[4], accI[4];
#pragma unroll
  for (int i = 0; i < 4; i++) {
    accR[i] = (f4v){0.f, 0.f, 0.f, 0.f};
    accI[i] = (f4v){0.f, 0.f, 0.f, 0.f};
  }
  s8v cA[4], cB[4][4], nA[4], nB[4][4];
  {
    int ka = k0 + quad * 8;
#pragma unroll
    for (int p = 0; p < 4; p++) cA[p] = *(const s8v*)(a0 + p * psA + ka);
#pragma unroll
    for (int tl = 0; tl < 4; tl++) {
      const unsigned short* b0 = ST + (size_t)(bn + tl * 16 + mn) * ldT + ka;
#pragma unroll
      for (int p = 0; p < 4; p++) cB[tl][p] = *(const s8v*)(b0 + p * psT);
    }
  }
  for (int kt = k0; kt < kend; kt += 32) {
    int kn = kt + 32;
    if (kn < kend) {
      int ka = kn + quad * 8;
#pragma unroll
      for (int p = 0; p < 4; p++) nA[p] = *(const s8v*)(a0 + p * psA + ka);
#pragma unroll
      for (int tl = 0; tl < 4; tl++) {
        const unsigned short* b0 = ST + (size_t)(bn + tl * 16 + mn) * ldT + ka;
#pragma unroll
        for (int p = 0; p < 4; p++) nB[tl][p] = *(const s8v*)(b0 + p * psT);
      }
    }
    s8v nih, nil_;
#pragma unroll
    for (int q = 0; q < 8; q++) {
      nih[q]  = (short)(cA[2][q] ^ (short)0x8000);   // -ai
      nil_[q] = (short)(cA[3][q] ^ (short)0x8000);
    }
#pragma unroll
    for (int tl = 0; tl < 4; tl++) {
      f4v r = accR[tl];
      r = __builtin_amdgcn_mfma_f32_16x16x32_bf16(cA[0], cB[tl][0], r, 0, 0, 0);
      r = __builtin_amdgcn_mfma_f32_16x16x32_bf16(cA[1], cB[tl][0], r, 0, 0, 0);
      r = __builtin_amdgcn_mfma_f32_16x16x32_bf16(cA[0], cB[tl][1], r, 0, 0, 0);
      r = __builtin_amdgcn_mfma_f32_16x16x32_bf16(nih, cB[tl][2], r, 0, 0, 0);
      r = __builtin_amdgcn_mfma_f32_16x16x32_bf16(nil_, cB[tl][2], r, 0, 0, 0);
      r = __builtin_amdgcn_mfma_f32_16x16x32_bf16(nih, cB[tl][3], r, 0, 0, 0);
      accR[tl] = r;
      f4v im = accI[tl];
      im = __builtin_amdgcn_mfma_f32_16x16x32_bf16(cA[0], cB[tl][2], im, 0, 0, 0);
      im = __builtin_amdgcn_mfma_f32_16x16x32_bf16(cA[1], cB[tl][2], im, 0, 0, 0);
      im = __builtin_amdgcn_mfma_f32_16x16x32_bf16(cA[0], cB[tl][3], im, 0, 0, 0);
      im = __builtin_amdgcn_mfma_f32_16x16x32_bf16(cA[2], cB[tl][0], im, 0, 0, 0);
      im = __builtin_amdgcn_mfma_f32_16x16x32_bf16(cA[3], cB[tl][0], im, 0, 0, 0);
      im = __builtin_amdgcn_mfma_f32_16x16x32_bf16(cA[2], cB[tl][1], im, 0, 0, 0);
      accI[tl] = im;
    }
    if (kn < kend) {
#pragma unroll
      for (int p = 0; p < 4; p++) cA[p] = nA[p];
#pragma unroll
      for (int tl = 0; tl < 4; tl++)
#pragma unroll
        for (int p = 0; p < 4; p++) cB[tl][p] = nB[tl][p];
    }
  }
  float2* P = Part + (size_t)blockIdx.x * M * N;
#pragma unroll
  for (int tl = 0; tl < 4; tl++) {
    int col = bn + tl * 16 + mn;
    if (col >= N) continue;
#pragma unroll
    for (int r = 0; r < 4; r++) {
      int row = blockIdx.z * 64 + wave * 16 + quad * 4 + r;
      if (row >= M) continue;
      P[(size_t)row * N + col] = make_float2(accR[tl][r], accI[tl][r]);
    }
  }
}

// Plain reduce: C = sum_z Part[z] + e0*I + e1*E1 + e2*E2.
__global__ void creduce(const float2* __restrict__ Part, float2* __restrict__ C,
                        int MN, int N, int S, float e0,
                        const float2* __restrict__ E1, float e1,
                        const float2* __restrict__ E2, float e2) {
  int idx = blockIdx.x * 256 + threadIdx.x;
  if (idx >= MN) return;
  float sr = 0.f, si = 0.f;
  for (int z = 0; z < S; z++) {
    float2 p = Part[(size_t)z * MN + idx];
    sr += p.x;
    si += p.y;
  }
  if (e0 != 0.f) {
    int r = idx / N;
    if (idx - r * N == r) sr += e0;
  }
  if (E1) { float2 b = E1[idx]; sr += e1 * b.x; si += e1 * b.y; }
  if (E2) { float2 b = E2[idx]; sr += e2 * b.x; si += e2 * b.y; }
  C[idx] = make_float2(sr, si);
}

// Tiled fused reduce with both gates (squaring + degree).
template <int WC_, int WSA, int WST>
__global__ void creduce_tiled(const float2* __restrict__ Part, int S, int M, int N,
                              int RP, int CP, float2* __restrict__ C,
                              unsigned short* __restrict__ SAp, size_t psA,
                              unsigned short* __restrict__ STp, size_t psT,
                              float e0, const float2* __restrict__ E1, float e1,
                              const float2* __restrict__ E2, float e2,
                              const int* __restrict__ gate, int slot,
                              const int* __restrict__ dgate, int dslot) {
  if (gate && slot >= *gate - 1) return;
  if (dgate && *dgate > dslot) return;
  __shared__ float vr[32][33], vi[32][33];
  int tx = threadIdx.x & 31, ty = threadIdx.x >> 5;
  int r0 = blockIdx.y * 32, c0 = blockIdx.x * 32;
  size_t MN = (size_t)M * N;
  for (int i = ty; i < 32; i += 8) {
    int r = r0 + i, c = c0 + tx;
    float sr = 0.f, si = 0.f;
    if (r < M && c < N) {
      size_t o = (size_t)r * N + c;
      for (int z = 0; z < S; z++) {
        float2 p = Part[z * MN + o];
        sr += p.x;
        si += p.y;
      }
      if (e0 != 0.f && r == c) sr += e0;
      if (E1) { float2 b = E1[o]; sr += e1 * b.x; si += e1 * b.y; }
      if (E2) { float2 b = E2[o]; sr += e2 * b.x; si += e2 * b.y; }
      if (WC_) C[o] = make_float2(sr, si);
    }
    if (WSA) split4(sr, si, SAp, psA, (size_t)r * CP + c);
    if (WST) { vr[i][tx] = sr; vi[i][tx] = si; }
  }
  if (WST) {
    __syncthreads();
    for (int i = ty; i < 32; i += 8) {
      int c = c0 + i, r = r0 + tx;
      split4(vr[tx][i], vi[tx][i], STp, psT, (size_t)c * RP + r);
    }
  }
}

// Fused build_B + split + splitT: BM fp32 + SA(B) + ST(B^T); runtime scale.
__global__ void build_B_split(const float* __restrict__ pm, int n,
                              const float* __restrict__ scale_p,
                              float2* __restrict__ BM,
                              unsigned short* __restrict__ SAp,
                              unsigned short* __restrict__ STp, size_t ps,
                              int RP, int CP) {
  __shared__ float vr[32][33], vi[32][33];
  float scale = scale_p[0];
  int tx = threadIdx.x & 31, ty = threadIdx.x >> 5;
  int r0 = blockIdx.y * 32, c0 = blockIdx.x * 32;
  for (int i = ty; i < 32; i += 8) {
    int r = r0 + i, c = c0 + tx;
    float sr = 0.f, si = 0.f;
    if (r < n && c < n) {
      float pij = pm[(size_t)r * n + c];
      float pji = pm[(size_t)c * n + r];
      sr = scale * (pij - pji);
      si = scale * (pij + pji);
      BM[(size_t)r * n + c] = make_float2(sr, si);
    }
    split4(sr, si, SAp, ps, (size_t)r * CP + c);
    vr[i][tx] = sr;
    vi[i][tx] = si;
  }
  __syncthreads();
  for (int i = ty; i < 32; i += 8) {
    int c = c0 + i, r = r0 + tx;
    split4(vr[tx][i], vi[tx][i], STp, ps, (size_t)c * RP + r);
  }
}

// ||A||_1 -> atomicMax as int bits (values >= 0 so int compare works).
__global__ void anorm_rows(const float* __restrict__ pm, int n,
                           int* __restrict__ anrm) {
  int i = blockIdx.x;
  __shared__ float red[256];
  float s = 0.f;
  for (int j = threadIdx.x; j < n; j += 256) {
    float pij = pm[(size_t)i * n + j];
    float pji = pm[(size_t)j * n + i];
    float a = pij - pji, b = pij + pji;
    s += sqrtf(a * a + b * b);
  }
  red[threadIdx.x] = s;
  __syncthreads();
  for (int off = 128; off > 0; off >>= 1) {
    if (threadIdx.x < off) red[threadIdx.x] += red[threadIdx.x + off];
    __syncthreads();
  }
  if (threadIdx.x == 0) atomicMax(anrm, __float_as_int(red[0] * 0.025f));
}

// s = clamp(ceil(log2(||A||_1/1.4)),1,5); scale = 0.025*2^-s;
// degf: 0 = deg-11, 1 = deg-8 (||B||<=0.43), 2 = deg-5 (||B||<=0.11).
__global__ void finalize_s(const int* __restrict__ anrm, int* __restrict__ sdev,
                           float* __restrict__ scale, int* __restrict__ degf) {
  float a = __int_as_float(*anrm);
  int s = (int)ceilf(log2f(fmaxf(a, 1e-20f) / 1.4f));
  s = min(max(s, 1), SQ_SLOTS + 1);
  *sdev = s;
  *scale = 0.025f * exp2f(-(float)s);
  float bn = a * exp2f(-(float)s);
  *degf = (bn > 0.43f) ? 0 : (bn > 0.11f ? 1 : 2);
}

// P_start = D_k for runtime degree: degf=0 -> D3{c9,c10,c11};
// 1 -> D2{c6,c7,c8}; 2 -> D1{c3,c4,c5}. SA planes only.
__global__ void combo3_planes(const float2* __restrict__ Bp, const float2* __restrict__ B2p,
                              unsigned short* __restrict__ planes, size_t ps,
                              int M, int N, int padR, int ld,
                              const int* __restrict__ degf) {
  const float E0[3] = {1.f / 362880.f, 1.f / 720.f, 1.f / 6.f};
  const float E1c[3] = {1.f / 3628800.f, 1.f / 5040.f, 1.f / 24.f};
  const float E2c[3] = {1.f / 39916800.f, 1.f / 40320.f, 1.f / 120.f};
  int f = *degf;
  float e0 = E0[f], e1 = E1c[f], e2 = E2c[f];
  int idx = blockIdx.x * 256 + threadIdx.x;
  if (idx >= padR * ld) return;
  int r = idx / ld, c = idx - r * ld;
  float sr = 0.f, si = 0.f;
  if (r < M && c < N) {
    size_t o = (size_t)r * N + c;
    float2 b = Bp[o], b2 = B2p[o];
    sr = e1 * b.x + e2 * b2.x;
    si = e1 * b.y + e2 * b2.y;
    if (r == c) sr += e0;
  }
  split4(sr, si, planes, ps, idx);
}

// ---- CSR build ----
__global__ void hist_edges(const int* __restrict__ dst, const float* __restrict__ em,
                           int* __restrict__ cnt) {
  int e = blockIdx.x * 256 + threadIdx.x;
  if (e >= E) return;
  float m = em ? em[e] : 1.0f;
  if (m != 0.f) atomicAdd(&cnt[dst[e]], 1);
}

__global__ __launch_bounds__(1024) void scan_offsets(const int* __restrict__ cnt, int n,
                                                     int* __restrict__ off,
                                                     int* __restrict__ cur,
                                                     float* __restrict__ dis) {
  __shared__ int sums[1024];
  int t = threadIdx.x;
  int base = t * 4;
  int v[4];
  int s = 0;
#pragma unroll
  for (int j = 0; j < 4; j++) {
    int i = base + j;
    int ci = (i < n) ? cnt[i] : 0;
    if (i < n) dis[i] = 1.0f / sqrtf((float)ci + 1.0f);
    v[j] = s;
    s += ci;
  }
  sums[t] = s;
  __syncthreads();
  for (int d = 1; d < 1024; d <<= 1) {
    int x = (t >= d) ? sums[t - d] : 0;
    __syncthreads();
    sums[t] += x;
    __syncthreads();
  }
  int pre = (t > 0) ? sums[t - 1] : 0;
#pragma unroll
  for (int j = 0; j < 4; j++) {
    int i = base + j;
    if (i < n) { int o = pre + v[j]; off[i] = o; cur[i] = o; }
  }
  if (t == 1023) off[n] = sums[1023];
}

__global__ void fill_edges(const int* __restrict__ src, const int* __restrict__ dst,
                           const float* __restrict__ em, const float* __restrict__ dis,
                           int* __restrict__ cur, int* __restrict__ esrc,
                           float* __restrict__ ecoef) {
  int e = blockIdx.x * 256 + threadIdx.x;
  if (e >= E) return;
  float m = em ? em[e] : 1.0f;
  if (m == 0.f) return;
  int s = src[e], d = dst[e];
  int pos = atomicAdd(&cur[d], 1);
  esrc[pos] = s;
  ecoef[pos] = dis[s] * dis[d];
}

template <int ACT>
__global__ void gcn_gather(const int* __restrict__ off, const int* __restrict__ esrc,
                           const float* __restrict__ ecoef, const float* __restrict__ Hm,
                           const float* __restrict__ dis, const float* __restrict__ bias,
                           float* __restrict__ out, int F) {
  int i = blockIdx.x;
  int e0 = off[i], e1 = off[i + 1];
  float d2 = dis[i] * dis[i];
  for (int f = threadIdx.x; f < F; f += blockDim.x) {
    float acc = d2 * Hm[(size_t)i * F + f] + bias[f];
    for (int e = e0; e < e1; e++)
      acc += ecoef[e] * Hm[(size_t)esrc[e] * F + f];
    if (ACT == 1) acc = fmaxf(acc, 0.f);
    out[(size_t)i * F + f] = acc;
  }
}

__global__ void enc1_fused(const int* __restrict__ off, const float* __restrict__ ecoef,
                           const float* __restrict__ dis, const float* __restrict__ w,
                           const float* __restrict__ b, float* __restrict__ xg1) {
  int i = blockIdx.x;
  int lane = threadIdx.x;   // 64 = one wave
  float s = 0.f;
  for (int e = off[i] + lane; e < off[i + 1]; e += 64) s += ecoef[e];
#pragma unroll
  for (int d = 32; d > 0; d >>= 1) s += __shfl_xor(s, d, 64);
  float sc = s + dis[i] * dis[i];
  xg1[(size_t)i * UHD + lane] = fmaxf(sc * w[lane] + b[lane], 0.f);
}

__global__ void agg_gather_split(const int* __restrict__ off, const int* __restrict__ esrc,
                                 const float2* __restrict__ evo,
                                 unsigned short* __restrict__ planes, size_t ps,
                                 int F, int M) {
  int i = blockIdx.x;
  if (i >= M) {
    for (int f = threadIdx.x; f < F; f += blockDim.x)
      split4(0.f, 0.f, planes, ps, (size_t)i * F + f);
    return;
  }
  int e0 = off[i], e1 = off[i + 1];
  for (int f = threadIdx.x; f < F; f += blockDim.x) {
    float sr = 0.f, si = 0.f;
    for (int e = e0; e < e1; e++) {
      float2 v = evo[(size_t)esrc[e] * F + f];
      sr += v.x;
      si += v.y;
    }
    split4(sr, si, planes, ps, (size_t)i * F + f);
  }
}

__global__ void rowdot_wn(const float* __restrict__ X, const float* __restrict__ w,
                          float* __restrict__ out, int F, int n,
                          float* __restrict__ normout) {
  int i = blockIdx.x;
  __shared__ float red[256];
  float s = 0.f;
  if (i == n) {
    for (int k = threadIdx.x; k < F; k += 256) s += w[k] * w[k];
  } else {
    for (int f = threadIdx.x; f < F; f += 256) s += X[(size_t)i * F + f] * w[f];
  }
  red[threadIdx.x] = s;
  __syncthreads();
  for (int off = 128; off > 0; off >>= 1) {
    if (threadIdx.x < off) red[threadIdx.x] += red[threadIdx.x + off];
    __syncthreads();
  }
  if (threadIdx.x == 0) {
    if (i == n) normout[0] = sqrtf(red[0]);
    else out[i] = red[0];
  }
}

__global__ __launch_bounds__(1024) void bitonic_topk(const float* __restrict__ score,
                                                     int n, int* __restrict__ perm, int k,
                                                     int* __restrict__ map,
                                                     int* __restrict__ cntz, int ncnt) {
  __shared__ unsigned long long keys[4096];
  int t = threadIdx.x;
  for (int i = t; i < 4096; i += 1024) {
    unsigned long long kk = 0ull;
    if (i < n) {
      float f = score[i];
      unsigned u = __float_as_uint(f);
      u = (f >= 0.0f) ? (u | 0x80000000u) : ~u;
      kk = ((unsigned long long)u << 32) | (unsigned)(~(unsigned)i);
    }
    keys[i] = kk;
  }
  __syncthreads();
  for (int size = 2; size <= 4096; size <<= 1) {
    for (int stride = size >> 1; stride > 0; stride >>= 1) {
      for (int i = t; i < 2048; i += 1024) {
        int pos = ((i & ~(stride - 1)) << 1) | (i & (stride - 1));
        int partner = pos + stride;
        bool desc = (pos & size) == 0;
        unsigned long long a = keys[pos], b = keys[partner];
        if ((a < b) == desc) { keys[pos] = b; keys[partner] = a; }
      }
      __syncthreads();
    }
  }
  for (int i = t; i < 4096; i += 1024) {
    int idx = (int)(~(unsigned)(keys[i] & 0xFFFFFFFFull));
    if (idx >= 0) map[idx] = (i < k) ? i : -1;
    if (i < k) perm[i] = idx;
  }
  for (int i = t; i < ncnt; i += 1024) cntz[i] = 0;
}

__global__ void pool_gather(const float* __restrict__ X, const int* __restrict__ perm,
                            const float* __restrict__ dot, const float* __restrict__ normbuf,
                            float* __restrict__ Xn, int F) {
  int i = blockIdx.x;
  int p = perm[i];
  float sc = tanhf(dot[p] / normbuf[0]);
  for (int f = threadIdx.x; f < F; f += blockDim.x)
    Xn[(size_t)i * F + f] = X[(size_t)p * F + f] * sc;
}

__global__ void remap_hist(const int* __restrict__ srcIn, const int* __restrict__ dstIn,
                           const float* __restrict__ emIn, const int* __restrict__ map,
                           int* __restrict__ srcOut, int* __restrict__ dstOut,
                           float* __restrict__ emOut, int* __restrict__ cnt) {
  int e = blockIdx.x * 256 + threadIdx.x;
  if (e >= E) return;
  int ns = map[srcIn[e]], nd = map[dstIn[e]];
  float m = emIn ? emIn[e] : 1.0f;
  if (ns < 0 || nd < 0) m = 0.f;
  srcOut[e] = ns < 0 ? 0 : ns;
  dstOut[e] = nd < 0 ? 0 : nd;
  emOut[e] = m;
  if (m != 0.f) atomicAdd(&cnt[nd], 1);
}

__global__ void col_mean(const float* __restrict__ X, float* __restrict__ out,
                         int rows, int cols) {
  int c = blockIdx.x;
  __shared__ float red[256];
  float s = 0.f;
  for (int r = threadIdx.x; r < rows; r += 256) s += X[(size_t)r * cols + c];
  red[threadIdx.x] = s;
  __syncthreads();
  for (int off = 128; off > 0; off >>= 1) {
    if (threadIdx.x < off) red[threadIdx.x] += red[threadIdx.x + off];
    __syncthreads();
  }
  if (threadIdx.x == 0) out[c] = red[0] / (float)rows;
}

// magph + col_means reading split-K PART directly (R13: folds the AGG1
// creduce — each element is consumed exactly once here, so the z-sum
// moves inline with no redundant work).
__global__ void magph_mean_part(const float2* __restrict__ Part, int S,
                                const float* __restrict__ xr,
                                const float* __restrict__ xi,
                                float* __restrict__ gm, float* __restrict__ gp,
                                int rows, int cols) {
  int c = blockIdx.x;
  __shared__ float rm[256], rp[256];
  size_t MN = (size_t)rows * cols;
  float sm = 0.f, sp = 0.f;
  for (int r = threadIdx.x; r < rows; r += 256) {
    size_t o = (size_t)r * cols + c;
    float re = xr[o], im = xi[o];
    for (int z = 0; z < S; z++) {
      float2 p = Part[z * MN + o];
      re += p.x;
      im += p.y;
    }
    sm += sqrtf(re * re + im * im);
    sp += atan2f(im, re);
  }
  rm[threadIdx.x] = sm;
  rp[threadIdx.x] = sp;
  __syncthreads();
  for (int off = 128; off > 0; off >>= 1) {
    if (threadIdx.x < off) {
      rm[threadIdx.x] += rm[threadIdx.x + off];
      rp[threadIdx.x] += rp[threadIdx.x + off];
    }
    __syncthreads();
  }
  if (threadIdx.x == 0) {
    gm[c] = rm[0] / (float)rows;
    gp[c] = rp[0] / (float)rows;
  }
}

template <int ACT>
__global__ void vecmat(const float* __restrict__ v, const float* __restrict__ W,
                       const float* __restrict__ b, float* __restrict__ out,
                       int Kdim, int Ndim) {
  __shared__ float vs[256];
  for (int k = threadIdx.x; k < Kdim; k += blockDim.x) vs[k] = v[k];
  __syncthreads();
  for (int j = threadIdx.x; j < Ndim; j += blockDim.x) {
    float acc = b ? b[j] : 0.f;
    for (int k = 0; k < Kdim; k++) acc += vs[k] * W[(size_t)k * Ndim + j];
    out[j] = (ACT == 1) ? fmaxf(acc, 0.f) : acc;
  }
}

__global__ void vecmat_tanh_wide(const float* __restrict__ v, const float* __restrict__ W,
                                 const float* __restrict__ b, float* __restrict__ out,
                                 int Kdim, int Ndim, int* __restrict__ anrm_init) {
  __shared__ float vs[64];
  if (threadIdx.x < Kdim) vs[threadIdx.x] = v[threadIdx.x];
  if (blockIdx.x == 0 && threadIdx.x == 0) *anrm_init = 0;
  __syncthreads();
  int j = blockIdx.x * 256 + threadIdx.x;
  if (j >= Ndim) return;
  float acc = b[j];
  for (int k = 0; k < Kdim; k++) acc += vs[k] * W[(size_t)k * Ndim + j];
  out[j] = tanhf(acc);
}

__global__ __launch_bounds__(256) void heads_fused(
    const float* __restrict__ GM, const float* __restrict__ GP,
    const float* __restrict__ mc1_w, const float* __restrict__ mc1_b,
    const float* __restrict__ mc2_w, const float* __restrict__ mc2_b,
    const float* __restrict__ pc1_w, const float* __restrict__ pc1_b,
    const float* __restrict__ pc2_w, const float* __restrict__ pc2_b,
    float* __restrict__ out) {
  __shared__ float g[256], h[128], acc[NC];
  int t = threadIdx.x;
  if (t < NC) acc[t] = 0.f;
  for (int pass = 0; pass < 2; pass++) {
    const float* gv = pass ? GP : GM;
    const float* w1 = pass ? pc1_w : mc1_w;
    const float* b1 = pass ? pc1_b : mc1_b;
    const float* w2 = pass ? pc2_w : mc2_w;
    const float* b2 = pass ? pc2_b : mc2_b;
    g[t] = gv[t];
    __syncthreads();
    if (t < 128) {
      float s = b1[t];
      for (int k = 0; k < 256; k++) s += g[k] * w1[(size_t)k * 128 + t];
      h[t] = fmaxf(s, 0.f);
    }
    __syncthreads();
    if (t < NC) {
      float s = b2[t];
      for (int k = 0; k < 128; k++) s += h[k] * w2[(size_t)k * NC + t];
      acc[t] += s;
    }
    __syncthreads();
  }
  if (t < NC) out[t] = acc[t];
}

// ---------------- host helpers ----------------
static inline int sk_chunk32(int K, int S) { return (((K + S - 1) / S) + 31) & ~31; }

// ---------------- host ----------------
extern "C" void kernel_launch(void* const* d_in, const int* in_sizes, int n_in,
                              void* d_out, int out_size, void* d_ws, size_t ws_size,
                              hipStream_t stream) {
  if (ws_size < WS_TOTAL) return;

  const float* x       = (const float*)d_in[0];
  const int*   ei      = (const int*)d_in[1];
  const float* gcn1_w  = (const float*)d_in[2];
  const float* gcn1_b  = (const float*)d_in[3];
  const float* pool1_w = (const float*)d_in[4];
  const float* gcn2_w  = (const float*)d_in[5];
  const float* gcn2_b  = (const float*)d_in[6];
  const float* pool2_w = (const float*)d_in[7];
  const float* inr_w   = (const float*)d_in[8];
  const float* inr_b   = (const float*)d_in[9];
  const float* ini_w   = (const float*)d_in[10];
  const float* ini_b   = (const float*)d_in[11];
  const float* enc1_w  = (const float*)d_in[12];
  const float* enc1_b  = (const float*)d_in[13];
  const float* enc2_w  = (const float*)d_in[14];
  const float* enc2_b  = (const float*)d_in[15];
  const float* p1_w    = (const float*)d_in[16];
  const float* p1_b    = (const float*)d_in[17];
  const float* p2_w    = (const float*)d_in[18];
  const float* p2_b    = (const float*)d_in[19];
  const float* p3_w    = (const float*)d_in[20];
  const float* p3_b    = (const float*)d_in[21];
  const float* rt_w    = (const float*)d_in[22];
  const float* rt_b    = (const float*)d_in[23];
  const float* it_w    = (const float*)d_in[24];
  const float* it_b    = (const float*)d_in[25];
  const float* msg_wr  = (const float*)d_in[26];
  const float* msg_wi  = (const float*)d_in[27];
  const float* mc1_w   = (const float*)d_in[28];
  const float* mc1_b   = (const float*)d_in[29];
  const float* mc2_w   = (const float*)d_in[30];
  const float* mc2_b   = (const float*)d_in[31];
  const float* pc1_w   = (const float*)d_in[32];
  const float* pc1_b   = (const float*)d_in[33];
  const float* pc2_w   = (const float*)d_in[34];
  const float* pc2_b   = (const float*)d_in[35];

  char* ws = (char*)d_ws;
  float*  H1    = (float*)(ws + O_H1);
  float*  OUT1  = (float*)(ws + O_OUT1);
  int*    CNT1  = (int*)(ws + O_DEG1);
  float*  DIS1  = (float*)(ws + O_DIS1);
  float*  SC1   = (float*)(ws + O_SC1);
  int*    PERM1 = (int*)(ws + O_PERM1);
  int*    MAP1  = (int*)(ws + O_MAP1);
  float*  H1P   = (float*)(ws + O_H1P);
  int*    SRC2  = (int*)(ws + O_SRC2);
  int*    DST2  = (int*)(ws + O_DST2);
  float*  EM2   = (float*)(ws + O_EM2);
  float*  H2    = (float*)(ws + O_H2);
  float*  OUT2  = (float*)(ws + O_OUT2);
  int*    CNT2  = (int*)(ws + O_DEG2);
  float*  DIS2  = (float*)(ws + O_DIS2);
  float*  SC2   = (float*)(ws + O_SC2);
  int*    PERM2 = (int*)(ws + O_PERM2);
  int*    MAP2  = (int*)(ws + O_MAP2);
  float*  H2P   = (float*)(ws + O_H2P);
  int*    SRC3  = (int*)(ws + O_SRC3);
  int*    DST3  = (int*)(ws + O_DST3);
  float*  EM3   = (float*)(ws + O_EM3);
  float*  XRb   = (float*)(ws + O_XR);
  float*  XIb   = (float*)(ws + O_XI);
  int*    CNT3  = (int*)(ws + O_DEG3);
  float*  DIS3  = (float*)(ws + O_DIS3);
  float*  XG1   = (float*)(ws + O_XG1);
  float*  XG2H  = (float*)(ws + O_XG2H);
  float*  XG2   = (float*)(ws + O_XG2);
  float*  EMB   = (float*)(ws + O_EMB);
  float*  T1    = (float*)(ws + O_T1);
  float*  T2    = (float*)(ws + O_T2);
  float*  NORM  = (float*)(ws + O_NORM);
  int*    ANRM  = (int*)(NORM + 2);
  int*    SDEV  = (int*)(NORM + 3);
  float*  SCALE = NORM + 4;
  int*    DEGF  = (int*)(NORM + 5);
  float*  PMV   = (float*)(ws + O_PM);
  float2* BM    = (float2*)(ws + O_BM);
  float2* XC    = (float2*)(ws + O_XC);
  float2* EVO   = (float2*)(ws + O_EVO);
  float*  GM    = (float*)(ws + O_GM);
  float*  GP    = (float*)(ws + O_GP);
  unsigned short* SA = (unsigned short*)(ws + O_SA);
  unsigned short* ST = (unsigned short*)(ws + O_ST);
  float2* PART  = (float2*)(ws + O_PARTX);
  float2* B2v   = (float2*)(ws + O_B2);
  int*    COFF  = (int*)(ws + O_CSR_OFF);
  int*    CCUR  = (int*)(ws + O_CSR_CUR);
  int*    CSRC  = (int*)(ws + O_CSR_SRC);
  float*  CCOEF = (float*)(ws + O_CSR_CF);

  const int* SRC1 = ei;
  const int* DST1 = ei + E;
  const int eg = E / 256;

  // ---------- Stage A: gcn1 (CSR gather) ----------
  rmm64<0><<<dim3(HD / 64, N0 / 64), 256, 0, stream>>>(x, gcn1_w, nullptr, H1, N0, HD, DIN, 1, 0);
  hipMemsetAsync(CNT1, 0, F4(N0), stream);
  hist_edges<<<eg, 256, 0, stream>>>(DST1, nullptr, CNT1);
  scan_offsets<<<1, 1024, 0, stream>>>(CNT1, N0, COFF, CCUR, DIS1);
  fill_edges<<<eg, 256, 0, stream>>>(SRC1, DST1, nullptr, DIS1, CCUR, CSRC, CCOEF);
  gcn_gather<1><<<N0, 256, 0, stream>>>(COFF, CSRC, CCOEF, H1, DIS1, gcn1_b, OUT1, HD);

  // ---------- pool1 ----------
  rowdot_wn<<<N0 + 1, 256, 0, stream>>>(OUT1, pool1_w, SC1, HD, N0, NORM);
  bitonic_topk<<<1, 1024, 0, stream>>>(SC1, N0, PERM1, K1, MAP1, CNT2, K1);
  pool_gather<<<K1, 256, 0, stream>>>(OUT1, PERM1, SC1, NORM, H1P, HD);
  remap_hist<<<eg, 256, 0, stream>>>(SRC1, DST1, nullptr, MAP1, SRC2, DST2, EM2, CNT2);

  // ---------- Stage C: gcn2 (CSR gather) ----------
  rmm64<0><<<dim3(HD / 64, (K1 + 63) / 64), 256, 0, stream>>>(H1P, gcn2_w, nullptr, H2, K1, HD, HD, 1, 0);
  scan_offsets<<<1, 1024, 0, stream>>>(CNT2, K1, COFF, CCUR, DIS2);
  fill_edges<<<eg, 256, 0, stream>>>(SRC2, DST2, EM2, DIS2, CCUR, CSRC, CCOEF);
  gcn_gather<1><<<K1, 256, 0, stream>>>(COFF, CSRC, CCOEF, H2, DIS2, gcn2_b, OUT2, HD);

  // ---------- pool2 ----------
  rowdot_wn<<<K1 + 1, 256, 0, stream>>>(OUT2, pool2_w, SC2, HD, K1, NORM + 1);
  bitonic_topk<<<1, 1024, 0, stream>>>(SC2, K1, PERM2, K2, MAP2, CNT3, K2);
  pool_gather<<<K2, 256, 0, stream>>>(OUT2, PERM2, SC2, NORM + 1, H2P, HD);
  remap_hist<<<eg, 256, 0, stream>>>(SRC2, DST2, EM2, MAP2, SRC3, DST3, EM3, CNT3);

  // ---------- xr / xi (dual GEMM) ----------
  rmm64_dual<0><<<dim3(HD / 64, (K2 + 63) / 64, 2), 256, 0, stream>>>(
      H2P, H2P, inr_w, ini_w, inr_b, ini_b, XRb, XIb, K2, HD, HD, 1);

  // ---------- CSR3 (persists through expm) ----------
  scan_offsets<<<1, 1024, 0, stream>>>(CNT3, K2, COFF, CCUR, DIS3);
  fill_edges<<<eg, 256, 0, stream>>>(SRC3, DST3, EM3, DIS3, CCUR, CSRC, CCOEF);

  // ---------- encoder GCNs on pooled graph ----------
  enc1_fused<<<K2, 64, 0, stream>>>(COFF, CCOEF, DIS3, enc1_w, enc1_b, XG1);
  rmm64<0><<<dim3(UHD / 64, (K2 + 63) / 64), 256, 0, stream>>>(XG1, enc2_w, nullptr, XG2H, K2, UHD, UHD, 1, 0);
  gcn_gather<0><<<K2, 64, 0, stream>>>(COFF, CSRC, CCOEF, XG2H, DIS3, enc2_b, XG2, UHD);
  col_mean<<<UHD, 256, 0, stream>>>(XG2, EMB, K2, UHD);

  // ---------- parameter MLP -> pm ; runtime s and Taylor degree ----------
  vecmat<1><<<1, 256, 0, stream>>>(EMB, p1_w, p1_b, T1, UHD, UHD);
  vecmat<1><<<1, 256, 0, stream>>>(T1, p2_w, p2_b, T2, UHD, UHD / 2);
  vecmat_tanh_wide<<<(PMN + 255) / 256, 256, 0, stream>>>(T2, p3_w, p3_b, PMV, UHD / 2, PMN, ANRM);
  anorm_rows<<<K2, 256, 0, stream>>>(PMV, K2, ANRM);
  finalize_s<<<1, 1, 0, stream>>>(ANRM, SDEV, SCALE, DEGF);

  // ---------- expm: PS deg-{11,8,5} (runtime) + gated squarings ----------
  const int sgrid = (PLD * PLD + 255) / 256;
  const dim3 tg22(PLD / 32, PLD / 32);
  const int chF = sk_chunk32(PLD, CSPLIT);   // 96
  const dim3 gBig(CSPLIT, 11, 11);
  const float c3 = 1.f / 6.f, c4 = 1.f / 24.f, c5 = 1.f / 120.f;
  const float c6 = 1.f / 720.f, c7 = 1.f / 5040.f, c8 = 1.f / 40320.f;

  build_B_split<<<tg22, 256, 0, stream>>>(PMV, K2, SCALE, BM, SA, ST, PPS, PLD, PLD);
  // B2 = B*B : B2v fp32 + SA <- B2
  cmm_bf16_sk<<<gBig, 256, 0, stream>>>(SA, PPS, PLD, ST, PPS, PLD, PART, K2, K2, PLD, chF,
                                        nullptr, 0, nullptr, 0);
  creduce_tiled<1, 1, 0><<<tg22, 256, 0, stream>>>(PART, CSPLIT, K2, K2, PLD, PLD,
      B2v, SA, PPS, nullptr, 0, 0.f, nullptr, 0.f, nullptr, 0.f, nullptr, 0, nullptr, 0);
  // B3 = B2*B : ST <- B3^T only (y for all degree variants)
  cmm_bf16_sk<<<gBig, 256, 0, stream>>>(SA, PPS, PLD, ST, PPS, PLD, PART, K2, K2, PLD, chF,
                                        nullptr, 0, nullptr, 0);
  creduce_tiled<0, 0, 1><<<tg22, 256, 0, stream>>>(PART, CSPLIT, K2, K2, PLD, PLD,
      nullptr, nullptr, 0, ST, PPS, 0.f, nullptr, 0.f, nullptr, 0.f, nullptr, 0, nullptr, 0);
  // P = D_start (degree-dependent coeffs; SA planes)
  combo3_planes<<<sgrid, 256, 0, stream>>>(BM, B2v, SA, PPS, K2, K2, PLD, PLD, DEGF);
  // Horner slot 1 (+D2): active iff deg-11 (DEGF == 0)
  cmm_bf16_sk<<<gBig, 256, 0, stream>>>(SA, PPS, PLD, ST, PPS, PLD, PART, K2, K2, PLD, chF,
                                        nullptr, 0, DEGF, 0);
  creduce_tiled<0, 1, 0><<<tg22, 256, 0, stream>>>(PART, CSPLIT, K2, K2, PLD, PLD,
      nullptr, SA, PPS, nullptr, 0, c6, BM, c7, B2v, c8, nullptr, 0, DEGF, 0);
  // Horner slot 2 (+D1): active iff deg >= 8 (DEGF <= 1)
  cmm_bf16_sk<<<gBig, 256, 0, stream>>>(SA, PPS, PLD, ST, PPS, PLD, PART, K2, K2, PLD, chF,
                                        nullptr, 0, DEGF, 1);
  creduce_tiled<0, 1, 0><<<tg22, 256, 0, stream>>>(PART, CSPLIT, K2, K2, PLD, PLD,
      nullptr, SA, PPS, nullptr, 0, c3, BM, c4, B2v, c5, nullptr, 0, DEGF, 1);
  // Horner slot 3 (+D0): always active
  cmm_bf16_sk<<<gBig, 256, 0, stream>>>(SA, PPS, PLD, ST, PPS, PLD, PART, K2, K2, PLD, chF,
                                        nullptr, 0, nullptr, 0);
  creduce_tiled<0, 1, 1><<<tg22, 256, 0, stream>>>(PART, CSPLIT, K2, K2, PLD, PLD,
      nullptr, SA, PPS, ST, PPS, 1.f, BM, 1.f, B2v, 0.5f, nullptr, 0, nullptr, 0);
  // Gated squaring slots: slot t active iff t < s-1
  for (int t = 0; t < SQ_SLOTS; ++t) {
    cmm_bf16_sk<<<gBig, 256, 0, stream>>>(SA, PPS, PLD, ST, PPS, PLD, PART, K2, K2, PLD, chF,
                                          SDEV, t, nullptr, 0);
    creduce_tiled<0, 1, 1><<<tg22, 256, 0, stream>>>(PART, CSPLIT, K2, K2, PLD, PLD,
        nullptr, SA, PPS, ST, PPS, 0.f, nullptr, 0.f, nullptr, 0.f, SDEV, t, nullptr, 0);
  }
  // SA holds S = U^(1/2) planes.

  // ---------- quantum message passing: EVO = S@(S@XC) ----------
  rmm64_dual<1><<<dim3(HD / 64, (K2 + 63) / 64, 2), 256, 0, stream>>>(
      XRb, XIb, rt_w, it_w, rt_b, it_b, (float*)XC, (float*)XC + 1, K2, HD, HD, 2);
  {
    const int mn = K2 * HD;
    const int rg = (mn + 255) / 256;
    const dim3 gSkin(CSPLIT, HD / 64, 11);
    const size_t psX = (size_t)HD * PLD;
    split_planesT<<<dim3((PLD + 31) / 32, (HD + 31) / 32), 256, 0, stream>>>(
        XC, K2, HD, ST, HD, PLD, psX);
    cmm_bf16_sk<<<gSkin, 256, 0, stream>>>(SA, PPS, PLD, ST, psX, PLD, PART, K2, HD, PLD, chF,
                                           nullptr, 0, nullptr, 0);
    creduce_tiled<0, 0, 1><<<dim3(HD / 32, PLD / 32), 256, 0, stream>>>(
        PART, CSPLIT, K2, HD, PLD, HD, nullptr, nullptr, 0, ST, psX,
        0.f, nullptr, 0.f, nullptr, 0.f, nullptr, 0, nullptr, 0);
    cmm_bf16_sk<<<gSkin, 256, 0, stream>>>(SA, PPS, PLD, ST, psX, PLD, PART, K2, HD, PLD, chF,
                                           nullptr, 0, nullptr, 0);
    creduce<<<rg, 256, 0, stream>>>(PART, EVO, mn, HD, CSPLIT, 0.f, nullptr, 0.f, nullptr, 0.f);
    const size_t psG = (size_t)PLD * HD;
    agg_gather_split<<<PLD, 256, 0, stream>>>(COFF, CSRC, EVO, SA, psG, HD, K2);
    split_planesT2<<<dim3((HD + 31) / 32, (HD + 31) / 32), 256, 0, stream>>>(
        msg_wr, msg_wi, HD, HD, ST, HD, HD, (size_t)HD * HD);
    cmm_bf16_sk<<<gSkin, 256, 0, stream>>>(SA, psG, HD, ST, (size_t)HD * HD, HD, PART,
                                           K2, HD, HD, sk_chunk32(HD, CSPLIT),
                                           nullptr, 0, nullptr, 0);
    // AGG1 reduce folded into magph (R13): read PART directly.
    magph_mean_part<<<HD, 256, 0, stream>>>(PART, CSPLIT, XRb, XIb, GM, GP, K2, HD);
  }

  // ---------- fused classifier heads ----------
  heads_fused<<<1, 256, 0, stream>>>(GM, GP, mc1_w, mc1_b, mc2_w, mc2_b,
                                     pc1_w, pc1_b, pc2_w, pc2_b, (float*)d_out);
}

// Round 14
// 833.277 us; speedup vs baseline: 1.0806x; 1.0806x over previous
//
#include <hip/hip_runtime.h>
#include <cstddef>
#include <utility>

// ---------------- problem constants ----------------
constexpr int N0  = 4096;
constexpr int E   = 65536;
constexpr int DIN = 128;
constexpr int HD  = 256;   // H
constexpr int NC  = 10;
constexpr int UHD = 64;    // UH
constexpr int K1  = 3277;  // ceil(0.8*4096)
constexpr int K2  = 656;   // ceil(0.2*3277)
constexpr int PMN = K2 * K2; // 430336

// expm(A): A = 2^s*B, RUNTIME s = clamp(ceil(log2(||A||_1/1.4)),1,5) (R12).
// Deg-11 PS Taylor (R13 degree gates reverted: they never fired — ||B||
// lands in (0.43,1.4] when s is chosen by this rule — and cost overhead).
constexpr int SQ_SLOTS = 4;  // max explicit squarings (last folded into EVO)

// MFMA plane geometry: 656 -> padded 704 = 11*64 = 22*32.
constexpr int PLD = 704;
constexpr size_t PPS = (size_t)PLD * PLD;

// Split-K: CSPLIT=8, z = blockIdx.x -> one k-slice per XCD (R8/R9).
constexpr int CSPLIT = 8;

// ---------------- workspace layout ----------------
#define F4(n) ((size_t)(n) * 4)
constexpr size_t O_H1    = 0;
constexpr size_t O_OUT1  = O_H1    + F4(N0 * HD);
constexpr size_t O_DEG1  = O_OUT1  + F4(N0 * HD);
constexpr size_t O_DIS1  = O_DEG1  + F4(N0);
constexpr size_t O_SC1   = O_DIS1  + F4(N0);
constexpr size_t O_PERM1 = O_SC1   + F4(N0);
constexpr size_t O_MAP1  = O_PERM1 + F4(N0);
constexpr size_t O_H1P   = O_MAP1  + F4(N0);
constexpr size_t O_SRC2  = O_H1P   + F4(K1 * HD);
constexpr size_t O_DST2  = O_SRC2  + F4(E);
constexpr size_t O_EM2   = O_DST2  + F4(E);
constexpr size_t O_H2    = O_EM2   + F4(E);
constexpr size_t O_OUT2  = O_H2    + F4(K1 * HD);
constexpr size_t O_DEG2  = O_OUT2  + F4(K1 * HD);
constexpr size_t O_DIS2  = O_DEG2  + F4(N0);
constexpr size_t O_SC2   = O_DIS2  + F4(N0);
constexpr size_t O_PERM2 = O_SC2   + F4(N0);
constexpr size_t O_MAP2  = O_PERM2 + F4(N0);
constexpr size_t O_H2P   = O_MAP2  + F4(N0);
constexpr size_t O_SRC3  = O_H2P   + F4(K2 * HD);
constexpr size_t O_DST3  = O_SRC3  + F4(E);
constexpr size_t O_EM3   = O_DST3  + F4(E);
constexpr size_t O_XR    = O_EM3   + F4(E);
constexpr size_t O_XI    = O_XR    + F4(K2 * HD);
constexpr size_t O_DEG3  = O_XI    + F4(K2 * HD);
constexpr size_t O_DIS3  = O_DEG3  + F4(1024);
constexpr size_t O_SCOEF = O_DIS3  + F4(1024);
constexpr size_t O_XG1   = O_SCOEF + F4(1024);
constexpr size_t O_XG2H  = O_XG1   + F4(K2 * UHD);
constexpr size_t O_XG2   = O_XG2H  + F4(K2 * UHD);
constexpr size_t O_EMB   = O_XG2   + F4(K2 * UHD);
constexpr size_t O_T1    = O_EMB   + F4(64);
constexpr size_t O_T2    = O_T1    + F4(64);
constexpr size_t O_NORM  = O_T2    + F4(64);   // [0..1] pool norms, [2] ANRM,
                                               // [3] S_DEV, [4] SCALE
constexpr size_t O_PM    = O_NORM  + F4(64);
constexpr size_t O_BM    = O_PM    + F4(PMN);          // float2
constexpr size_t O_P0    = O_BM    + F4(PMN) * 2;      // float2 (unused)
constexpr size_t O_P1    = O_P0    + F4(PMN) * 2;      // float2 (unused)
constexpr size_t O_XRT   = O_P1    + F4(PMN) * 2;
constexpr size_t O_XIT   = O_XRT   + F4(K2 * HD);
constexpr size_t O_XC    = O_XIT   + F4(K2 * HD);      // float2
constexpr size_t O_EVO   = O_XC    + F4(K2 * HD) * 2;  // float2
constexpr size_t O_AGG0  = O_EVO   + F4(K2 * HD) * 2;  // float2
constexpr size_t O_WC    = O_AGG0  + F4(K2 * HD) * 2;  // float2 256x256
constexpr size_t O_AGG1  = O_WC    + F4(HD * HD) * 2;  // float2 (unused)
constexpr size_t O_MAG   = O_AGG1  + F4(K2 * HD) * 2;
constexpr size_t O_PH    = O_MAG   + F4(K2 * HD);
constexpr size_t O_GM    = O_PH    + F4(K2 * HD);
constexpr size_t O_GP    = O_GM    + F4(256);
constexpr size_t O_HM    = O_GP    + F4(256);
constexpr size_t O_HP    = O_HM    + F4(256);
constexpr size_t O_LM    = O_HP    + F4(256);
constexpr size_t O_LP    = O_LM    + F4(64);
constexpr size_t WS_NEED = O_LP    + F4(64);

// SA/ST bf16 plane sets in the dead stage-A/B region (below O_SRC3).
constexpr size_t O_SA = 0;
constexpr size_t O_ST = O_SA + PPS * 2 * 4;
static_assert(O_ST + PPS * 2 * 4 <= O_SRC3, "SA/ST must fit in dead region");

// B2 fp32 (only fp32 PS power re-read as epilogue input) aliases XRT region.
constexpr size_t O_B2 = O_XRT;
static_assert(O_B2 + F4(PMN) * 2 <= O_MAG, "B2 must fit in XRT..AGG1 region");

// CSR slot in the MAG/PH region.
constexpr size_t O_CSR_OFF = O_MAG;                 // (N0+1) ints
constexpr size_t O_CSR_CUR = O_CSR_OFF + F4(4104);
constexpr size_t O_CSR_SRC = O_CSR_CUR + F4(4104);  // E ints
constexpr size_t O_CSR_CF  = O_CSR_SRC + F4(E);     // E floats
static_assert(O_CSR_CF + F4(E) <= O_GM, "CSR must fit in MAG/PH region");

// Extension region past WS_NEED (harness ws_size ~268 MB; runtime-guarded).
constexpr size_t O_PARTX  = (WS_NEED + 255) & ~(size_t)255;
constexpr size_t PART_SZ  = (size_t)CSPLIT * PMN * 8;   // 27.5 MB
constexpr size_t WS_TOTAL = O_PARTX + PART_SZ;

// ---------------- bf16 helpers ----------------
typedef __attribute__((ext_vector_type(8))) short s8v;   // 8 bf16 (4 VGPRs)
typedef __attribute__((ext_vector_type(4))) float f4v;   // MFMA acc

__device__ inline unsigned short f2bf(float x) {
  unsigned u = __float_as_uint(x);
  u += 0x7FFFu + ((u >> 16) & 1u);
  return (unsigned short)(u >> 16);
}
__device__ inline float bf2f(unsigned short h) {
  return __uint_as_float(((unsigned)h) << 16);
}
__device__ inline void split4(float re, float im, unsigned short* out,
                              size_t ps, size_t o) {
  unsigned short rh = f2bf(re);
  unsigned short rl = f2bf(re - bf2f(rh));
  unsigned short ih = f2bf(im);
  unsigned short il = f2bf(im - bf2f(ih));
  out[o] = rh; out[ps + o] = rl; out[2 * ps + o] = ih; out[3 * ps + o] = il;
}

// ---------------- kernels ----------------

// real GEMM fp32 with register prefetch double-buffer (R14: rocprof showed
// rmm64_dual at 41 us / 144 GB/s / 3% VALUBusy — barrier-drain latency-bound
// exactly like R5's cmm; prefetch hides the staging loads behind FMA).
// Pool-score path stays fp32 for exact top-k ordering.
template <int ACT>
__global__ void rmm64(const float* __restrict__ A, const float* __restrict__ B,
                      const float* __restrict__ bias, float* __restrict__ C,
                      int M, int N, int K, int CS, int CO) {
  __shared__ float As[64][17];
  __shared__ float Bs[16][64];
  int t  = threadIdx.x;
  int tx = t & 15, ty = t >> 4;
  int bm = blockIdx.y * 64, bn = blockIdx.x * 64;
  float ra[4], rb[4];
#pragma unroll
  for (int i = 0; i < 4; i++) {
    int l = t + i * 256;
    int gr = bm + (l >> 4);
    ra[i] = (gr < M) ? A[(size_t)gr * K + (l & 15)] : 0.f;
    int gc = bn + (l & 63);
    rb[i] = (gc < N) ? B[(size_t)(l >> 6) * N + gc] : 0.f;
  }
  float acc[4][4] = {};
  for (int kt = 0; kt < K; kt += 16) {
#pragma unroll
    for (int i = 0; i < 4; i++) {
      int l = t + i * 256;
      As[l >> 4][l & 15] = ra[i];
      Bs[l >> 6][l & 63] = rb[i];
    }
    __syncthreads();
    int kn = kt + 16;
    if (kn < K) {
#pragma unroll
      for (int i = 0; i < 4; i++) {
        int l = t + i * 256;
        int gr = bm + (l >> 4);
        ra[i] = (gr < M) ? A[(size_t)gr * K + kn + (l & 15)] : 0.f;
        int gc = bn + (l & 63);
        rb[i] = (gc < N) ? B[(size_t)(kn + (l >> 6)) * N + gc] : 0.f;
      }
    }
#pragma unroll
    for (int kk = 0; kk < 16; kk++) {
      float a[4], b[4];
#pragma unroll
      for (int i = 0; i < 4; i++) a[i] = As[ty + 16 * i][kk];
#pragma unroll
      for (int j = 0; j < 4; j++) b[j] = Bs[kk][tx + 16 * j];
#pragma unroll
      for (int i = 0; i < 4; i++)
#pragma unroll
        for (int j = 0; j < 4; j++) acc[i][j] += a[i] * b[j];
    }
    __syncthreads();
  }
#pragma unroll
  for (int i = 0; i < 4; i++) {
    int r = bm + ty + 16 * i;
    if (r >= M) continue;
#pragma unroll
    for (int j = 0; j < 4; j++) {
      int c = bn + tx + 16 * j;
      if (c >= N) continue;
      float v = acc[i][j] + (bias ? bias[c] : 0.f);
      if (ACT == 1) v = fmaxf(v, 0.f);
      C[((size_t)r * N + c) * CS + CO] = v;
    }
  }
}

// Dual rmm64 (blockIdx.z selects operand set), with the same prefetch.
template <int ACT>
__global__ void rmm64_dual(const float* __restrict__ A0, const float* __restrict__ A1,
                           const float* __restrict__ B0, const float* __restrict__ B1,
                           const float* __restrict__ b0, const float* __restrict__ b1,
                           float* __restrict__ C0, float* __restrict__ C1,
                           int M, int N, int K, int CS) {
  const float* A = blockIdx.z ? A1 : A0;
  const float* B = blockIdx.z ? B1 : B0;
  const float* bias = blockIdx.z ? b1 : b0;
  float* C = blockIdx.z ? C1 : C0;
  __shared__ float As[64][17];
  __shared__ float Bs[16][64];
  int t  = threadIdx.x;
  int tx = t & 15, ty = t >> 4;
  int bm = blockIdx.y * 64, bn = blockIdx.x * 64;
  float ra[4], rb[4];
#pragma unroll
  for (int i = 0; i < 4; i++) {
    int l = t + i * 256;
    int gr = bm + (l >> 4);
    ra[i] = (gr < M) ? A[(size_t)gr * K + (l & 15)] : 0.f;
    int gc = bn + (l & 63);
    rb[i] = (gc < N) ? B[(size_t)(l >> 6) * N + gc] : 0.f;
  }
  float acc[4][4] = {};
  for (int kt = 0; kt < K; kt += 16) {
#pragma unroll
    for (int i = 0; i < 4; i++) {
      int l = t + i * 256;
      As[l >> 4][l & 15] = ra[i];
      Bs[l >> 6][l & 63] = rb[i];
    }
    __syncthreads();
    int kn = kt + 16;
    if (kn < K) {
#pragma unroll
      for (int i = 0; i < 4; i++) {
        int l = t + i * 256;
        int gr = bm + (l >> 4);
        ra[i] = (gr < M) ? A[(size_t)gr * K + kn + (l & 15)] : 0.f;
        int gc = bn + (l & 63);
        rb[i] = (gc < N) ? B[(size_t)(kn + (l >> 6)) * N + gc] : 0.f;
      }
    }
#pragma unroll
    for (int kk = 0; kk < 16; kk++) {
      float a[4], b[4];
#pragma unroll
      for (int i = 0; i < 4; i++) a[i] = As[ty + 16 * i][kk];
#pragma unroll
      for (int j = 0; j < 4; j++) b[j] = Bs[kk][tx + 16 * j];
#pragma unroll
      for (int i = 0; i < 4; i++)
#pragma unroll
        for (int j = 0; j < 4; j++) acc[i][j] += a[i] * b[j];
    }
    __syncthreads();
  }
#pragma unroll
  for (int i = 0; i < 4; i++) {
    int r = bm + ty + 16 * i;
    if (r >= M) continue;
#pragma unroll
    for (int j = 0; j < 4; j++) {
      int c = bn + tx + 16 * j;
      if (c >= N) continue;
      float v = acc[i][j] + (bias ? bias[c] : 0.f);
      if (ACT == 1) v = fmaxf(v, 0.f);
      C[((size_t)r * N + c) * CS] = v;
    }
  }
}

// Transposed split: out[n*ld + k] = split(in[k][n]); tiled via LDS.
__global__ void split_planesT(const float2* __restrict__ in, int inM, int inN,
                              unsigned short* __restrict__ out, int padR, int ld,
                              size_t ps) {
  __shared__ float2 tile[32][33];
  int tx = threadIdx.x & 31, ty = threadIdx.x >> 5;   // 32 x 8
  int k0 = blockIdx.x * 32, n0 = blockIdx.y * 32;
  for (int i = ty; i < 32; i += 8) {
    int k = k0 + i, n = n0 + tx;
    tile[i][tx] = (k < inM && n < inN) ? in[(size_t)k * inN + n]
                                       : make_float2(0.f, 0.f);
  }
  __syncthreads();
  for (int i = ty; i < 32; i += 8) {
    int n = n0 + i, k = k0 + tx;
    if (n < padR && k < ld)
      split4(tile[tx][i].x, tile[tx][i].y, out, ps, (size_t)n * ld + k);
  }
}

// Transposed split from two real fp32 matrices (re, im): W = re + i*im.
__global__ void split_planesT2(const float* __restrict__ re, const float* __restrict__ im,
                               int inM, int inN, unsigned short* __restrict__ out,
                               int padR, int ld, size_t ps) {
  __shared__ float2 tile[32][33];
  int tx = threadIdx.x & 31, ty = threadIdx.x >> 5;
  int k0 = blockIdx.x * 32, n0 = blockIdx.y * 32;
  for (int i = ty; i < 32; i += 8) {
    int k = k0 + i, n = n0 + tx;
    tile[i][tx] = (k < inM && n < inN)
        ? make_float2(re[(size_t)k * inN + n], im[(size_t)k * inN + n])
        : make_float2(0.f, 0.f);
  }
  __syncthreads();
  for (int i = ty; i < 32; i += 8) {
    int n = n0 + i, k = k0 + tx;
    if (n < padR && k < ld)
      split4(tile[tx][i].x, tile[tx][i].y, out, ps, (size_t)n * ld + k);
  }
}

// Split-K complex MFMA GEMM with register double-buffer prefetch.
// gate/slot: runtime squaring gate (inactive if slot >= *gate-1).
__global__ __launch_bounds__(256, 2) void cmm_bf16_sk(
    const unsigned short* __restrict__ SA, size_t psA, int ldA,
    const unsigned short* __restrict__ ST, size_t psT, int ldT,
    float2* __restrict__ Part, int M, int N, int Kp, int chunk,
    const int* __restrict__ gate, int slot) {
  if (gate && slot >= *gate - 1) return;
  int k0 = blockIdx.x * chunk;
  int kend = min(Kp, k0 + chunk);
  int t = threadIdx.x;
  int wave = t >> 6, lane = t & 63;
  int quad = lane >> 4, mn = lane & 15;
  int rowA = blockIdx.z * 64 + wave * 16 + mn;
  int bn = blockIdx.y * 64;
  const unsigned short* a0 = SA + (size_t)rowA * ldA;
  f4v accR[4], accI[4];
#pragma unroll
  for (int i = 0; i < 4; i++) {
    accR[i] = (f4v){0.f, 0.f, 0.f, 0.f};
    accI[i] = (f4v){0.f, 0.f, 0.f, 0.f};
  }
  s8v cA[4], cB[4][4], nA[4], nB[4][4];
  {
    int ka = k0 + quad * 8;
#pragma unroll
    for (int p = 0; p < 4; p++) cA[p] = *(const s8v*)(a0 + p * psA + ka);
#pragma unroll
    for (int tl = 0; tl < 4; tl++) {
      const unsigned short* b0 = ST + (size_t)(bn + tl * 16 + mn) * ldT + ka;
#pragma unroll
      for (int p = 0; p < 4; p++) cB[tl][p] = *(const s8v*)(b0 + p * psT);
    }
  }
  for (int kt = k0; kt < kend; kt += 32) {
    int kn = kt + 32;
    if (kn < kend) {
      int ka = kn + quad * 8;
#pragma unroll
      for (int p = 0; p < 4; p++) nA[p] = *(const s8v*)(a0 + p * psA + ka);
#pragma unroll
      for (int tl = 0; tl < 4; tl++) {
        const unsigned short* b0 = ST + (size_t)(bn + tl * 16 + mn) * ldT + ka;
#pragma unroll
        for (int p = 0; p < 4; p++) nB[tl][p] = *(const s8v*)(b0 + p * psT);
      }
    }
    s8v nih, nil_;
#pragma unroll
    for (int q = 0; q < 8; q++) {
      nih[q]  = (short)(cA[2][q] ^ (short)0x8000);   // -ai
      nil_[q] = (short)(cA[3][q] ^ (short)0x8000);
    }
#pragma unroll
    for (int tl = 0; tl < 4; tl++) {
      f4v r = accR[tl];
      r = __builtin_amdgcn_mfma_f32_16x16x32_bf16(cA[0], cB[tl][0], r, 0, 0, 0);
      r = __builtin_amdgcn_mfma_f32_16x16x32_bf16(cA[1], cB[tl][0], r, 0, 0, 0);
      r = __builtin_amdgcn_mfma_f32_16x16x32_bf16(cA[0], cB[tl][1], r, 0, 0, 0);
      r = __builtin_amdgcn_mfma_f32_16x16x32_bf16(nih, cB[tl][2], r, 0, 0, 0);
      r = __builtin_amdgcn_mfma_f32_16x16x32_bf16(nil_, cB[tl][2], r, 0, 0, 0);
      r = __builtin_amdgcn_mfma_f32_16x16x32_bf16(nih, cB[tl][3], r, 0, 0, 0);
      accR[tl] = r;
      f4v im = accI[tl];
      im = __builtin_amdgcn_mfma_f32_16x16x32_bf16(cA[0], cB[tl][2], im, 0, 0, 0);
      im = __builtin_amdgcn_mfma_f32_16x16x32_bf16(cA[1], cB[tl][2], im, 0, 0, 0);
      im = __builtin_amdgcn_mfma_f32_16x16x32_bf16(cA[0], cB[tl][3], im, 0, 0, 0);
      im = __builtin_amdgcn_mfma_f32_16x16x32_bf16(cA[2], cB[tl][0], im, 0, 0, 0);
      im = __builtin_amdgcn_mfma_f32_16x16x32_bf16(cA[3], cB[tl][0], im, 0, 0, 0);
      im = __builtin_amdgcn_mfma_f32_16x16x32_bf16(cA[2], cB[tl][1], im, 0, 0, 0);
      accI[tl] = im;
    }
    if (kn < kend) {
#pragma unroll
      for (int p = 0; p < 4; p++) cA[p] = nA[p];
#pragma unroll
      for (int tl = 0; tl < 4; tl++)
#pragma unroll
        for (int p = 0; p < 4; p++) cB[tl][p] = nB[tl][p];
    }
  }
  float2* P = Part + (size_t)blockIdx.x * M * N;
#pragma unroll
  for (int tl = 0; tl < 4; tl++) {
    int col = bn + tl * 16 + mn;
    if (col >= N) continue;
#pragma unroll
    for (int r = 0; r < 4; r++) {
      int row = blockIdx.z * 64 + wave * 16 + quad * 4 + r;
      if (row >= M) continue;
      P[(size_t)row * N + col] = make_float2(accR[tl][r], accI[tl][r]);
    }
  }
}

// Plain reduce: C = sum_z Part[z] + e0*I + e1*E1 + e2*E2.
__global__ void creduce(const float2* __restrict__ Part, float2* __restrict__ C,
                        int MN, int N, int S, float e0,
                        const float2* __restrict__ E1, float e1,
                        const float2* __restrict__ E2, float e2) {
  int idx = blockIdx.x * 256 + threadIdx.x;
  if (idx >= MN) return;
  float sr = 0.f, si = 0.f;
  for (int z = 0; z < S; z++) {
    float2 p = Part[(size_t)z * MN + idx];
    sr += p.x;
    si += p.y;
  }
  if (e0 != 0.f) {
    int r = idx / N;
    if (idx - r * N == r) sr += e0;
  }
  if (E1) { float2 b = E1[idx]; sr += e1 * b.x; si += e1 * b.y; }
  if (E2) { float2 b = E2[idx]; sr += e2 * b.x; si += e2 * b.y; }
  C[idx] = make_float2(sr, si);
}

// Tiled fused reduce: sum_z Part + epilogue -> optional fp32 C, SA planes,
// transposed ST planes. Gated (inactive slot preserves SA).
template <int WC_, int WSA, int WST>
__global__ void creduce_tiled(const float2* __restrict__ Part, int S, int M, int N,
                              int RP, int CP, float2* __restrict__ C,
                              unsigned short* __restrict__ SAp, size_t psA,
                              unsigned short* __restrict__ STp, size_t psT,
                              float e0, const float2* __restrict__ E1, float e1,
                              const float2* __restrict__ E2, float e2,
                              const int* __restrict__ gate, int slot) {
  if (gate && slot >= *gate - 1) return;
  __shared__ float vr[32][33], vi[32][33];
  int tx = threadIdx.x & 31, ty = threadIdx.x >> 5;
  int r0 = blockIdx.y * 32, c0 = blockIdx.x * 32;
  size_t MN = (size_t)M * N;
  for (int i = ty; i < 32; i += 8) {
    int r = r0 + i, c = c0 + tx;
    float sr = 0.f, si = 0.f;
    if (r < M && c < N) {
      size_t o = (size_t)r * N + c;
      for (int z = 0; z < S; z++) {
        float2 p = Part[z * MN + o];
        sr += p.x;
        si += p.y;
      }
      if (e0 != 0.f && r == c) sr += e0;
      if (E1) { float2 b = E1[o]; sr += e1 * b.x; si += e1 * b.y; }
      if (E2) { float2 b = E2[o]; sr += e2 * b.x; si += e2 * b.y; }
      if (WC_) C[o] = make_float2(sr, si);
    }
    if (WSA) split4(sr, si, SAp, psA, (size_t)r * CP + c);
    if (WST) { vr[i][tx] = sr; vi[i][tx] = si; }
  }
  if (WST) {
    __syncthreads();
    for (int i = ty; i < 32; i += 8) {
      int c = c0 + i, r = r0 + tx;
      split4(vr[tx][i], vi[tx][i], STp, psT, (size_t)c * RP + r);
    }
  }
}

// Fused build_B + split + splitT: BM fp32 + SA(B) + ST(B^T); runtime scale.
__global__ void build_B_split(const float* __restrict__ pm, int n,
                              const float* __restrict__ scale_p,
                              float2* __restrict__ BM,
                              unsigned short* __restrict__ SAp,
                              unsigned short* __restrict__ STp, size_t ps,
                              int RP, int CP) {
  __shared__ float vr[32][33], vi[32][33];
  float scale = scale_p[0];
  int tx = threadIdx.x & 31, ty = threadIdx.x >> 5;
  int r0 = blockIdx.y * 32, c0 = blockIdx.x * 32;
  for (int i = ty; i < 32; i += 8) {
    int r = r0 + i, c = c0 + tx;
    float sr = 0.f, si = 0.f;
    if (r < n && c < n) {
      float pij = pm[(size_t)r * n + c];
      float pji = pm[(size_t)c * n + r];
      sr = scale * (pij - pji);
      si = scale * (pij + pji);
      BM[(size_t)r * n + c] = make_float2(sr, si);
    }
    split4(sr, si, SAp, ps, (size_t)r * CP + c);
    vr[i][tx] = sr;
    vi[i][tx] = si;
  }
  __syncthreads();
  for (int i = ty; i < 32; i += 8) {
    int c = c0 + i, r = r0 + tx;
    split4(vr[tx][i], vi[tx][i], STp, ps, (size_t)c * RP + r);
  }
}

// ||A||_1 -> atomicMax as int bits (values >= 0 so int compare works).
__global__ void anorm_rows(const float* __restrict__ pm, int n,
                           int* __restrict__ anrm) {
  int i = blockIdx.x;
  __shared__ float red[256];
  float s = 0.f;
  for (int j = threadIdx.x; j < n; j += 256) {
    float pij = pm[(size_t)i * n + j];
    float pji = pm[(size_t)j * n + i];
    float a = pij - pji, b = pij + pji;
    s += sqrtf(a * a + b * b);
  }
  red[threadIdx.x] = s;
  __syncthreads();
  for (int off = 128; off > 0; off >>= 1) {
    if (threadIdx.x < off) red[threadIdx.x] += red[threadIdx.x + off];
    __syncthreads();
  }
  if (threadIdx.x == 0) atomicMax(anrm, __float_as_int(red[0] * 0.025f));
}

// s = clamp(ceil(log2(||A||_1/1.4)),1,5); scale = 0.025*2^-s.
__global__ void finalize_s(const int* __restrict__ anrm, int* __restrict__ sdev,
                           float* __restrict__ scale) {
  float a = __int_as_float(*anrm);
  int s = (int)ceilf(log2f(fmaxf(a, 1e-20f) / 1.4f));
  s = min(max(s, 1), SQ_SLOTS + 1);
  *sdev = s;
  *scale = 0.025f * exp2f(-(float)s);
}

// D3 = c9*I + c10*B + c11*B2 -> SA planes only.
__global__ void combo3_planes(const float2* __restrict__ Bp, const float2* __restrict__ B2p,
                              unsigned short* __restrict__ planes, size_t ps,
                              int M, int N, int padR, int ld,
                              float e0, float e1, float e2) {
  int idx = blockIdx.x * 256 + threadIdx.x;
  if (idx >= padR * ld) return;
  int r = idx / ld, c = idx - r * ld;
  float sr = 0.f, si = 0.f;
  if (r < M && c < N) {
    size_t o = (size_t)r * N + c;
    float2 b = Bp[o], b2 = B2p[o];
    sr = e1 * b.x + e2 * b2.x;
    si = e1 * b.y + e2 * b2.y;
    if (r == c) sr += e0;
  }
  split4(sr, si, planes, ps, idx);
}

// ---- CSR build ----
__global__ void hist_edges(const int* __restrict__ dst, const float* __restrict__ em,
                           int* __restrict__ cnt) {
  int e = blockIdx.x * 256 + threadIdx.x;
  if (e >= E) return;
  float m = em ? em[e] : 1.0f;
  if (m != 0.f) atomicAdd(&cnt[dst[e]], 1);
}

__global__ __launch_bounds__(1024) void scan_offsets(const int* __restrict__ cnt, int n,
                                                     int* __restrict__ off,
                                                     int* __restrict__ cur,
                                                     float* __restrict__ dis) {
  __shared__ int sums[1024];
  int t = threadIdx.x;
  int base = t * 4;
  int v[4];
  int s = 0;
#pragma unroll
  for (int j = 0; j < 4; j++) {
    int i = base + j;
    int ci = (i < n) ? cnt[i] : 0;
    if (i < n) dis[i] = 1.0f / sqrtf((float)ci + 1.0f);
    v[j] = s;
    s += ci;
  }
  sums[t] = s;
  __syncthreads();
  for (int d = 1; d < 1024; d <<= 1) {
    int x = (t >= d) ? sums[t - d] : 0;
    __syncthreads();
    sums[t] += x;
    __syncthreads();
  }
  int pre = (t > 0) ? sums[t - 1] : 0;
#pragma unroll
  for (int j = 0; j < 4; j++) {
    int i = base + j;
    if (i < n) { int o = pre + v[j]; off[i] = o; cur[i] = o; }
  }
  if (t == 1023) off[n] = sums[1023];
}

__global__ void fill_edges(const int* __restrict__ src, const int* __restrict__ dst,
                           const float* __restrict__ em, const float* __restrict__ dis,
                           int* __restrict__ cur, int* __restrict__ esrc,
                           float* __restrict__ ecoef) {
  int e = blockIdx.x * 256 + threadIdx.x;
  if (e >= E) return;
  float m = em ? em[e] : 1.0f;
  if (m == 0.f) return;
  int s = src[e], d = dst[e];
  int pos = atomicAdd(&cur[d], 1);
  esrc[pos] = s;
  ecoef[pos] = dis[s] * dis[d];
}

template <int ACT>
__global__ void gcn_gather(const int* __restrict__ off, const int* __restrict__ esrc,
                           const float* __restrict__ ecoef, const float* __restrict__ Hm,
                           const float* __restrict__ dis, const float* __restrict__ bias,
                           float* __restrict__ out, int F) {
  int i = blockIdx.x;
  int e0 = off[i], e1 = off[i + 1];
  float d2 = dis[i] * dis[i];
  for (int f = threadIdx.x; f < F; f += blockDim.x) {
    float acc = d2 * Hm[(size_t)i * F + f] + bias[f];
    for (int e = e0; e < e1; e++)
      acc += ecoef[e] * Hm[(size_t)esrc[e] * F + f];
    if (ACT == 1) acc = fmaxf(acc, 0.f);
    out[(size_t)i * F + f] = acc;
  }
}

__global__ void enc1_fused(const int* __restrict__ off, const float* __restrict__ ecoef,
                           const float* __restrict__ dis, const float* __restrict__ w,
                           const float* __restrict__ b, float* __restrict__ xg1) {
  int i = blockIdx.x;
  int lane = threadIdx.x;   // 64 = one wave
  float s = 0.f;
  for (int e = off[i] + lane; e < off[i + 1]; e += 64) s += ecoef[e];
#pragma unroll
  for (int d = 32; d > 0; d >>= 1) s += __shfl_xor(s, d, 64);
  float sc = s + dis[i] * dis[i];
  xg1[(size_t)i * UHD + lane] = fmaxf(sc * w[lane] + b[lane], 0.f);
}

__global__ void agg_gather_split(const int* __restrict__ off, const int* __restrict__ esrc,
                                 const float2* __restrict__ evo,
                                 unsigned short* __restrict__ planes, size_t ps,
                                 int F, int M) {
  int i = blockIdx.x;
  if (i >= M) {
    for (int f = threadIdx.x; f < F; f += blockDim.x)
      split4(0.f, 0.f, planes, ps, (size_t)i * F + f);
    return;
  }
  int e0 = off[i], e1 = off[i + 1];
  for (int f = threadIdx.x; f < F; f += blockDim.x) {
    float sr = 0.f, si = 0.f;
    for (int e = e0; e < e1; e++) {
      float2 v = evo[(size_t)esrc[e] * F + f];
      sr += v.x;
      si += v.y;
    }
    split4(sr, si, planes, ps, (size_t)i * F + f);
  }
}

__global__ void rowdot_wn(const float* __restrict__ X, const float* __restrict__ w,
                          float* __restrict__ out, int F, int n,
                          float* __restrict__ normout) {
  int i = blockIdx.x;
  __shared__ float red[256];
  float s = 0.f;
  if (i == n) {
    for (int k = threadIdx.x; k < F; k += 256) s += w[k] * w[k];
  } else {
    for (int f = threadIdx.x; f < F; f += 256) s += X[(size_t)i * F + f] * w[f];
  }
  red[threadIdx.x] = s;
  __syncthreads();
  for (int off = 128; off > 0; off >>= 1) {
    if (threadIdx.x < off) red[threadIdx.x] += red[threadIdx.x + off];
    __syncthreads();
  }
  if (threadIdx.x == 0) {
    if (i == n) normout[0] = sqrtf(red[0]);
    else out[i] = red[0];
  }
}

__global__ __launch_bounds__(1024) void bitonic_topk(const float* __restrict__ score,
                                                     int n, int* __restrict__ perm, int k,
                                                     int* __restrict__ map,
                                                     int* __restrict__ cntz, int ncnt) {
  __shared__ unsigned long long keys[4096];
  int t = threadIdx.x;
  for (int i = t; i < 4096; i += 1024) {
    unsigned long long kk = 0ull;
    if (i < n) {
      float f = score[i];
      unsigned u = __float_as_uint(f);
      u = (f >= 0.0f) ? (u | 0x80000000u) : ~u;
      kk = ((unsigned long long)u << 32) | (unsigned)(~(unsigned)i);
    }
    keys[i] = kk;
  }
  __syncthreads();
  for (int size = 2; size <= 4096; size <<= 1) {
    for (int stride = size >> 1; stride > 0; stride >>= 1) {
      for (int i = t; i < 2048; i += 1024) {
        int pos = ((i & ~(stride - 1)) << 1) | (i & (stride - 1));
        int partner = pos + stride;
        bool desc = (pos & size) == 0;
        unsigned long long a = keys[pos], b = keys[partner];
        if ((a < b) == desc) { keys[pos] = b; keys[partner] = a; }
      }
      __syncthreads();
    }
  }
  for (int i = t; i < 4096; i += 1024) {
    int idx = (int)(~(unsigned)(keys[i] & 0xFFFFFFFFull));
    if (idx >= 0) map[idx] = (i < k) ? i : -1;
    if (i < k) perm[i] = idx;
  }
  for (int i = t; i < ncnt; i += 1024) cntz[i] = 0;
}

__global__ void pool_gather(const float* __restrict__ X, const int* __restrict__ perm,
                            const float* __restrict__ dot, const float* __restrict__ normbuf,
                            float* __restrict__ Xn, int F) {
  int i = blockIdx.x;
  int p = perm[i];
  float sc = tanhf(dot[p] / normbuf[0]);
  for (int f = threadIdx.x; f < F; f += blockDim.x)
    Xn[(size_t)i * F + f] = X[(size_t)p * F + f] * sc;
}

__global__ void remap_hist(const int* __restrict__ srcIn, const int* __restrict__ dstIn,
                           const float* __restrict__ emIn, const int* __restrict__ map,
                           int* __restrict__ srcOut, int* __restrict__ dstOut,
                           float* __restrict__ emOut, int* __restrict__ cnt) {
  int e = blockIdx.x * 256 + threadIdx.x;
  if (e >= E) return;
  int ns = map[srcIn[e]], nd = map[dstIn[e]];
  float m = emIn ? emIn[e] : 1.0f;
  if (ns < 0 || nd < 0) m = 0.f;
  srcOut[e] = ns < 0 ? 0 : ns;
  dstOut[e] = nd < 0 ? 0 : nd;
  emOut[e] = m;
  if (m != 0.f) atomicAdd(&cnt[nd], 1);
}

__global__ void col_mean(const float* __restrict__ X, float* __restrict__ out,
                         int rows, int cols) {
  int c = blockIdx.x;
  __shared__ float red[256];
  float s = 0.f;
  for (int r = threadIdx.x; r < rows; r += 256) s += X[(size_t)r * cols + c];
  red[threadIdx.x] = s;
  __syncthreads();
  for (int off = 128; off > 0; off >>= 1) {
    if (threadIdx.x < off) red[threadIdx.x] += red[threadIdx.x + off];
    __syncthreads();
  }
  if (threadIdx.x == 0) out[c] = red[0] / (float)rows;
}

// magph + col_means reading split-K PART directly (folds AGG1 reduce).
__global__ void magph_mean_part(const float2* __restrict__ Part, int S,
                                const float* __restrict__ xr,
                                const float* __restrict__ xi,
                                float* __restrict__ gm, float* __restrict__ gp,
                                int rows, int cols) {
  int c = blockIdx.x;
  __shared__ float rm[256], rp[256];
  size_t MN = (size_t)rows * cols;
  float sm = 0.f, sp = 0.f;
  for (int r = threadIdx.x; r < rows; r += 256) {
    size_t o = (size_t)r * cols + c;
    float re = xr[o], im = xi[o];
    for (int z = 0; z < S; z++) {
      float2 p = Part[z * MN + o];
      re += p.x;
      im += p.y;
    }
    sm += sqrtf(re * re + im * im);
    sp += atan2f(im, re);
  }
  rm[threadIdx.x] = sm;
  rp[threadIdx.x] = sp;
  __syncthreads();
  for (int off = 128; off > 0; off >>= 1) {
    if (threadIdx.x < off) {
      rm[threadIdx.x] += rm[threadIdx.x + off];
      rp[threadIdx.x] += rp[threadIdx.x + off];
    }
    __syncthreads();
  }
  if (threadIdx.x == 0) {
    gm[c] = rm[0] / (float)rows;
    gp[c] = rp[0] / (float)rows;
  }
}

template <int ACT>
__global__ void vecmat(const float* __restrict__ v, const float* __restrict__ W,
                       const float* __restrict__ b, float* __restrict__ out,
                       int Kdim, int Ndim) {
  __shared__ float vs[256];
  for (int k = threadIdx.x; k < Kdim; k += blockDim.x) vs[k] = v[k];
  __syncthreads();
  for (int j = threadIdx.x; j < Ndim; j += blockDim.x) {
    float acc = b ? b[j] : 0.f;
    for (int k = 0; k < Kdim; k++) acc += vs[k] * W[(size_t)k * Ndim + j];
    out[j] = (ACT == 1) ? fmaxf(acc, 0.f) : acc;
  }
}

__global__ void vecmat_tanh_wide(const float* __restrict__ v, const float* __restrict__ W,
                                 const float* __restrict__ b, float* __restrict__ out,
                                 int Kdim, int Ndim, int* __restrict__ anrm_init) {
  __shared__ float vs[64];
  if (threadIdx.x < Kdim) vs[threadIdx.x] = v[threadIdx.x];
  if (blockIdx.x == 0 && threadIdx.x == 0) *anrm_init = 0;
  __syncthreads();
  int j = blockIdx.x * 256 + threadIdx.x;
  if (j >= Ndim) return;
  float acc = b[j];
  for (int k = 0; k < Kdim; k++) acc += vs[k] * W[(size_t)k * Ndim + j];
  out[j] = tanhf(acc);
}

__global__ __launch_bounds__(256) void heads_fused(
    const float* __restrict__ GM, const float* __restrict__ GP,
    const float* __restrict__ mc1_w, const float* __restrict__ mc1_b,
    const float* __restrict__ mc2_w, const float* __restrict__ mc2_b,
    const float* __restrict__ pc1_w, const float* __restrict__ pc1_b,
    const float* __restrict__ pc2_w, const float* __restrict__ pc2_b,
    float* __restrict__ out) {
  __shared__ float g[256], h[128], acc[NC];
  int t = threadIdx.x;
  if (t < NC) acc[t] = 0.f;
  for (int pass = 0; pass < 2; pass++) {
    const float* gv = pass ? GP : GM;
    const float* w1 = pass ? pc1_w : mc1_w;
    const float* b1 = pass ? pc1_b : mc1_b;
    const float* w2 = pass ? pc2_w : mc2_w;
    const float* b2 = pass ? pc2_b : mc2_b;
    g[t] = gv[t];
    __syncthreads();
    if (t < 128) {
      float s = b1[t];
      for (int k = 0; k < 256; k++) s += g[k] * w1[(size_t)k * 128 + t];
      h[t] = fmaxf(s, 0.f);
    }
    __syncthreads();
    if (t < NC) {
      float s = b2[t];
      for (int k = 0; k < 128; k++) s += h[k] * w2[(size_t)k * NC + t];
      acc[t] += s;
    }
    __syncthreads();
  }
  if (t < NC) out[t] = acc[t];
}

// ---------------- host helpers ----------------
static inline int sk_chunk32(int K, int S) { return (((K + S - 1) / S) + 31) & ~31; }

// ---------------- host ----------------
extern "C" void kernel_launch(void* const* d_in, const int* in_sizes, int n_in,
                              void* d_out, int out_size, void* d_ws, size_t ws_size,
                              hipStream_t stream) {
  if (ws_size < WS_TOTAL) return;

  const float* x       = (const float*)d_in[0];
  const int*   ei      = (const int*)d_in[1];
  const float* gcn1_w  = (const float*)d_in[2];
  const float* gcn1_b  = (const float*)d_in[3];
  const float* pool1_w = (const float*)d_in[4];
  const float* gcn2_w  = (const float*)d_in[5];
  const float* gcn2_b  = (const float*)d_in[6];
  const float* pool2_w = (const float*)d_in[7];
  const float* inr_w   = (const float*)d_in[8];
  const float* inr_b   = (const float*)d_in[9];
  const float* ini_w   = (const float*)d_in[10];
  const float* ini_b   = (const float*)d_in[11];
  const float* enc1_w  = (const float*)d_in[12];
  const float* enc1_b  = (const float*)d_in[13];
  const float* enc2_w  = (const float*)d_in[14];
  const float* enc2_b  = (const float*)d_in[15];
  const float* p1_w    = (const float*)d_in[16];
  const float* p1_b    = (const float*)d_in[17];
  const float* p2_w    = (const float*)d_in[18];
  const float* p2_b    = (const float*)d_in[19];
  const float* p3_w    = (const float*)d_in[20];
  const float* p3_b    = (const float*)d_in[21];
  const float* rt_w    = (const float*)d_in[22];
  const float* rt_b    = (const float*)d_in[23];
  const float* it_w    = (const float*)d_in[24];
  const float* it_b    = (const float*)d_in[25];
  const float* msg_wr  = (const float*)d_in[26];
  const float* msg_wi  = (const float*)d_in[27];
  const float* mc1_w   = (const float*)d_in[28];
  const float* mc1_b   = (const float*)d_in[29];
  const float* mc2_w   = (const float*)d_in[30];
  const float* mc2_b   = (const float*)d_in[31];
  const float* pc1_w   = (const float*)d_in[32];
  const float* pc1_b   = (const float*)d_in[33];
  const float* pc2_w   = (const float*)d_in[34];
  const float* pc2_b   = (const float*)d_in[35];

  char* ws = (char*)d_ws;
  float*  H1    = (float*)(ws + O_H1);
  float*  OUT1  = (float*)(ws + O_OUT1);
  int*    CNT1  = (int*)(ws + O_DEG1);
  float*  DIS1  = (float*)(ws + O_DIS1);
  float*  SC1   = (float*)(ws + O_SC1);
  int*    PERM1 = (int*)(ws + O_PERM1);
  int*    MAP1  = (int*)(ws + O_MAP1);
  float*  H1P   = (float*)(ws + O_H1P);
  int*    SRC2  = (int*)(ws + O_SRC2);
  int*    DST2  = (int*)(ws + O_DST2);
  float*  EM2   = (float*)(ws + O_EM2);
  float*  H2    = (float*)(ws + O_H2);
  float*  OUT2  = (float*)(ws + O_OUT2);
  int*    CNT2  = (int*)(ws + O_DEG2);
  float*  DIS2  = (float*)(ws + O_DIS2);
  float*  SC2   = (float*)(ws + O_SC2);
  int*    PERM2 = (int*)(ws + O_PERM2);
  int*    MAP2  = (int*)(ws + O_MAP2);
  float*  H2P   = (float*)(ws + O_H2P);
  int*    SRC3  = (int*)(ws + O_SRC3);
  int*    DST3  = (int*)(ws + O_DST3);
  float*  EM3   = (float*)(ws + O_EM3);
  float*  XRb   = (float*)(ws + O_XR);
  float*  XIb   = (float*)(ws + O_XI);
  int*    CNT3  = (int*)(ws + O_DEG3);
  float*  DIS3  = (float*)(ws + O_DIS3);
  float*  XG1   = (float*)(ws + O_XG1);
  float*  XG2H  = (float*)(ws + O_XG2H);
  float*  XG2   = (float*)(ws + O_XG2);
  float*  EMB   = (float*)(ws + O_EMB);
  float*  T1    = (float*)(ws + O_T1);
  float*  T2    = (float*)(ws + O_T2);
  float*  NORM  = (float*)(ws + O_NORM);
  int*    ANRM  = (int*)(NORM + 2);
  int*    SDEV  = (int*)(NORM + 3);
  float*  SCALE = NORM + 4;
  float*  PMV   = (float*)(ws + O_PM);
  float2* BM    = (float2*)(ws + O_BM);
  float2* XC    = (float2*)(ws + O_XC);
  float2* EVO   = (float2*)(ws + O_EVO);
  float*  GM    = (float*)(ws + O_GM);
  float*  GP    = (float*)(ws + O_GP);
  unsigned short* SA = (unsigned short*)(ws + O_SA);
  unsigned short* ST = (unsigned short*)(ws + O_ST);
  float2* PART  = (float2*)(ws + O_PARTX);
  float2* B2v   = (float2*)(ws + O_B2);
  int*    COFF  = (int*)(ws + O_CSR_OFF);
  int*    CCUR  = (int*)(ws + O_CSR_CUR);
  int*    CSRC  = (int*)(ws + O_CSR_SRC);
  float*  CCOEF = (float*)(ws + O_CSR_CF);

  const int* SRC1 = ei;
  const int* DST1 = ei + E;
  const int eg = E / 256;

  // ---------- Stage A: gcn1 (CSR gather) ----------
  rmm64<0><<<dim3(HD / 64, N0 / 64), 256, 0, stream>>>(x, gcn1_w, nullptr, H1, N0, HD, DIN, 1, 0);
  hipMemsetAsync(CNT1, 0, F4(N0), stream);
  hist_edges<<<eg, 256, 0, stream>>>(DST1, nullptr, CNT1);
  scan_offsets<<<1, 1024, 0, stream>>>(CNT1, N0, COFF, CCUR, DIS1);
  fill_edges<<<eg, 256, 0, stream>>>(SRC1, DST1, nullptr, DIS1, CCUR, CSRC, CCOEF);
  gcn_gather<1><<<N0, 256, 0, stream>>>(COFF, CSRC, CCOEF, H1, DIS1, gcn1_b, OUT1, HD);

  // ---------- pool1 ----------
  rowdot_wn<<<N0 + 1, 256, 0, stream>>>(OUT1, pool1_w, SC1, HD, N0, NORM);
  bitonic_topk<<<1, 1024, 0, stream>>>(SC1, N0, PERM1, K1, MAP1, CNT2, K1);
  pool_gather<<<K1, 256, 0, stream>>>(OUT1, PERM1, SC1, NORM, H1P, HD);
  remap_hist<<<eg, 256, 0, stream>>>(SRC1, DST1, nullptr, MAP1, SRC2, DST2, EM2, CNT2);

  // ---------- Stage C: gcn2 (CSR gather) ----------
  rmm64<0><<<dim3(HD / 64, (K1 + 63) / 64), 256, 0, stream>>>(H1P, gcn2_w, nullptr, H2, K1, HD, HD, 1, 0);
  scan_offsets<<<1, 1024, 0, stream>>>(CNT2, K1, COFF, CCUR, DIS2);
  fill_edges<<<eg, 256, 0, stream>>>(SRC2, DST2, EM2, DIS2, CCUR, CSRC, CCOEF);
  gcn_gather<1><<<K1, 256, 0, stream>>>(COFF, CSRC, CCOEF, H2, DIS2, gcn2_b, OUT2, HD);

  // ---------- pool2 ----------
  rowdot_wn<<<K1 + 1, 256, 0, stream>>>(OUT2, pool2_w, SC2, HD, K1, NORM + 1);
  bitonic_topk<<<1, 1024, 0, stream>>>(SC2, K1, PERM2, K2, MAP2, CNT3, K2);
  pool_gather<<<K2, 256, 0, stream>>>(OUT2, PERM2, SC2, NORM + 1, H2P, HD);
  remap_hist<<<eg, 256, 0, stream>>>(SRC2, DST2, EM2, MAP2, SRC3, DST3, EM3, CNT3);

  // ---------- xr / xi (dual GEMM) ----------
  rmm64_dual<0><<<dim3(HD / 64, (K2 + 63) / 64, 2), 256, 0, stream>>>(
      H2P, H2P, inr_w, ini_w, inr_b, ini_b, XRb, XIb, K2, HD, HD, 1);

  // ---------- CSR3 (persists through expm) ----------
  scan_offsets<<<1, 1024, 0, stream>>>(CNT3, K2, COFF, CCUR, DIS3);
  fill_edges<<<eg, 256, 0, stream>>>(SRC3, DST3, EM3, DIS3, CCUR, CSRC, CCOEF);

  // ---------- encoder GCNs on pooled graph ----------
  enc1_fused<<<K2, 64, 0, stream>>>(COFF, CCOEF, DIS3, enc1_w, enc1_b, XG1);
  rmm64<0><<<dim3(UHD / 64, (K2 + 63) / 64), 256, 0, stream>>>(XG1, enc2_w, nullptr, XG2H, K2, UHD, UHD, 1, 0);
  gcn_gather<0><<<K2, 64, 0, stream>>>(COFF, CSRC, CCOEF, XG2H, DIS3, enc2_b, XG2, UHD);
  col_mean<<<UHD, 256, 0, stream>>>(XG2, EMB, K2, UHD);

  // ---------- parameter MLP -> pm ; runtime squaring count s ----------
  vecmat<1><<<1, 256, 0, stream>>>(EMB, p1_w, p1_b, T1, UHD, UHD);
  vecmat<1><<<1, 256, 0, stream>>>(T1, p2_w, p2_b, T2, UHD, UHD / 2);
  vecmat_tanh_wide<<<(PMN + 255) / 256, 256, 0, stream>>>(T2, p3_w, p3_b, PMV, UHD / 2, PMN, ANRM);
  anorm_rows<<<K2, 256, 0, stream>>>(PMV, K2, ANRM);
  finalize_s<<<1, 1, 0, stream>>>(ANRM, SDEV, SCALE);

  // ---------- expm: PS deg-11 + gated squarings (last folded into EVO) ----
  const int sgrid = (PLD * PLD + 255) / 256;
  const dim3 tg22(PLD / 32, PLD / 32);
  const int chF = sk_chunk32(PLD, CSPLIT);   // 96
  const dim3 gBig(CSPLIT, 11, 11);
  const float c3 = 1.f / 6.f, c4 = 1.f / 24.f, c5 = 1.f / 120.f;
  const float c6 = 1.f / 720.f, c7 = 1.f / 5040.f, c8 = 1.f / 40320.f;
  const float c9 = 1.f / 362880.f, c10 = 1.f / 3628800.f, c11 = 1.f / 39916800.f;

  build_B_split<<<tg22, 256, 0, stream>>>(PMV, K2, SCALE, BM, SA, ST, PPS, PLD, PLD);
  // B2 = B*B : B2v fp32 + SA <- B2
  cmm_bf16_sk<<<gBig, 256, 0, stream>>>(SA, PPS, PLD, ST, PPS, PLD, PART, K2, K2, PLD, chF, nullptr, 0);
  creduce_tiled<1, 1, 0><<<tg22, 256, 0, stream>>>(PART, CSPLIT, K2, K2, PLD, PLD,
      B2v, SA, PPS, nullptr, 0, 0.f, nullptr, 0.f, nullptr, 0.f, nullptr, 0);
  // B3 = B2*B : ST <- B3^T only
  cmm_bf16_sk<<<gBig, 256, 0, stream>>>(SA, PPS, PLD, ST, PPS, PLD, PART, K2, K2, PLD, chF, nullptr, 0);
  creduce_tiled<0, 0, 1><<<tg22, 256, 0, stream>>>(PART, CSPLIT, K2, K2, PLD, PLD,
      nullptr, nullptr, 0, ST, PPS, 0.f, nullptr, 0.f, nullptr, 0.f, nullptr, 0);
  // P = D3 (SA planes)
  combo3_planes<<<sgrid, 256, 0, stream>>>(BM, B2v, SA, PPS, K2, K2, PLD, PLD, c9, c10, c11);
  // Horner x3
  cmm_bf16_sk<<<gBig, 256, 0, stream>>>(SA, PPS, PLD, ST, PPS, PLD, PART, K2, K2, PLD, chF, nullptr, 0);
  creduce_tiled<0, 1, 0><<<tg22, 256, 0, stream>>>(PART, CSPLIT, K2, K2, PLD, PLD,
      nullptr, SA, PPS, nullptr, 0, c6, BM, c7, B2v, c8, nullptr, 0);
  cmm_bf16_sk<<<gBig, 256, 0, stream>>>(SA, PPS, PLD, ST, PPS, PLD, PART, K2, K2, PLD, chF, nullptr, 0);
  creduce_tiled<0, 1, 0><<<tg22, 256, 0, stream>>>(PART, CSPLIT, K2, K2, PLD, PLD,
      nullptr, SA, PPS, nullptr, 0, c3, BM, c4, B2v, c5, nullptr, 0);
  cmm_bf16_sk<<<gBig, 256, 0, stream>>>(SA, PPS, PLD, ST, PPS, PLD, PART, K2, K2, PLD, chF, nullptr, 0);
  creduce_tiled<0, 1, 1><<<tg22, 256, 0, stream>>>(PART, CSPLIT, K2, K2, PLD, PLD,
      nullptr, SA, PPS, ST, PPS, 1.f, BM, 1.f, B2v, 0.5f, nullptr, 0);
  // Gated squaring slots: slot t active iff t < s-1
  for (int t = 0; t < SQ_SLOTS; ++t) {
    cmm_bf16_sk<<<gBig, 256, 0, stream>>>(SA, PPS, PLD, ST, PPS, PLD, PART, K2, K2, PLD, chF, SDEV, t);
    creduce_tiled<0, 1, 1><<<tg22, 256, 0, stream>>>(PART, CSPLIT, K2, K2, PLD, PLD,
        nullptr, SA, PPS, ST, PPS, 0.f, nullptr, 0.f, nullptr, 0.f, SDEV, t);
  }
  // SA holds S = U^(1/2) planes.

  // ---------- quantum message passing: EVO = S@(S@XC) ----------
  rmm64_dual<1><<<dim3(HD / 64, (K2 + 63) / 64, 2), 256, 0, stream>>>(
      XRb, XIb, rt_w, it_w, rt_b, it_b, (float*)XC, (float*)XC + 1, K2, HD, HD, 2);
  {
    const int mn = K2 * HD;
    const int rg = (mn + 255) / 256;
    const dim3 gSkin(CSPLIT, HD / 64, 11);
    const size_t psX = (size_t)HD * PLD;
    split_planesT<<<dim3((PLD + 31) / 32, (HD + 31) / 32), 256, 0, stream>>>(
        XC, K2, HD, ST, HD, PLD, psX);
    cmm_bf16_sk<<<gSkin, 256, 0, stream>>>(SA, PPS, PLD, ST, psX, PLD, PART, K2, HD, PLD, chF, nullptr, 0);
    creduce_tiled<0, 0, 1><<<dim3(HD / 32, PLD / 32), 256, 0, stream>>>(
        PART, CSPLIT, K2, HD, PLD, HD, nullptr, nullptr, 0, ST, psX,
        0.f, nullptr, 0.f, nullptr, 0.f, nullptr, 0);
    cmm_bf16_sk<<<gSkin, 256, 0, stream>>>(SA, PPS, PLD, ST, psX, PLD, PART, K2, HD, PLD, chF, nullptr, 0);
    creduce<<<rg, 256, 0, stream>>>(PART, EVO, mn, HD, CSPLIT, 0.f, nullptr, 0.f, nullptr, 0.f);
    const size_t psG = (size_t)PLD * HD;
    agg_gather_split<<<PLD, 256, 0, stream>>>(COFF, CSRC, EVO, SA, psG, HD, K2);
    split_planesT2<<<dim3((HD + 31) / 32, (HD + 31) / 32), 256, 0, stream>>>(
        msg_wr, msg_wi, HD, HD, ST, HD, HD, (size_t)HD * HD);
    cmm_bf16_sk<<<gSkin, 256, 0, stream>>>(SA, psG, HD, ST, (size_t)HD * HD, HD, PART,
                                           K2, HD, HD, sk_chunk32(HD, CSPLIT), nullptr, 0);
    magph_mean_part<<<HD, 256, 0, stream>>>(PART, CSPLIT, XRb, XIb, GM, GP, K2, HD);
  }

  // ---------- fused classifier heads ----------
  heads_fused<<<1, 256, 0, stream>>>(GM, GP, mc1_w, mc1_b, mc2_w, mc2_b,
                                     pc1_w, pc1_b, pc2_w, pc2_b, (float*)d_out);
}

// Round 15
// 822.543 us; speedup vs baseline: 1.0947x; 1.0131x over previous
//
#include <hip/hip_runtime.h>
#include <cstddef>
#include <utility>

// ---------------- problem constants ----------------
constexpr int N0  = 4096;
constexpr int E   = 65536;
constexpr int DIN = 128;
constexpr int HD  = 256;   // H
constexpr int NC  = 10;
constexpr int UHD = 64;    // UH
constexpr int K1  = 3277;  // ceil(0.8*4096)
constexpr int K2  = 656;   // ceil(0.2*3277)
constexpr int PMN = K2 * K2; // 430336

// expm(A): A = 2^s*B, RUNTIME s = clamp(ceil(log2(||A||_1/1.4)),1,5) (R12).
// Deg-11 PS Taylor; s-1 gated squarings; final squaring folded into EVO.
constexpr int SQ_SLOTS = 4;

// MFMA plane geometry: 656 -> padded 704 = 11*64 = 22*32.
constexpr int PLD = 704;
constexpr size_t PPS = (size_t)PLD * PLD;

// Split-K: CSPLIT=8, z = blockIdx.x -> one k-slice per XCD (R8/R9).
constexpr int CSPLIT = 8;

// ---------------- workspace layout ----------------
#define F4(n) ((size_t)(n) * 4)
constexpr size_t O_H1    = 0;
constexpr size_t O_OUT1  = O_H1    + F4(N0 * HD);
constexpr size_t O_DEG1  = O_OUT1  + F4(N0 * HD);
constexpr size_t O_DIS1  = O_DEG1  + F4(N0);
constexpr size_t O_SC1   = O_DIS1  + F4(N0);
constexpr size_t O_PERM1 = O_SC1   + F4(N0);
constexpr size_t O_MAP1  = O_PERM1 + F4(N0);
constexpr size_t O_H1P   = O_MAP1  + F4(N0);
constexpr size_t O_SRC2  = O_H1P   + F4(K1 * HD);
constexpr size_t O_DST2  = O_SRC2  + F4(E);
constexpr size_t O_EM2   = O_DST2  + F4(E);
constexpr size_t O_H2    = O_EM2   + F4(E);
constexpr size_t O_OUT2  = O_H2    + F4(K1 * HD);
constexpr size_t O_DEG2  = O_OUT2  + F4(K1 * HD);
constexpr size_t O_DIS2  = O_DEG2  + F4(N0);
constexpr size_t O_SC2   = O_DIS2  + F4(N0);
constexpr size_t O_PERM2 = O_SC2   + F4(N0);
constexpr size_t O_MAP2  = O_PERM2 + F4(N0);
constexpr size_t O_H2P   = O_MAP2  + F4(N0);
constexpr size_t O_SRC3  = O_H2P   + F4(K2 * HD);
constexpr size_t O_DST3  = O_SRC3  + F4(E);
constexpr size_t O_EM3   = O_DST3  + F4(E);
constexpr size_t O_XR    = O_EM3   + F4(E);
constexpr size_t O_XI    = O_XR    + F4(K2 * HD);
constexpr size_t O_DEG3  = O_XI    + F4(K2 * HD);
constexpr size_t O_DIS3  = O_DEG3  + F4(1024);
constexpr size_t O_SCOEF = O_DIS3  + F4(1024);
constexpr size_t O_XG1   = O_SCOEF + F4(1024);
constexpr size_t O_XG2H  = O_XG1   + F4(K2 * UHD);
constexpr size_t O_XG2   = O_XG2H  + F4(K2 * UHD);
constexpr size_t O_EMB   = O_XG2   + F4(K2 * UHD);
constexpr size_t O_T1    = O_EMB   + F4(64);
constexpr size_t O_T2    = O_T1    + F4(64);
constexpr size_t O_NORM  = O_T2    + F4(64);   // [0..1] pool norms, [2] ANRM,
                                               // [3] S_DEV, [4] SCALE, [5] DONE
constexpr size_t O_PM    = O_NORM  + F4(64);
constexpr size_t O_BM    = O_PM    + F4(PMN);          // float2
constexpr size_t O_P0    = O_BM    + F4(PMN) * 2;      // float2 (unused)
constexpr size_t O_P1    = O_P0    + F4(PMN) * 2;      // float2 (unused)
constexpr size_t O_XRT   = O_P1    + F4(PMN) * 2;
constexpr size_t O_XIT   = O_XRT   + F4(K2 * HD);
constexpr size_t O_XC    = O_XIT   + F4(K2 * HD);      // float2
constexpr size_t O_EVO   = O_XC    + F4(K2 * HD) * 2;  // float2
constexpr size_t O_AGG0  = O_EVO   + F4(K2 * HD) * 2;  // float2
constexpr size_t O_WC    = O_AGG0  + F4(K2 * HD) * 2;  // float2
constexpr size_t O_AGG1  = O_WC    + F4(HD * HD) * 2;  // float2 (unused)
constexpr size_t O_MAG   = O_AGG1  + F4(K2 * HD) * 2;
constexpr size_t O_PH    = O_MAG   + F4(K2 * HD);
constexpr size_t O_GM    = O_PH    + F4(K2 * HD);
constexpr size_t O_GP    = O_GM    + F4(256);
constexpr size_t O_HM    = O_GP    + F4(256);
constexpr size_t O_HP    = O_HM    + F4(256);
constexpr size_t O_LM    = O_HP    + F4(256);
constexpr size_t O_LP    = O_LM    + F4(64);
constexpr size_t WS_NEED = O_LP    + F4(64);

// SA/ST bf16 plane sets in the dead stage-A/B region (below O_SRC3).
constexpr size_t O_SA = 0;
constexpr size_t O_ST = O_SA + PPS * 2 * 4;
static_assert(O_ST + PPS * 2 * 4 <= O_SRC3, "SA/ST must fit in dead region");

// B2 fp32 aliases XRT region (only fp32 PS power re-read as epilogue input).
constexpr size_t O_B2 = O_XRT;
static_assert(O_B2 + F4(PMN) * 2 <= O_MAG, "B2 must fit in XRT..AGG1 region");

// CSR slot in the MAG/PH region.
constexpr size_t O_CSR_OFF = O_MAG;                 // (N0+1) ints
constexpr size_t O_CSR_CUR = O_CSR_OFF + F4(4104);
constexpr size_t O_CSR_SRC = O_CSR_CUR + F4(4104);  // E ints
constexpr size_t O_CSR_CF  = O_CSR_SRC + F4(E);     // E floats
static_assert(O_CSR_CF + F4(E) <= O_GM, "CSR must fit in MAG/PH region");

// Extension region past WS_NEED (harness ws_size ~268 MB; runtime-guarded).
constexpr size_t O_PARTX  = (WS_NEED + 255) & ~(size_t)255;
constexpr size_t PART_SZ  = (size_t)CSPLIT * PMN * 8;   // 27.5 MB
constexpr size_t WS_TOTAL = O_PARTX + PART_SZ;

// ---------------- bf16 helpers ----------------
typedef __attribute__((ext_vector_type(8))) short s8v;
typedef __attribute__((ext_vector_type(4))) float f4v;

__device__ inline unsigned short f2bf(float x) {
  unsigned u = __float_as_uint(x);
  u += 0x7FFFu + ((u >> 16) & 1u);
  return (unsigned short)(u >> 16);
}
__device__ inline float bf2f(unsigned short h) {
  return __uint_as_float(((unsigned)h) << 16);
}
__device__ inline void split4(float re, float im, unsigned short* out,
                              size_t ps, size_t o) {
  unsigned short rh = f2bf(re);
  unsigned short rl = f2bf(re - bf2f(rh));
  unsigned short ih = f2bf(im);
  unsigned short il = f2bf(im - bf2f(ih));
  out[o] = rh; out[ps + o] = rl; out[2 * ps + o] = ih; out[3 * ps + o] = il;
}

// ---------------- kernels ----------------

// real GEMM fp32 with register prefetch (R14). Pool-score path stays fp32.
template <int ACT>
__global__ void rmm64(const float* __restrict__ A, const float* __restrict__ B,
                      const float* __restrict__ bias, float* __restrict__ C,
                      int M, int N, int K, int CS, int CO) {
  __shared__ float As[64][17];
  __shared__ float Bs[16][64];
  int t  = threadIdx.x;
  int tx = t & 15, ty = t >> 4;
  int bm = blockIdx.y * 64, bn = blockIdx.x * 64;
  float ra[4], rb[4];
#pragma unroll
  for (int i = 0; i < 4; i++) {
    int l = t + i * 256;
    int gr = bm + (l >> 4);
    ra[i] = (gr < M) ? A[(size_t)gr * K + (l & 15)] : 0.f;
    int gc = bn + (l & 63);
    rb[i] = (gc < N) ? B[(size_t)(l >> 6) * N + gc] : 0.f;
  }
  float acc[4][4] = {};
  for (int kt = 0; kt < K; kt += 16) {
#pragma unroll
    for (int i = 0; i < 4; i++) {
      int l = t + i * 256;
      As[l >> 4][l & 15] = ra[i];
      Bs[l >> 6][l & 63] = rb[i];
    }
    __syncthreads();
    int kn = kt + 16;
    if (kn < K) {
#pragma unroll
      for (int i = 0; i < 4; i++) {
        int l = t + i * 256;
        int gr = bm + (l >> 4);
        ra[i] = (gr < M) ? A[(size_t)gr * K + kn + (l & 15)] : 0.f;
        int gc = bn + (l & 63);
        rb[i] = (gc < N) ? B[(size_t)(kn + (l >> 6)) * N + gc] : 0.f;
      }
    }
#pragma unroll
    for (int kk = 0; kk < 16; kk++) {
      float a[4], b[4];
#pragma unroll
      for (int i = 0; i < 4; i++) a[i] = As[ty + 16 * i][kk];
#pragma unroll
      for (int j = 0; j < 4; j++) b[j] = Bs[kk][tx + 16 * j];
#pragma unroll
      for (int i = 0; i < 4; i++)
#pragma unroll
        for (int j = 0; j < 4; j++) acc[i][j] += a[i] * b[j];
    }
    __syncthreads();
  }
#pragma unroll
  for (int i = 0; i < 4; i++) {
    int r = bm + ty + 16 * i;
    if (r >= M) continue;
#pragma unroll
    for (int j = 0; j < 4; j++) {
      int c = bn + tx + 16 * j;
      if (c >= N) continue;
      float v = acc[i][j] + (bias ? bias[c] : 0.f);
      if (ACT == 1) v = fmaxf(v, 0.f);
      C[((size_t)r * N + c) * CS + CO] = v;
    }
  }
}

// Dual rmm64 (blockIdx.z selects operand set), with prefetch.
template <int ACT>
__global__ void rmm64_dual(const float* __restrict__ A0, const float* __restrict__ A1,
                           const float* __restrict__ B0, const float* __restrict__ B1,
                           const float* __restrict__ b0, const float* __restrict__ b1,
                           float* __restrict__ C0, float* __restrict__ C1,
                           int M, int N, int K, int CS) {
  const float* A = blockIdx.z ? A1 : A0;
  const float* B = blockIdx.z ? B1 : B0;
  const float* bias = blockIdx.z ? b1 : b0;
  float* C = blockIdx.z ? C1 : C0;
  __shared__ float As[64][17];
  __shared__ float Bs[16][64];
  int t  = threadIdx.x;
  int tx = t & 15, ty = t >> 4;
  int bm = blockIdx.y * 64, bn = blockIdx.x * 64;
  float ra[4], rb[4];
#pragma unroll
  for (int i = 0; i < 4; i++) {
    int l = t + i * 256;
    int gr = bm + (l >> 4);
    ra[i] = (gr < M) ? A[(size_t)gr * K + (l & 15)] : 0.f;
    int gc = bn + (l & 63);
    rb[i] = (gc < N) ? B[(size_t)(l >> 6) * N + gc] : 0.f;
  }
  float acc[4][4] = {};
  for (int kt = 0; kt < K; kt += 16) {
#pragma unroll
    for (int i = 0; i < 4; i++) {
      int l = t + i * 256;
      As[l >> 4][l & 15] = ra[i];
      Bs[l >> 6][l & 63] = rb[i];
    }
    __syncthreads();
    int kn = kt + 16;
    if (kn < K) {
#pragma unroll
      for (int i = 0; i < 4; i++) {
        int l = t + i * 256;
        int gr = bm + (l >> 4);
        ra[i] = (gr < M) ? A[(size_t)gr * K + kn + (l & 15)] : 0.f;
        int gc = bn + (l & 63);
        rb[i] = (gc < N) ? B[(size_t)(kn + (l >> 6)) * N + gc] : 0.f;
      }
    }
#pragma unroll
    for (int kk = 0; kk < 16; kk++) {
      float a[4], b[4];
#pragma unroll
      for (int i = 0; i < 4; i++) a[i] = As[ty + 16 * i][kk];
#pragma unroll
      for (int j = 0; j < 4; j++) b[j] = Bs[kk][tx + 16 * j];
#pragma unroll
      for (int i = 0; i < 4; i++)
#pragma unroll
        for (int j = 0; j < 4; j++) acc[i][j] += a[i] * b[j];
    }
    __syncthreads();
  }
#pragma unroll
  for (int i = 0; i < 4; i++) {
    int r = bm + ty + 16 * i;
    if (r >= M) continue;
#pragma unroll
    for (int j = 0; j < 4; j++) {
      int c = bn + tx + 16 * j;
      if (c >= N) continue;
      float v = acc[i][j] + (bias ? bias[c] : 0.f);
      if (ACT == 1) v = fmaxf(v, 0.f);
      C[((size_t)r * N + c) * CS] = v;
    }
  }
}

// Transposed split: out[n*ld + k] = split(in[k][n]); tiled via LDS.
__global__ void split_planesT(const float2* __restrict__ in, int inM, int inN,
                              unsigned short* __restrict__ out, int padR, int ld,
                              size_t ps) {
  __shared__ float2 tile[32][33];
  int tx = threadIdx.x & 31, ty = threadIdx.x >> 5;
  int k0 = blockIdx.x * 32, n0 = blockIdx.y * 32;
  for (int i = ty; i < 32; i += 8) {
    int k = k0 + i, n = n0 + tx;
    tile[i][tx] = (k < inM && n < inN) ? in[(size_t)k * inN + n]
                                       : make_float2(0.f, 0.f);
  }
  __syncthreads();
  for (int i = ty; i < 32; i += 8) {
    int n = n0 + i, k = k0 + tx;
    if (n < padR && k < ld)
      split4(tile[tx][i].x, tile[tx][i].y, out, ps, (size_t)n * ld + k);
  }
}

// Transposed split from two real fp32 matrices (re, im).
__global__ void split_planesT2(const float* __restrict__ re, const float* __restrict__ im,
                               int inM, int inN, unsigned short* __restrict__ out,
                               int padR, int ld, size_t ps) {
  __shared__ float2 tile[32][33];
  int tx = threadIdx.x & 31, ty = threadIdx.x >> 5;
  int k0 = blockIdx.x * 32, n0 = blockIdx.y * 32;
  for (int i = ty; i < 32; i += 8) {
    int k = k0 + i, n = n0 + tx;
    tile[i][tx] = (k < inM && n < inN)
        ? make_float2(re[(size_t)k * inN + n], im[(size_t)k * inN + n])
        : make_float2(0.f, 0.f);
  }
  __syncthreads();
  for (int i = ty; i < 32; i += 8) {
    int n = n0 + i, k = k0 + tx;
    if (n < padR && k < ld)
      split4(tile[tx][i].x, tile[tx][i].y, out, ps, (size_t)n * ld + k);
  }
}

// Split-K complex MFMA GEMM with register double-buffer prefetch.
__global__ __launch_bounds__(256, 2) void cmm_bf16_sk(
    const unsigned short* __restrict__ SA, size_t psA, int ldA,
    const unsigned short* __restrict__ ST, size_t psT, int ldT,
    float2* __restrict__ Part, int M, int N, int Kp, int chunk,
    const int* __restrict__ gate, int slot) {
  if (gate && slot >= *gate - 1) return;
  int k0 = blockIdx.x * chunk;
  int kend = min(Kp, k0 + chunk);
  int t = threadIdx.x;
  int wave = t >> 6, lane = t & 63;
  int quad = lane >> 4, mn = lane & 15;
  int rowA = blockIdx.z * 64 + wave * 16 + mn;
  int bn = blockIdx.y * 64;
  const unsigned short* a0 = SA + (size_t)rowA * ldA;
  f4v accR[4], accI[4];
#pragma unroll
  for (int i = 0; i < 4; i++) {
    accR[i] = (f4v){0.f, 0.f, 0.f, 0.f};
    accI[i] = (f4v){0.f, 0.f, 0.f, 0.f};
  }
  s8v cA[4], cB[4][4], nA[4], nB[4][4];
  {
    int ka = k0 + quad * 8;
#pragma unroll
    for (int p = 0; p < 4; p++) cA[p] = *(const s8v*)(a0 + p * psA + ka);
#pragma unroll
    for (int tl = 0; tl < 4; tl++) {
      const unsigned short* b0 = ST + (size_t)(bn + tl * 16 + mn) * ldT + ka;
#pragma unroll
      for (int p = 0; p < 4; p++) cB[tl][p] = *(const s8v*)(b0 + p * psT);
    }
  }
  for (int kt = k0; kt < kend; kt += 32) {
    int kn = kt + 32;
    if (kn < kend) {
      int ka = kn + quad * 8;
#pragma unroll
      for (int p = 0; p < 4; p++) nA[p] = *(const s8v*)(a0 + p * psA + ka);
#pragma unroll
      for (int tl = 0; tl < 4; tl++) {
        const unsigned short* b0 = ST + (size_t)(bn + tl * 16 + mn) * ldT + ka;
#pragma unroll
        for (int p = 0; p < 4; p++) nB[tl][p] = *(const s8v*)(b0 + p * psT);
      }
    }
    s8v nih, nil_;
#pragma unroll
    for (int q = 0; q < 8; q++) {
      nih[q]  = (short)(cA[2][q] ^ (short)0x8000);
      nil_[q] = (short)(cA[3][q] ^ (short)0x8000);
    }
#pragma unroll
    for (int tl = 0; tl < 4; tl++) {
      f4v r = accR[tl];
      r = __builtin_amdgcn_mfma_f32_16x16x32_bf16(cA[0], cB[tl][0], r, 0, 0, 0);
      r = __builtin_amdgcn_mfma_f32_16x16x32_bf16(cA[1], cB[tl][0], r, 0, 0, 0);
      r = __builtin_amdgcn_mfma_f32_16x16x32_bf16(cA[0], cB[tl][1], r, 0, 0, 0);
      r = __builtin_amdgcn_mfma_f32_16x16x32_bf16(nih, cB[tl][2], r, 0, 0, 0);
      r = __builtin_amdgcn_mfma_f32_16x16x32_bf16(nil_, cB[tl][2], r, 0, 0, 0);
      r = __builtin_amdgcn_mfma_f32_16x16x32_bf16(nih, cB[tl][3], r, 0, 0, 0);
      accR[tl] = r;
      f4v im = accI[tl];
      im = __builtin_amdgcn_mfma_f32_16x16x32_bf16(cA[0], cB[tl][2], im, 0, 0, 0);
      im = __builtin_amdgcn_mfma_f32_16x16x32_bf16(cA[1], cB[tl][2], im, 0, 0, 0);
      im = __builtin_amdgcn_mfma_f32_16x16x32_bf16(cA[0], cB[tl][3], im, 0, 0, 0);
      im = __builtin_amdgcn_mfma_f32_16x16x32_bf16(cA[2], cB[tl][0], im, 0, 0, 0);
      im = __builtin_amdgcn_mfma_f32_16x16x32_bf16(cA[3], cB[tl][0], im, 0, 0, 0);
      im = __builtin_amdgcn_mfma_f32_16x16x32_bf16(cA[2], cB[tl][1], im, 0, 0, 0);
      accI[tl] = im;
    }
    if (kn < kend) {
#pragma unroll
      for (int p = 0; p < 4; p++) cA[p] = nA[p];
#pragma unroll
      for (int tl = 0; tl < 4; tl++)
#pragma unroll
        for (int p = 0; p < 4; p++) cB[tl][p] = nB[tl][p];
    }
  }
  float2* P = Part + (size_t)blockIdx.x * M * N;
#pragma unroll
  for (int tl = 0; tl < 4; tl++) {
    int col = bn + tl * 16 + mn;
    if (col >= N) continue;
#pragma unroll
    for (int r = 0; r < 4; r++) {
      int row = blockIdx.z * 64 + wave * 16 + quad * 4 + r;
      if (row >= M) continue;
      P[(size_t)row * N + col] = make_float2(accR[tl][r], accI[tl][r]);
    }
  }
}

// Plain reduce: C = sum_z Part[z].
__global__ void creduce(const float2* __restrict__ Part, float2* __restrict__ C,
                        int MN, int N, int S, float e0,
                        const float2* __restrict__ E1, float e1,
                        const float2* __restrict__ E2, float e2) {
  int idx = blockIdx.x * 256 + threadIdx.x;
  if (idx >= MN) return;
  float sr = 0.f, si = 0.f;
  for (int z = 0; z < S; z++) {
    float2 p = Part[(size_t)z * MN + idx];
    sr += p.x;
    si += p.y;
  }
  if (e0 != 0.f) {
    int r = idx / N;
    if (idx - r * N == r) sr += e0;
  }
  if (E1) { float2 b = E1[idx]; sr += e1 * b.x; si += e1 * b.y; }
  if (E2) { float2 b = E2[idx]; sr += e2 * b.x; si += e2 * b.y; }
  C[idx] = make_float2(sr, si);
}

// Tiled fused reduce: sum_z Part + epilogue -> optional fp32 C, SA planes,
// transposed ST planes. Gated (inactive slot preserves SA).
template <int WC_, int WSA, int WST>
__global__ void creduce_tiled(const float2* __restrict__ Part, int S, int M, int N,
                              int RP, int CP, float2* __restrict__ C,
                              unsigned short* __restrict__ SAp, size_t psA,
                              unsigned short* __restrict__ STp, size_t psT,
                              float e0, const float2* __restrict__ E1, float e1,
                              const float2* __restrict__ E2, float e2,
                              const int* __restrict__ gate, int slot) {
  if (gate && slot >= *gate - 1) return;
  __shared__ float vr[32][33], vi[32][33];
  int tx = threadIdx.x & 31, ty = threadIdx.x >> 5;
  int r0 = blockIdx.y * 32, c0 = blockIdx.x * 32;
  size_t MN = (size_t)M * N;
  for (int i = ty; i < 32; i += 8) {
    int r = r0 + i, c = c0 + tx;
    float sr = 0.f, si = 0.f;
    if (r < M && c < N) {
      size_t o = (size_t)r * N + c;
      for (int z = 0; z < S; z++) {
        float2 p = Part[z * MN + o];
        sr += p.x;
        si += p.y;
      }
      if (e0 != 0.f && r == c) sr += e0;
      if (E1) { float2 b = E1[o]; sr += e1 * b.x; si += e1 * b.y; }
      if (E2) { float2 b = E2[o]; sr += e2 * b.x; si += e2 * b.y; }
      if (WC_) C[o] = make_float2(sr, si);
    }
    if (WSA) split4(sr, si, SAp, psA, (size_t)r * CP + c);
    if (WST) { vr[i][tx] = sr; vi[i][tx] = si; }
  }
  if (WST) {
    __syncthreads();
    for (int i = ty; i < 32; i += 8) {
      int c = c0 + i, r = r0 + tx;
      split4(vr[tx][i], vi[tx][i], STp, psT, (size_t)c * RP + r);
    }
  }
}

// Fused build_B + split + splitT; runtime scale.
__global__ void build_B_split(const float* __restrict__ pm, int n,
                              const float* __restrict__ scale_p,
                              float2* __restrict__ BM,
                              unsigned short* __restrict__ SAp,
                              unsigned short* __restrict__ STp, size_t ps,
                              int RP, int CP) {
  __shared__ float vr[32][33], vi[32][33];
  float scale = scale_p[0];
  int tx = threadIdx.x & 31, ty = threadIdx.x >> 5;
  int r0 = blockIdx.y * 32, c0 = blockIdx.x * 32;
  for (int i = ty; i < 32; i += 8) {
    int r = r0 + i, c = c0 + tx;
    float sr = 0.f, si = 0.f;
    if (r < n && c < n) {
      float pij = pm[(size_t)r * n + c];
      float pji = pm[(size_t)c * n + r];
      sr = scale * (pij - pji);
      si = scale * (pij + pji);
      BM[(size_t)r * n + c] = make_float2(sr, si);
    }
    split4(sr, si, SAp, ps, (size_t)r * CP + c);
    vr[i][tx] = sr;
    vi[i][tx] = si;
  }
  __syncthreads();
  for (int i = ty; i < 32; i += 8) {
    int c = c0 + i, r = r0 + tx;
    split4(vr[tx][i], vi[tx][i], STp, ps, (size_t)c * RP + r);
  }
}

// ||A||_1 rows + fused finalize (R15): last finishing block computes
// s = clamp(ceil(log2(||A||_1/1.4)),1,5) and scale = 0.025*2^-s.
__global__ void anorm_rows(const float* __restrict__ pm, int n,
                           int* __restrict__ anrm, int* __restrict__ done,
                           int* __restrict__ sdev, float* __restrict__ scale) {
  int i = blockIdx.x;
  __shared__ float red[256];
  float s = 0.f;
  for (int j = threadIdx.x; j < n; j += 256) {
    float pij = pm[(size_t)i * n + j];
    float pji = pm[(size_t)j * n + i];
    float a = pij - pji, b = pij + pji;
    s += sqrtf(a * a + b * b);
  }
  red[threadIdx.x] = s;
  __syncthreads();
  for (int off = 128; off > 0; off >>= 1) {
    if (threadIdx.x < off) red[threadIdx.x] += red[threadIdx.x + off];
    __syncthreads();
  }
  if (threadIdx.x == 0) {
    atomicMax(anrm, __float_as_int(red[0] * 0.025f));
    __threadfence();
    int d = atomicAdd(done, 1);
    if (d == gridDim.x - 1) {
      float a = __int_as_float(atomicMax(anrm, 0));  // atomic read (>=0)
      int sq = (int)ceilf(log2f(fmaxf(a, 1e-20f) / 1.4f));
      sq = min(max(sq, 1), SQ_SLOTS + 1);
      *sdev = sq;
      *scale = 0.025f * exp2f(-(float)sq);
    }
  }
}

// D3 = c9*I + c10*B + c11*B2 -> SA planes only.
__global__ void combo3_planes(const float2* __restrict__ Bp, const float2* __restrict__ B2p,
                              unsigned short* __restrict__ planes, size_t ps,
                              int M, int N, int padR, int ld,
                              float e0, float e1, float e2) {
  int idx = blockIdx.x * 256 + threadIdx.x;
  if (idx >= padR * ld) return;
  int r = idx / ld, c = idx - r * ld;
  float sr = 0.f, si = 0.f;
  if (r < M && c < N) {
    size_t o = (size_t)r * N + c;
    float2 b = Bp[o], b2 = B2p[o];
    sr = e1 * b.x + e2 * b2.x;
    si = e1 * b.y + e2 * b2.y;
    if (r == c) sr += e0;
  }
  split4(sr, si, planes, ps, idx);
}

// ---- CSR build ----
__global__ void hist_edges(const int* __restrict__ dst, const float* __restrict__ em,
                           int* __restrict__ cnt) {
  int e = blockIdx.x * 256 + threadIdx.x;
  if (e >= E) return;
  float m = em ? em[e] : 1.0f;
  if (m != 0.f) atomicAdd(&cnt[dst[e]], 1);
}

__global__ __launch_bounds__(1024) void scan_offsets(const int* __restrict__ cnt, int n,
                                                     int* __restrict__ off,
                                                     int* __restrict__ cur,
                                                     float* __restrict__ dis) {
  __shared__ int sums[1024];
  int t = threadIdx.x;
  int base = t * 4;
  int v[4];
  int s = 0;
#pragma unroll
  for (int j = 0; j < 4; j++) {
    int i = base + j;
    int ci = (i < n) ? cnt[i] : 0;
    if (i < n) dis[i] = 1.0f / sqrtf((float)ci + 1.0f);
    v[j] = s;
    s += ci;
  }
  sums[t] = s;
  __syncthreads();
  for (int d = 1; d < 1024; d <<= 1) {
    int x = (t >= d) ? sums[t - d] : 0;
    __syncthreads();
    sums[t] += x;
    __syncthreads();
  }
  int pre = (t > 0) ? sums[t - 1] : 0;
#pragma unroll
  for (int j = 0; j < 4; j++) {
    int i = base + j;
    if (i < n) { int o = pre + v[j]; off[i] = o; cur[i] = o; }
  }
  if (t == 1023) off[n] = sums[1023];
}

__global__ void fill_edges(const int* __restrict__ src, const int* __restrict__ dst,
                           const float* __restrict__ em, const float* __restrict__ dis,
                           int* __restrict__ cur, int* __restrict__ esrc,
                           float* __restrict__ ecoef) {
  int e = blockIdx.x * 256 + threadIdx.x;
  if (e >= E) return;
  float m = em ? em[e] : 1.0f;
  if (m == 0.f) return;
  int s = src[e], d = dst[e];
  int pos = atomicAdd(&cur[d], 1);
  esrc[pos] = s;
  ecoef[pos] = dis[s] * dis[d];
}

// Fused GCN aggregate + self-loop + bias (+relu) (+pool score, R15).
// SCORE=1: per-row dot with w reduced in-block (bit-identical tree to the
// old rowdot: red[tid] = acc*w[f], same 256-wide halving); extra block i==M
// computes ||w|| into normout.
template <int ACT, int SCORE>
__global__ void gcn_gather(const int* __restrict__ off, const int* __restrict__ esrc,
                           const float* __restrict__ ecoef, const float* __restrict__ Hm,
                           const float* __restrict__ dis, const float* __restrict__ bias,
                           float* __restrict__ out, int F, int M,
                           const float* __restrict__ w, float* __restrict__ score,
                           float* __restrict__ normout) {
  __shared__ float red[256];
  int i = blockIdx.x;
  if (SCORE && i == M) {
    float s = 0.f;
    for (int k = threadIdx.x; k < F; k += 256) s += w[k] * w[k];
    red[threadIdx.x] = s;
    __syncthreads();
    for (int o = 128; o > 0; o >>= 1) {
      if (threadIdx.x < o) red[threadIdx.x] += red[threadIdx.x + o];
      __syncthreads();
    }
    if (threadIdx.x == 0) normout[0] = sqrtf(red[0]);
    return;
  }
  int e0 = off[i], e1 = off[i + 1];
  float d2 = dis[i] * dis[i];
  float sdot = 0.f;
  for (int f = threadIdx.x; f < F; f += blockDim.x) {
    float acc = d2 * Hm[(size_t)i * F + f] + bias[f];
    for (int e = e0; e < e1; e++)
      acc += ecoef[e] * Hm[(size_t)esrc[e] * F + f];
    if (ACT == 1) acc = fmaxf(acc, 0.f);
    out[(size_t)i * F + f] = acc;
    if (SCORE) sdot += acc * w[f];
  }
  if (SCORE) {
    red[threadIdx.x] = sdot;
    __syncthreads();
    for (int o = 128; o > 0; o >>= 1) {
      if (threadIdx.x < o) red[threadIdx.x] += red[threadIdx.x + o];
      __syncthreads();
    }
    if (threadIdx.x == 0) score[i] = red[0];
  }
}

__global__ void enc1_fused(const int* __restrict__ off, const float* __restrict__ ecoef,
                           const float* __restrict__ dis, const float* __restrict__ w,
                           const float* __restrict__ b, float* __restrict__ xg1) {
  int i = blockIdx.x;
  int lane = threadIdx.x;
  float s = 0.f;
  for (int e = off[i] + lane; e < off[i + 1]; e += 64) s += ecoef[e];
#pragma unroll
  for (int d = 32; d > 0; d >>= 1) s += __shfl_xor(s, d, 64);
  float sc = s + dis[i] * dis[i];
  xg1[(size_t)i * UHD + lane] = fmaxf(sc * w[lane] + b[lane], 0.f);
}

__global__ void agg_gather_split(const int* __restrict__ off, const int* __restrict__ esrc,
                                 const float2* __restrict__ evo,
                                 unsigned short* __restrict__ planes, size_t ps,
                                 int F, int M) {
  int i = blockIdx.x;
  if (i >= M) {
    for (int f = threadIdx.x; f < F; f += blockDim.x)
      split4(0.f, 0.f, planes, ps, (size_t)i * F + f);
    return;
  }
  int e0 = off[i], e1 = off[i + 1];
  for (int f = threadIdx.x; f < F; f += blockDim.x) {
    float sr = 0.f, si = 0.f;
    for (int e = e0; e < e1; e++) {
      float2 v = evo[(size_t)esrc[e] * F + f];
      sr += v.x;
      si += v.y;
    }
    split4(sr, si, planes, ps, (size_t)i * F + f);
  }
}

__global__ __launch_bounds__(1024) void bitonic_topk(const float* __restrict__ score,
                                                     int n, int* __restrict__ perm, int k,
                                                     int* __restrict__ map,
                                                     int* __restrict__ cntz, int ncnt) {
  __shared__ unsigned long long keys[4096];
  int t = threadIdx.x;
  for (int i = t; i < 4096; i += 1024) {
    unsigned long long kk = 0ull;
    if (i < n) {
      float f = score[i];
      unsigned u = __float_as_uint(f);
      u = (f >= 0.0f) ? (u | 0x80000000u) : ~u;
      kk = ((unsigned long long)u << 32) | (unsigned)(~(unsigned)i);
    }
    keys[i] = kk;
  }
  __syncthreads();
  for (int size = 2; size <= 4096; size <<= 1) {
    for (int stride = size >> 1; stride > 0; stride >>= 1) {
      for (int i = t; i < 2048; i += 1024) {
        int pos = ((i & ~(stride - 1)) << 1) | (i & (stride - 1));
        int partner = pos + stride;
        bool desc = (pos & size) == 0;
        unsigned long long a = keys[pos], b = keys[partner];
        if ((a < b) == desc) { keys[pos] = b; keys[partner] = a; }
      }
      __syncthreads();
    }
  }
  for (int i = t; i < 4096; i += 1024) {
    int idx = (int)(~(unsigned)(keys[i] & 0xFFFFFFFFull));
    if (idx >= 0) map[idx] = (i < k) ? i : -1;
    if (i < k) perm[i] = idx;
  }
  for (int i = t; i < ncnt; i += 1024) cntz[i] = 0;
}

// Fused pool_gather + remap + histogram (R15): blocks [0,k) gather pooled
// rows; blocks [k, k+E/256) remap edges + histogram (cnt pre-zeroed by sort).
__global__ void pool_remap(const float* __restrict__ X, const int* __restrict__ perm,
                           const float* __restrict__ dot, const float* __restrict__ normbuf,
                           float* __restrict__ Xn, int F, int k,
                           const int* __restrict__ srcIn, const int* __restrict__ dstIn,
                           const float* __restrict__ emIn, const int* __restrict__ map,
                           int* __restrict__ srcOut, int* __restrict__ dstOut,
                           float* __restrict__ emOut, int* __restrict__ cnt) {
  int b = blockIdx.x;
  if (b < k) {
    int p = perm[b];
    float sc = tanhf(dot[p] / normbuf[0]);
    for (int f = threadIdx.x; f < F; f += blockDim.x)
      Xn[(size_t)b * F + f] = X[(size_t)p * F + f] * sc;
  } else {
    int e = (b - k) * 256 + threadIdx.x;
    if (e >= E) return;
    int ns = map[srcIn[e]], nd = map[dstIn[e]];
    float m = emIn ? emIn[e] : 1.0f;
    if (ns < 0 || nd < 0) m = 0.f;
    srcOut[e] = ns < 0 ? 0 : ns;
    dstOut[e] = nd < 0 ? 0 : nd;
    emOut[e] = m;
    if (m != 0.f) atomicAdd(&cnt[nd], 1);
  }
}

__global__ void col_mean(const float* __restrict__ X, float* __restrict__ out,
                         int rows, int cols) {
  int c = blockIdx.x;
  __shared__ float red[256];
  float s = 0.f;
  for (int r = threadIdx.x; r < rows; r += 256) s += X[(size_t)r * cols + c];
  red[threadIdx.x] = s;
  __syncthreads();
  for (int off = 128; off > 0; off >>= 1) {
    if (threadIdx.x < off) red[threadIdx.x] += red[threadIdx.x + off];
    __syncthreads();
  }
  if (threadIdx.x == 0) out[c] = red[0] / (float)rows;
}

// magph + col_means reading split-K PART directly (folds AGG1 reduce).
__global__ void magph_mean_part(const float2* __restrict__ Part, int S,
                                const float* __restrict__ xr,
                                const float* __restrict__ xi,
                                float* __restrict__ gm, float* __restrict__ gp,
                                int rows, int cols) {
  int c = blockIdx.x;
  __shared__ float rm[256], rp[256];
  size_t MN = (size_t)rows * cols;
  float sm = 0.f, sp = 0.f;
  for (int r = threadIdx.x; r < rows; r += 256) {
    size_t o = (size_t)r * cols + c;
    float re = xr[o], im = xi[o];
    for (int z = 0; z < S; z++) {
      float2 p = Part[z * MN + o];
      re += p.x;
      im += p.y;
    }
    sm += sqrtf(re * re + im * im);
    sp += atan2f(im, re);
  }
  rm[threadIdx.x] = sm;
  rp[threadIdx.x] = sp;
  __syncthreads();
  for (int off = 128; off > 0; off >>= 1) {
    if (threadIdx.x < off) {
      rm[threadIdx.x] += rm[threadIdx.x + off];
      rp[threadIdx.x] += rp[threadIdx.x + off];
    }
    __syncthreads();
  }
  if (threadIdx.x == 0) {
    gm[c] = rm[0] / (float)rows;
    gp[c] = rp[0] / (float)rows;
  }
}

// Fused p1+p2 MLP (two tiny vec-mats, one block; R15).
__global__ void vecmat2(const float* __restrict__ v,
                        const float* __restrict__ W1, const float* __restrict__ b1,
                        const float* __restrict__ W2, const float* __restrict__ b2,
                        float* __restrict__ T2out) {
  __shared__ float vs[64], t1[64];
  int t = threadIdx.x;
  if (t < 64) vs[t] = v[t];
  __syncthreads();
  if (t < 64) {
    float acc = b1[t];
    for (int k = 0; k < 64; k++) acc += vs[k] * W1[(size_t)k * 64 + t];
    t1[t] = fmaxf(acc, 0.f);
  }
  __syncthreads();
  if (t < 32) {
    float acc = b2[t];
    for (int k = 0; k < 64; k++) acc += t1[k] * W2[(size_t)k * 32 + t];
    T2out[t] = fmaxf(acc, 0.f);
  }
}

// vec @ mat tanh; block 0 thread 0 inits ANRM and DONE (runs fully before
// anorm_rows starts).
__global__ void vecmat_tanh_wide(const float* __restrict__ v, const float* __restrict__ W,
                                 const float* __restrict__ b, float* __restrict__ out,
                                 int Kdim, int Ndim, int* __restrict__ anrm_init,
                                 int* __restrict__ done_init) {
  __shared__ float vs[64];
  if (threadIdx.x < Kdim) vs[threadIdx.x] = v[threadIdx.x];
  if (blockIdx.x == 0 && threadIdx.x == 0) { *anrm_init = 0; *done_init = 0; }
  __syncthreads();
  int j = blockIdx.x * 256 + threadIdx.x;
  if (j >= Ndim) return;
  float acc = b[j];
  for (int k = 0; k < Kdim; k++) acc += vs[k] * W[(size_t)k * Ndim + j];
  out[j] = tanhf(acc);
}

__global__ __launch_bounds__(256) void heads_fused(
    const float* __restrict__ GM, const float* __restrict__ GP,
    const float* __restrict__ mc1_w, const float* __restrict__ mc1_b,
    const float* __restrict__ mc2_w, const float* __restrict__ mc2_b,
    const float* __restrict__ pc1_w, const float* __restrict__ pc1_b,
    const float* __restrict__ pc2_w, const float* __restrict__ pc2_b,
    float* __restrict__ out) {
  __shared__ float g[256], h[128], acc[NC];
  int t = threadIdx.x;
  if (t < NC) acc[t] = 0.f;
  for (int pass = 0; pass < 2; pass++) {
    const float* gv = pass ? GP : GM;
    const float* w1 = pass ? pc1_w : mc1_w;
    const float* b1 = pass ? pc1_b : mc1_b;
    const float* w2 = pass ? pc2_w : mc2_w;
    const float* b2 = pass ? pc2_b : mc2_b;
    g[t] = gv[t];
    __syncthreads();
    if (t < 128) {
      float s = b1[t];
      for (int k = 0; k < 256; k++) s += g[k] * w1[(size_t)k * 128 + t];
      h[t] = fmaxf(s, 0.f);
    }
    __syncthreads();
    if (t < NC) {
      float s = b2[t];
      for (int k = 0; k < 128; k++) s += h[k] * w2[(size_t)k * NC + t];
      acc[t] += s;
    }
    __syncthreads();
  }
  if (t < NC) out[t] = acc[t];
}

// ---------------- host helpers ----------------
static inline int sk_chunk32(int K, int S) { return (((K + S - 1) / S) + 31) & ~31; }

// ---------------- host ----------------
extern "C" void kernel_launch(void* const* d_in, const int* in_sizes, int n_in,
                              void* d_out, int out_size, void* d_ws, size_t ws_size,
                              hipStream_t stream) {
  if (ws_size < WS_TOTAL) return;

  const float* x       = (const float*)d_in[0];
  const int*   ei      = (const int*)d_in[1];
  const float* gcn1_w  = (const float*)d_in[2];
  const float* gcn1_b  = (const float*)d_in[3];
  const float* pool1_w = (const float*)d_in[4];
  const float* gcn2_w  = (const float*)d_in[5];
  const float* gcn2_b  = (const float*)d_in[6];
  const float* pool2_w = (const float*)d_in[7];
  const float* inr_w   = (const float*)d_in[8];
  const float* inr_b   = (const float*)d_in[9];
  const float* ini_w   = (const float*)d_in[10];
  const float* ini_b   = (const float*)d_in[11];
  const float* enc1_w  = (const float*)d_in[12];
  const float* enc1_b  = (const float*)d_in[13];
  const float* enc2_w  = (const float*)d_in[14];
  const float* enc2_b  = (const float*)d_in[15];
  const float* p1_w    = (const float*)d_in[16];
  const float* p1_b    = (const float*)d_in[17];
  const float* p2_w    = (const float*)d_in[18];
  const float* p2_b    = (const float*)d_in[19];
  const float* p3_w    = (const float*)d_in[20];
  const float* p3_b    = (const float*)d_in[21];
  const float* rt_w    = (const float*)d_in[22];
  const float* rt_b    = (const float*)d_in[23];
  const float* it_w    = (const float*)d_in[24];
  const float* it_b    = (const float*)d_in[25];
  const float* msg_wr  = (const float*)d_in[26];
  const float* msg_wi  = (const float*)d_in[27];
  const float* mc1_w   = (const float*)d_in[28];
  const float* mc1_b   = (const float*)d_in[29];
  const float* mc2_w   = (const float*)d_in[30];
  const float* mc2_b   = (const float*)d_in[31];
  const float* pc1_w   = (const float*)d_in[32];
  const float* pc1_b   = (const float*)d_in[33];
  const float* pc2_w   = (const float*)d_in[34];
  const float* pc2_b   = (const float*)d_in[35];

  char* ws = (char*)d_ws;
  float*  H1    = (float*)(ws + O_H1);
  float*  OUT1  = (float*)(ws + O_OUT1);
  int*    CNT1  = (int*)(ws + O_DEG1);
  float*  DIS1  = (float*)(ws + O_DIS1);
  float*  SC1   = (float*)(ws + O_SC1);
  int*    PERM1 = (int*)(ws + O_PERM1);
  int*    MAP1  = (int*)(ws + O_MAP1);
  float*  H1P   = (float*)(ws + O_H1P);
  int*    SRC2  = (int*)(ws + O_SRC2);
  int*    DST2  = (int*)(ws + O_DST2);
  float*  EM2   = (float*)(ws + O_EM2);
  float*  H2    = (float*)(ws + O_H2);
  float*  OUT2  = (float*)(ws + O_OUT2);
  int*    CNT2  = (int*)(ws + O_DEG2);
  float*  DIS2  = (float*)(ws + O_DIS2);
  float*  SC2   = (float*)(ws + O_SC2);
  int*    PERM2 = (int*)(ws + O_PERM2);
  int*    MAP2  = (int*)(ws + O_MAP2);
  float*  H2P   = (float*)(ws + O_H2P);
  int*    SRC3  = (int*)(ws + O_SRC3);
  int*    DST3  = (int*)(ws + O_DST3);
  float*  EM3   = (float*)(ws + O_EM3);
  float*  XRb   = (float*)(ws + O_XR);
  float*  XIb   = (float*)(ws + O_XI);
  int*    CNT3  = (int*)(ws + O_DEG3);
  float*  DIS3  = (float*)(ws + O_DIS3);
  float*  XG1   = (float*)(ws + O_XG1);
  float*  XG2H  = (float*)(ws + O_XG2H);
  float*  XG2   = (float*)(ws + O_XG2);
  float*  EMB   = (float*)(ws + O_EMB);
  float*  T2    = (float*)(ws + O_T2);
  float*  NORM  = (float*)(ws + O_NORM);
  int*    ANRM  = (int*)(NORM + 2);
  int*    SDEV  = (int*)(NORM + 3);
  float*  SCALE = NORM + 4;
  int*    DONE  = (int*)(NORM + 5);
  float*  PMV   = (float*)(ws + O_PM);
  float2* BM    = (float2*)(ws + O_BM);
  float2* XC    = (float2*)(ws + O_XC);
  float2* EVO   = (float2*)(ws + O_EVO);
  float*  GM    = (float*)(ws + O_GM);
  float*  GP    = (float*)(ws + O_GP);
  unsigned short* SA = (unsigned short*)(ws + O_SA);
  unsigned short* ST = (unsigned short*)(ws + O_ST);
  float2* PART  = (float2*)(ws + O_PARTX);
  float2* B2v   = (float2*)(ws + O_B2);
  int*    COFF  = (int*)(ws + O_CSR_OFF);
  int*    CCUR  = (int*)(ws + O_CSR_CUR);
  int*    CSRC  = (int*)(ws + O_CSR_SRC);
  float*  CCOEF = (float*)(ws + O_CSR_CF);

  const int* SRC1 = ei;
  const int* DST1 = ei + E;
  const int eg = E / 256;

  // ---------- Stage A: gcn1 (CSR gather, fused pool1 score) ----------
  rmm64<0><<<dim3(HD / 64, N0 / 64), 256, 0, stream>>>(x, gcn1_w, nullptr, H1, N0, HD, DIN, 1, 0);
  hipMemsetAsync(CNT1, 0, F4(N0), stream);
  hist_edges<<<eg, 256, 0, stream>>>(DST1, nullptr, CNT1);
  scan_offsets<<<1, 1024, 0, stream>>>(CNT1, N0, COFF, CCUR, DIS1);
  fill_edges<<<eg, 256, 0, stream>>>(SRC1, DST1, nullptr, DIS1, CCUR, CSRC, CCOEF);
  gcn_gather<1, 1><<<N0 + 1, 256, 0, stream>>>(COFF, CSRC, CCOEF, H1, DIS1, gcn1_b,
                                               OUT1, HD, N0, pool1_w, SC1, NORM);

  // ---------- pool1 (sort -> fused gather+remap+hist) ----------
  bitonic_topk<<<1, 1024, 0, stream>>>(SC1, N0, PERM1, K1, MAP1, CNT2, K1);
  pool_remap<<<K1 + eg, 256, 0, stream>>>(OUT1, PERM1, SC1, NORM, H1P, HD, K1,
                                          SRC1, DST1, nullptr, MAP1, SRC2, DST2, EM2, CNT2);

  // ---------- Stage C: gcn2 (CSR gather, fused pool2 score) ----------
  rmm64<0><<<dim3(HD / 64, (K1 + 63) / 64), 256, 0, stream>>>(H1P, gcn2_w, nullptr, H2, K1, HD, HD, 1, 0);
  scan_offsets<<<1, 1024, 0, stream>>>(CNT2, K1, COFF, CCUR, DIS2);
  fill_edges<<<eg, 256, 0, stream>>>(SRC2, DST2, EM2, DIS2, CCUR, CSRC, CCOEF);
  gcn_gather<1, 1><<<K1 + 1, 256, 0, stream>>>(COFF, CSRC, CCOEF, H2, DIS2, gcn2_b,
                                               OUT2, HD, K1, pool2_w, SC2, NORM + 1);

  // ---------- pool2 ----------
  bitonic_topk<<<1, 1024, 0, stream>>>(SC2, K1, PERM2, K2, MAP2, CNT3, K2);
  pool_remap<<<K2 + eg, 256, 0, stream>>>(OUT2, PERM2, SC2, NORM + 1, H2P, HD, K2,
                                          SRC2, DST2, EM2, MAP2, SRC3, DST3, EM3, CNT3);

  // ---------- xr / xi (dual GEMM) ----------
  rmm64_dual<0><<<dim3(HD / 64, (K2 + 63) / 64, 2), 256, 0, stream>>>(
      H2P, H2P, inr_w, ini_w, inr_b, ini_b, XRb, XIb, K2, HD, HD, 1);

  // ---------- CSR3 (persists through expm) ----------
  scan_offsets<<<1, 1024, 0, stream>>>(CNT3, K2, COFF, CCUR, DIS3);
  fill_edges<<<eg, 256, 0, stream>>>(SRC3, DST3, EM3, DIS3, CCUR, CSRC, CCOEF);

  // ---------- encoder GCNs on pooled graph ----------
  enc1_fused<<<K2, 64, 0, stream>>>(COFF, CCOEF, DIS3, enc1_w, enc1_b, XG1);
  rmm64<0><<<dim3(UHD / 64, (K2 + 63) / 64), 256, 0, stream>>>(XG1, enc2_w, nullptr, XG2H, K2, UHD, UHD, 1, 0);
  gcn_gather<0, 0><<<K2, 64, 0, stream>>>(COFF, CSRC, CCOEF, XG2H, DIS3, enc2_b,
                                          XG2, UHD, K2, nullptr, nullptr, nullptr);
  col_mean<<<UHD, 256, 0, stream>>>(XG2, EMB, K2, UHD);

  // ---------- parameter MLP -> pm ; runtime squaring count s ----------
  vecmat2<<<1, 64, 0, stream>>>(EMB, p1_w, p1_b, p2_w, p2_b, T2);
  vecmat_tanh_wide<<<(PMN + 255) / 256, 256, 0, stream>>>(T2, p3_w, p3_b, PMV, UHD / 2, PMN, ANRM, DONE);
  anorm_rows<<<K2, 256, 0, stream>>>(PMV, K2, ANRM, DONE, SDEV, SCALE);

  // ---------- expm: PS deg-11 + gated squarings (last folded into EVO) ----
  const int sgrid = (PLD * PLD + 255) / 256;
  const dim3 tg22(PLD / 32, PLD / 32);
  const int chF = sk_chunk32(PLD, CSPLIT);   // 96
  const dim3 gBig(CSPLIT, 11, 11);
  const float c3 = 1.f / 6.f, c4 = 1.f / 24.f, c5 = 1.f / 120.f;
  const float c6 = 1.f / 720.f, c7 = 1.f / 5040.f, c8 = 1.f / 40320.f;
  const float c9 = 1.f / 362880.f, c10 = 1.f / 3628800.f, c11 = 1.f / 39916800.f;

  build_B_split<<<tg22, 256, 0, stream>>>(PMV, K2, SCALE, BM, SA, ST, PPS, PLD, PLD);
  cmm_bf16_sk<<<gBig, 256, 0, stream>>>(SA, PPS, PLD, ST, PPS, PLD, PART, K2, K2, PLD, chF, nullptr, 0);
  creduce_tiled<1, 1, 0><<<tg22, 256, 0, stream>>>(PART, CSPLIT, K2, K2, PLD, PLD,
      B2v, SA, PPS, nullptr, 0, 0.f, nullptr, 0.f, nullptr, 0.f, nullptr, 0);
  cmm_bf16_sk<<<gBig, 256, 0, stream>>>(SA, PPS, PLD, ST, PPS, PLD, PART, K2, K2, PLD, chF, nullptr, 0);
  creduce_tiled<0, 0, 1><<<tg22, 256, 0, stream>>>(PART, CSPLIT, K2, K2, PLD, PLD,
      nullptr, nullptr, 0, ST, PPS, 0.f, nullptr, 0.f, nullptr, 0.f, nullptr, 0);
  combo3_planes<<<sgrid, 256, 0, stream>>>(BM, B2v, SA, PPS, K2, K2, PLD, PLD, c9, c10, c11);
  cmm_bf16_sk<<<gBig, 256, 0, stream>>>(SA, PPS, PLD, ST, PPS, PLD, PART, K2, K2, PLD, chF, nullptr, 0);
  creduce_tiled<0, 1, 0><<<tg22, 256, 0, stream>>>(PART, CSPLIT, K2, K2, PLD, PLD,
      nullptr, SA, PPS, nullptr, 0, c6, BM, c7, B2v, c8, nullptr, 0);
  cmm_bf16_sk<<<gBig, 256, 0, stream>>>(SA, PPS, PLD, ST, PPS, PLD, PART, K2, K2, PLD, chF, nullptr, 0);
  creduce_tiled<0, 1, 0><<<tg22, 256, 0, stream>>>(PART, CSPLIT, K2, K2, PLD, PLD,
      nullptr, SA, PPS, nullptr, 0, c3, BM, c4, B2v, c5, nullptr, 0);
  cmm_bf16_sk<<<gBig, 256, 0, stream>>>(SA, PPS, PLD, ST, PPS, PLD, PART, K2, K2, PLD, chF, nullptr, 0);
  creduce_tiled<0, 1, 1><<<tg22, 256, 0, stream>>>(PART, CSPLIT, K2, K2, PLD, PLD,
      nullptr, SA, PPS, ST, PPS, 1.f, BM, 1.f, B2v, 0.5f, nullptr, 0);
  for (int t = 0; t < SQ_SLOTS; ++t) {
    cmm_bf16_sk<<<gBig, 256, 0, stream>>>(SA, PPS, PLD, ST, PPS, PLD, PART, K2, K2, PLD, chF, SDEV, t);
    creduce_tiled<0, 1, 1><<<tg22, 256, 0, stream>>>(PART, CSPLIT, K2, K2, PLD, PLD,
        nullptr, SA, PPS, ST, PPS, 0.f, nullptr, 0.f, nullptr, 0.f, SDEV, t);
  }
  // SA holds S = U^(1/2) planes.

  // ---------- quantum message passing: EVO = S@(S@XC) ----------
  rmm64_dual<1><<<dim3(HD / 64, (K2 + 63) / 64, 2), 256, 0, stream>>>(
      XRb, XIb, rt_w, it_w, rt_b, it_b, (float*)XC, (float*)XC + 1, K2, HD, HD, 2);
  {
    const int mn = K2 * HD;
    const int rg = (mn + 255) / 256;
    const dim3 gSkin(CSPLIT, HD / 64, 11);
    const size_t psX = (size_t)HD * PLD;
    split_planesT<<<dim3((PLD + 31) / 32, (HD + 31) / 32), 256, 0, stream>>>(
        XC, K2, HD, ST, HD, PLD, psX);
    cmm_bf16_sk<<<gSkin, 256, 0, stream>>>(SA, PPS, PLD, ST, psX, PLD, PART, K2, HD, PLD, chF, nullptr, 0);
    creduce_tiled<0, 0, 1><<<dim3(HD / 32, PLD / 32), 256, 0, stream>>>(
        PART, CSPLIT, K2, HD, PLD, HD, nullptr, nullptr, 0, ST, psX,
        0.f, nullptr, 0.f, nullptr, 0.f, nullptr, 0);
    cmm_bf16_sk<<<gSkin, 256, 0, stream>>>(SA, PPS, PLD, ST, psX, PLD, PART, K2, HD, PLD, chF, nullptr, 0);
    creduce<<<rg, 256, 0, stream>>>(PART, EVO, mn, HD, CSPLIT, 0.f, nullptr, 0.f, nullptr, 0.f);
    const size_t psG = (size_t)PLD * HD;
    agg_gather_split<<<PLD, 256, 0, stream>>>(COFF, CSRC, EVO, SA, psG, HD, K2);
    split_planesT2<<<dim3((HD + 31) / 32, (HD + 31) / 32), 256, 0, stream>>>(
        msg_wr, msg_wi, HD, HD, ST, HD, HD, (size_t)HD * HD);
    cmm_bf16_sk<<<gSkin, 256, 0, stream>>>(SA, psG, HD, ST, (size_t)HD * HD, HD, PART,
                                           K2, HD, HD, sk_chunk32(HD, CSPLIT), nullptr, 0);
    magph_mean_part<<<HD, 256, 0, stream>>>(PART, CSPLIT, XRb, XIb, GM, GP, K2, HD);
  }

  // ---------- fused classifier heads ----------
  heads_fused<<<1, 256, 0, stream>>>(GM, GP, mc1_w, mc1_b, mc2_w, mc2_b,
                                     pc1_w, pc1_b, pc2_w, pc2_b, (float*)d_out);
}

// Round 16
// 730.827 us; speedup vs baseline: 1.2321x; 1.1255x over previous
//
#include <hip/hip_runtime.h>
#include <cstddef>
#include <utility>

// ---------------- problem constants ----------------
constexpr int N0  = 4096;
constexpr int E   = 65536;
constexpr int DIN = 128;
constexpr int HD  = 256;   // H
constexpr int NC  = 10;
constexpr int UHD = 64;    // UH
constexpr int K1  = 3277;  // ceil(0.8*4096)
constexpr int K2  = 656;   // ceil(0.2*3277)
constexpr int PMN = K2 * K2; // 430336

// expm(A): A = 2^s*B, RUNTIME s = clamp(ceil(log2(||A||_1/1.4)),1,5) (R12).
// Deg-11 PS Taylor; s-1 gated squarings; final squaring folded into EVO.
constexpr int SQ_SLOTS = 4;

// MFMA plane geometry: 656 -> padded 704 = 11*64 = 22*32.
constexpr int PLD = 704;
constexpr size_t PPS = (size_t)PLD * PLD;

// Split-K: CSPLIT=8, z = blockIdx.x -> one k-slice per XCD (R8/R9).
constexpr int CSPLIT = 8;

// ---------------- workspace layout ----------------
#define F4(n) ((size_t)(n) * 4)
constexpr size_t O_H1    = 0;
constexpr size_t O_OUT1  = O_H1    + F4(N0 * HD);
constexpr size_t O_DEG1  = O_OUT1  + F4(N0 * HD);
constexpr size_t O_DIS1  = O_DEG1  + F4(N0);
constexpr size_t O_SC1   = O_DIS1  + F4(N0);
constexpr size_t O_PERM1 = O_SC1   + F4(N0);
constexpr size_t O_MAP1  = O_PERM1 + F4(N0);
constexpr size_t O_H1P   = O_MAP1  + F4(N0);
constexpr size_t O_SRC2  = O_H1P   + F4(K1 * HD);
constexpr size_t O_DST2  = O_SRC2  + F4(E);
constexpr size_t O_EM2   = O_DST2  + F4(E);
constexpr size_t O_H2    = O_EM2   + F4(E);
constexpr size_t O_OUT2  = O_H2    + F4(K1 * HD);
constexpr size_t O_DEG2  = O_OUT2  + F4(K1 * HD);
constexpr size_t O_DIS2  = O_DEG2  + F4(N0);
constexpr size_t O_SC2   = O_DIS2  + F4(N0);
constexpr size_t O_PERM2 = O_SC2   + F4(N0);
constexpr size_t O_MAP2  = O_PERM2 + F4(N0);
constexpr size_t O_H2P   = O_MAP2  + F4(N0);
constexpr size_t O_SRC3  = O_H2P   + F4(K2 * HD);
constexpr size_t O_DST3  = O_SRC3  + F4(E);
constexpr size_t O_EM3   = O_DST3  + F4(E);
constexpr size_t O_XR    = O_EM3   + F4(E);
constexpr size_t O_XI    = O_XR    + F4(K2 * HD);
constexpr size_t O_DEG3  = O_XI    + F4(K2 * HD);
constexpr size_t O_DIS3  = O_DEG3  + F4(1024);
constexpr size_t O_SCOEF = O_DIS3  + F4(1024);
constexpr size_t O_XG1   = O_SCOEF + F4(1024);
constexpr size_t O_XG2H  = O_XG1   + F4(K2 * UHD);
constexpr size_t O_XG2   = O_XG2H  + F4(K2 * UHD);
constexpr size_t O_EMB   = O_XG2   + F4(K2 * UHD);
constexpr size_t O_T1    = O_EMB   + F4(64);
constexpr size_t O_T2    = O_T1    + F4(64);
constexpr size_t O_NORM  = O_T2    + F4(64);   // [0..1] pool norms, [2] ANRM,
                                               // [3] S_DEV, [4] SCALE, [5] DONE
constexpr size_t O_PM    = O_NORM  + F4(64);
constexpr size_t O_BM    = O_PM    + F4(PMN);          // float2
constexpr size_t O_P0    = O_BM    + F4(PMN) * 2;      // float2 (unused)
constexpr size_t O_P1    = O_P0    + F4(PMN) * 2;      // float2 (unused)
constexpr size_t O_XRT   = O_P1    + F4(PMN) * 2;
constexpr size_t O_XIT   = O_XRT   + F4(K2 * HD);
constexpr size_t O_XC    = O_XIT   + F4(K2 * HD);      // float2
constexpr size_t O_EVO   = O_XC    + F4(K2 * HD) * 2;  // float2
constexpr size_t O_AGG0  = O_EVO   + F4(K2 * HD) * 2;  // float2
constexpr size_t O_WC    = O_AGG0  + F4(K2 * HD) * 2;  // float2
constexpr size_t O_AGG1  = O_WC    + F4(HD * HD) * 2;  // float2 (unused)
constexpr size_t O_MAG   = O_AGG1  + F4(K2 * HD) * 2;
constexpr size_t O_PH    = O_MAG   + F4(K2 * HD);
constexpr size_t O_GM    = O_PH    + F4(K2 * HD);
constexpr size_t O_GP    = O_GM    + F4(256);
constexpr size_t O_HM    = O_GP    + F4(256);
constexpr size_t O_HP    = O_HM    + F4(256);
constexpr size_t O_LM    = O_HP    + F4(256);
constexpr size_t O_LP    = O_LM    + F4(64);
constexpr size_t WS_NEED = O_LP    + F4(64);

// SA/ST bf16 plane sets in the dead stage-A/B region (below O_SRC3).
constexpr size_t O_SA = 0;
constexpr size_t O_ST = O_SA + PPS * 2 * 4;
static_assert(O_ST + PPS * 2 * 4 <= O_SRC3, "SA/ST must fit in dead region");

// B2 fp32 aliases XRT region (only fp32 PS power re-read as epilogue input).
constexpr size_t O_B2 = O_XRT;
static_assert(O_B2 + F4(PMN) * 2 <= O_MAG, "B2 must fit in XRT..AGG1 region");

// CSR slot in the MAG/PH region.
constexpr size_t O_CSR_OFF = O_MAG;                 // (N0+1) ints
constexpr size_t O_CSR_CUR = O_CSR_OFF + F4(4104);
constexpr size_t O_CSR_SRC = O_CSR_CUR + F4(4104);  // E ints
constexpr size_t O_CSR_CF  = O_CSR_SRC + F4(E);     // E floats
static_assert(O_CSR_CF + F4(E) <= O_GM, "CSR must fit in MAG/PH region");

// Extension region past WS_NEED (harness ws_size ~268 MB; runtime-guarded).
constexpr size_t O_PARTX  = (WS_NEED + 255) & ~(size_t)255;
constexpr size_t PART_SZ  = (size_t)CSPLIT * PMN * 8;   // 27.5 MB
constexpr size_t WS_TOTAL = O_PARTX + PART_SZ;

// ---------------- bf16 helpers ----------------
typedef __attribute__((ext_vector_type(8))) short s8v;
typedef __attribute__((ext_vector_type(4))) float f4v;

__device__ inline unsigned short f2bf(float x) {
  unsigned u = __float_as_uint(x);
  u += 0x7FFFu + ((u >> 16) & 1u);
  return (unsigned short)(u >> 16);
}
__device__ inline float bf2f(unsigned short h) {
  return __uint_as_float(((unsigned)h) << 16);
}
__device__ inline void split4(float re, float im, unsigned short* out,
                              size_t ps, size_t o) {
  unsigned short rh = f2bf(re);
  unsigned short rl = f2bf(re - bf2f(rh));
  unsigned short ih = f2bf(im);
  unsigned short il = f2bf(im - bf2f(ih));
  out[o] = rh; out[ps + o] = rl; out[2 * ps + o] = ih; out[3 * ps + o] = il;
}

// ---------------- kernels ----------------

// real GEMM fp32 with register prefetch (R14). Pool-score path stays fp32.
template <int ACT>
__global__ void rmm64(const float* __restrict__ A, const float* __restrict__ B,
                      const float* __restrict__ bias, float* __restrict__ C,
                      int M, int N, int K, int CS, int CO) {
  __shared__ float As[64][17];
  __shared__ float Bs[16][64];
  int t  = threadIdx.x;
  int tx = t & 15, ty = t >> 4;
  int bm = blockIdx.y * 64, bn = blockIdx.x * 64;
  float ra[4], rb[4];
#pragma unroll
  for (int i = 0; i < 4; i++) {
    int l = t + i * 256;
    int gr = bm + (l >> 4);
    ra[i] = (gr < M) ? A[(size_t)gr * K + (l & 15)] : 0.f;
    int gc = bn + (l & 63);
    rb[i] = (gc < N) ? B[(size_t)(l >> 6) * N + gc] : 0.f;
  }
  float acc[4][4] = {};
  for (int kt = 0; kt < K; kt += 16) {
#pragma unroll
    for (int i = 0; i < 4; i++) {
      int l = t + i * 256;
      As[l >> 4][l & 15] = ra[i];
      Bs[l >> 6][l & 63] = rb[i];
    }
    __syncthreads();
    int kn = kt + 16;
    if (kn < K) {
#pragma unroll
      for (int i = 0; i < 4; i++) {
        int l = t + i * 256;
        int gr = bm + (l >> 4);
        ra[i] = (gr < M) ? A[(size_t)gr * K + kn + (l & 15)] : 0.f;
        int gc = bn + (l & 63);
        rb[i] = (gc < N) ? B[(size_t)(kn + (l >> 6)) * N + gc] : 0.f;
      }
    }
#pragma unroll
    for (int kk = 0; kk < 16; kk++) {
      float a[4], b[4];
#pragma unroll
      for (int i = 0; i < 4; i++) a[i] = As[ty + 16 * i][kk];
#pragma unroll
      for (int j = 0; j < 4; j++) b[j] = Bs[kk][tx + 16 * j];
#pragma unroll
      for (int i = 0; i < 4; i++)
#pragma unroll
        for (int j = 0; j < 4; j++) acc[i][j] += a[i] * b[j];
    }
    __syncthreads();
  }
#pragma unroll
  for (int i = 0; i < 4; i++) {
    int r = bm + ty + 16 * i;
    if (r >= M) continue;
#pragma unroll
    for (int j = 0; j < 4; j++) {
      int c = bn + tx + 16 * j;
      if (c >= N) continue;
      float v = acc[i][j] + (bias ? bias[c] : 0.f);
      if (ACT == 1) v = fmaxf(v, 0.f);
      C[((size_t)r * N + c) * CS + CO] = v;
    }
  }
}

// Dual rmm64 (blockIdx.z selects operand set), with prefetch.
template <int ACT>
__global__ void rmm64_dual(const float* __restrict__ A0, const float* __restrict__ A1,
                           const float* __restrict__ B0, const float* __restrict__ B1,
                           const float* __restrict__ b0, const float* __restrict__ b1,
                           float* __restrict__ C0, float* __restrict__ C1,
                           int M, int N, int K, int CS) {
  const float* A = blockIdx.z ? A1 : A0;
  const float* B = blockIdx.z ? B1 : B0;
  const float* bias = blockIdx.z ? b1 : b0;
  float* C = blockIdx.z ? C1 : C0;
  __shared__ float As[64][17];
  __shared__ float Bs[16][64];
  int t  = threadIdx.x;
  int tx = t & 15, ty = t >> 4;
  int bm = blockIdx.y * 64, bn = blockIdx.x * 64;
  float ra[4], rb[4];
#pragma unroll
  for (int i = 0; i < 4; i++) {
    int l = t + i * 256;
    int gr = bm + (l >> 4);
    ra[i] = (gr < M) ? A[(size_t)gr * K + (l & 15)] : 0.f;
    int gc = bn + (l & 63);
    rb[i] = (gc < N) ? B[(size_t)(l >> 6) * N + gc] : 0.f;
  }
  float acc[4][4] = {};
  for (int kt = 0; kt < K; kt += 16) {
#pragma unroll
    for (int i = 0; i < 4; i++) {
      int l = t + i * 256;
      As[l >> 4][l & 15] = ra[i];
      Bs[l >> 6][l & 63] = rb[i];
    }
    __syncthreads();
    int kn = kt + 16;
    if (kn < K) {
#pragma unroll
      for (int i = 0; i < 4; i++) {
        int l = t + i * 256;
        int gr = bm + (l >> 4);
        ra[i] = (gr < M) ? A[(size_t)gr * K + kn + (l & 15)] : 0.f;
        int gc = bn + (l & 63);
        rb[i] = (gc < N) ? B[(size_t)(kn + (l >> 6)) * N + gc] : 0.f;
      }
    }
#pragma unroll
    for (int kk = 0; kk < 16; kk++) {
      float a[4], b[4];
#pragma unroll
      for (int i = 0; i < 4; i++) a[i] = As[ty + 16 * i][kk];
#pragma unroll
      for (int j = 0; j < 4; j++) b[j] = Bs[kk][tx + 16 * j];
#pragma unroll
      for (int i = 0; i < 4; i++)
#pragma unroll
        for (int j = 0; j < 4; j++) acc[i][j] += a[i] * b[j];
    }
    __syncthreads();
  }
#pragma unroll
  for (int i = 0; i < 4; i++) {
    int r = bm + ty + 16 * i;
    if (r >= M) continue;
#pragma unroll
    for (int j = 0; j < 4; j++) {
      int c = bn + tx + 16 * j;
      if (c >= N) continue;
      float v = acc[i][j] + (bias ? bias[c] : 0.f);
      if (ACT == 1) v = fmaxf(v, 0.f);
      C[((size_t)r * N + c) * CS] = v;
    }
  }
}

// Transposed split: out[n*ld + k] = split(in[k][n]); tiled via LDS.
__global__ void split_planesT(const float2* __restrict__ in, int inM, int inN,
                              unsigned short* __restrict__ out, int padR, int ld,
                              size_t ps) {
  __shared__ float2 tile[32][33];
  int tx = threadIdx.x & 31, ty = threadIdx.x >> 5;
  int k0 = blockIdx.x * 32, n0 = blockIdx.y * 32;
  for (int i = ty; i < 32; i += 8) {
    int k = k0 + i, n = n0 + tx;
    tile[i][tx] = (k < inM && n < inN) ? in[(size_t)k * inN + n]
                                       : make_float2(0.f, 0.f);
  }
  __syncthreads();
  for (int i = ty; i < 32; i += 8) {
    int n = n0 + i, k = k0 + tx;
    if (n < padR && k < ld)
      split4(tile[tx][i].x, tile[tx][i].y, out, ps, (size_t)n * ld + k);
  }
}

// Transposed split from two real fp32 matrices (re, im).
__global__ void split_planesT2(const float* __restrict__ re, const float* __restrict__ im,
                               int inM, int inN, unsigned short* __restrict__ out,
                               int padR, int ld, size_t ps) {
  __shared__ float2 tile[32][33];
  int tx = threadIdx.x & 31, ty = threadIdx.x >> 5;
  int k0 = blockIdx.x * 32, n0 = blockIdx.y * 32;
  for (int i = ty; i < 32; i += 8) {
    int k = k0 + i, n = n0 + tx;
    tile[i][tx] = (k < inM && n < inN)
        ? make_float2(re[(size_t)k * inN + n], im[(size_t)k * inN + n])
        : make_float2(0.f, 0.f);
  }
  __syncthreads();
  for (int i = ty; i < 32; i += 8) {
    int n = n0 + i, k = k0 + tx;
    if (n < padR && k < ld)
      split4(tile[tx][i].x, tile[tx][i].y, out, ps, (size_t)n * ld + k);
  }
}

// Split-K complex MFMA GEMM. R16: B tile staged cooperatively in LDS
// (double-buffered) — all 4 waves read the same 64-col B tile, so one
// 16 KB cooperative load replaces 4x redundant per-wave fragment loads
// (R6: outstanding-load-latency bound). A stays in per-wave register
// prefetch (rows are wave-unique). Fragments read via ds_read_b128 at
// 2-way bank aliasing (free, m136). One barrier per k-iter: a wave only
// reaches iter i's barrier after finishing iter i-1 reads of buf^1, so
// iter i+1 writes to buf^1 are race-free.
__global__ __launch_bounds__(256, 2) void cmm_bf16_sk(
    const unsigned short* __restrict__ SA, size_t psA, int ldA,
    const unsigned short* __restrict__ ST, size_t psT, int ldT,
    float2* __restrict__ Part, int M, int N, int Kp, int chunk,
    const int* __restrict__ gate, int slot) {
  if (gate && slot >= *gate - 1) return;
  __shared__ unsigned short Bl[2][4 * 64 * 32];   // [buf][(p*64+c)*32 + k]
  int k0 = blockIdx.x * chunk;
  int kend = min(Kp, k0 + chunk);
  int t = threadIdx.x;
  int wave = t >> 6, lane = t & 63;
  int quad = lane >> 4, mn = lane & 15;
  int rowA = blockIdx.z * 64 + wave * 16 + mn;
  int bn = blockIdx.y * 64;
  const unsigned short* a0 = SA + (size_t)rowA * ldA;
  // cooperative-B thread mapping: plane pB = t>>6, column cB_ = t&63
  int pB = t >> 6, cB_ = t & 63;
  const unsigned short* bsrc = ST + (size_t)(bn + cB_) * ldT + pB * psT;
  f4v accR[4], accI[4];
#pragma unroll
  for (int i = 0; i < 4; i++) {
    accR[i] = (f4v){0.f, 0.f, 0.f, 0.f};
    accI[i] = (f4v){0.f, 0.f, 0.f, 0.f};
  }
  s8v cA[4], nA[4], rB[4], nB[4];
  {
    int ka = k0 + quad * 8;
#pragma unroll
    for (int p = 0; p < 4; p++) cA[p] = *(const s8v*)(a0 + p * psA + ka);
#pragma unroll
    for (int j = 0; j < 4; j++) rB[j] = *(const s8v*)(bsrc + k0 + j * 8);
  }
  int it = 0;
  for (int kt = k0; kt < kend; kt += 32, ++it) {
    int buf = it & 1;
    // commit staged B regs to LDS
    unsigned short* bl = &Bl[buf][(size_t)t * 32];   // (pB*64+cB_)*32
#pragma unroll
    for (int j = 0; j < 4; j++) *(s8v*)(bl + j * 8) = rB[j];
    __syncthreads();
    int kn = kt + 32;
    if (kn < kend) {   // issue next tile's loads (A regs + B coop)
      int ka = kn + quad * 8;
#pragma unroll
      for (int p = 0; p < 4; p++) nA[p] = *(const s8v*)(a0 + p * psA + ka);
#pragma unroll
      for (int j = 0; j < 4; j++) nB[j] = *(const s8v*)(bsrc + kn + j * 8);
    }
    s8v nih, nil_;
#pragma unroll
    for (int q = 0; q < 8; q++) {
      nih[q]  = (short)(cA[2][q] ^ (short)0x8000);
      nil_[q] = (short)(cA[3][q] ^ (short)0x8000);
    }
#pragma unroll
    for (int tl = 0; tl < 4; tl++) {
      int c = tl * 16 + mn;
      s8v b0 = *(const s8v*)&Bl[buf][(0 * 64 + c) * 32 + quad * 8];
      s8v b1 = *(const s8v*)&Bl[buf][(1 * 64 + c) * 32 + quad * 8];
      s8v b2 = *(const s8v*)&Bl[buf][(2 * 64 + c) * 32 + quad * 8];
      s8v b3 = *(const s8v*)&Bl[buf][(3 * 64 + c) * 32 + quad * 8];
      f4v r = accR[tl];
      r = __builtin_amdgcn_mfma_f32_16x16x32_bf16(cA[0], b0, r, 0, 0, 0);
      r = __builtin_amdgcn_mfma_f32_16x16x32_bf16(cA[1], b0, r, 0, 0, 0);
      r = __builtin_amdgcn_mfma_f32_16x16x32_bf16(cA[0], b1, r, 0, 0, 0);
      r = __builtin_amdgcn_mfma_f32_16x16x32_bf16(nih, b2, r, 0, 0, 0);
      r = __builtin_amdgcn_mfma_f32_16x16x32_bf16(nil_, b2, r, 0, 0, 0);
      r = __builtin_amdgcn_mfma_f32_16x16x32_bf16(nih, b3, r, 0, 0, 0);
      accR[tl] = r;
      f4v im = accI[tl];
      im = __builtin_amdgcn_mfma_f32_16x16x32_bf16(cA[0], b2, im, 0, 0, 0);
      im = __builtin_amdgcn_mfma_f32_16x16x32_bf16(cA[1], b2, im, 0, 0, 0);
      im = __builtin_amdgcn_mfma_f32_16x16x32_bf16(cA[0], b3, im, 0, 0, 0);
      im = __builtin_amdgcn_mfma_f32_16x16x32_bf16(cA[2], b0, im, 0, 0, 0);
      im = __builtin_amdgcn_mfma_f32_16x16x32_bf16(cA[3], b0, im, 0, 0, 0);
      im = __builtin_amdgcn_mfma_f32_16x16x32_bf16(cA[2], b1, im, 0, 0, 0);
      accI[tl] = im;
    }
    if (kn < kend) {
#pragma unroll
      for (int p = 0; p < 4; p++) cA[p] = nA[p];
#pragma unroll
      for (int j = 0; j < 4; j++) rB[j] = nB[j];
    }
  }
  float2* P = Part + (size_t)blockIdx.x * M * N;
#pragma unroll
  for (int tl = 0; tl < 4; tl++) {
    int col = bn + tl * 16 + mn;
    if (col >= N) continue;
#pragma unroll
    for (int r = 0; r < 4; r++) {
      int row = blockIdx.z * 64 + wave * 16 + quad * 4 + r;
      if (row >= M) continue;
      P[(size_t)row * N + col] = make_float2(accR[tl][r], accI[tl][r]);
    }
  }
}

// Plain reduce: C = sum_z Part[z].
__global__ void creduce(const float2* __restrict__ Part, float2* __restrict__ C,
                        int MN, int N, int S, float e0,
                        const float2* __restrict__ E1, float e1,
                        const float2* __restrict__ E2, float e2) {
  int idx = blockIdx.x * 256 + threadIdx.x;
  if (idx >= MN) return;
  float sr = 0.f, si = 0.f;
  for (int z = 0; z < S; z++) {
    float2 p = Part[(size_t)z * MN + idx];
    sr += p.x;
    si += p.y;
  }
  if (e0 != 0.f) {
    int r = idx / N;
    if (idx - r * N == r) sr += e0;
  }
  if (E1) { float2 b = E1[idx]; sr += e1 * b.x; si += e1 * b.y; }
  if (E2) { float2 b = E2[idx]; sr += e2 * b.x; si += e2 * b.y; }
  C[idx] = make_float2(sr, si);
}

// Tiled fused reduce: sum_z Part + epilogue -> optional fp32 C, SA planes,
// transposed ST planes. Gated (inactive slot preserves SA).
template <int WC_, int WSA, int WST>
__global__ void creduce_tiled(const float2* __restrict__ Part, int S, int M, int N,
                              int RP, int CP, float2* __restrict__ C,
                              unsigned short* __restrict__ SAp, size_t psA,
                              unsigned short* __restrict__ STp, size_t psT,
                              float e0, const float2* __restrict__ E1, float e1,
                              const float2* __restrict__ E2, float e2,
                              const int* __restrict__ gate, int slot) {
  if (gate && slot >= *gate - 1) return;
  __shared__ float vr[32][33], vi[32][33];
  int tx = threadIdx.x & 31, ty = threadIdx.x >> 5;
  int r0 = blockIdx.y * 32, c0 = blockIdx.x * 32;
  size_t MN = (size_t)M * N;
  for (int i = ty; i < 32; i += 8) {
    int r = r0 + i, c = c0 + tx;
    float sr = 0.f, si = 0.f;
    if (r < M && c < N) {
      size_t o = (size_t)r * N + c;
      for (int z = 0; z < S; z++) {
        float2 p = Part[z * MN + o];
        sr += p.x;
        si += p.y;
      }
      if (e0 != 0.f && r == c) sr += e0;
      if (E1) { float2 b = E1[o]; sr += e1 * b.x; si += e1 * b.y; }
      if (E2) { float2 b = E2[o]; sr += e2 * b.x; si += e2 * b.y; }
      if (WC_) C[o] = make_float2(sr, si);
    }
    if (WSA) split4(sr, si, SAp, psA, (size_t)r * CP + c);
    if (WST) { vr[i][tx] = sr; vi[i][tx] = si; }
  }
  if (WST) {
    __syncthreads();
    for (int i = ty; i < 32; i += 8) {
      int c = c0 + i, r = r0 + tx;
      split4(vr[tx][i], vi[tx][i], STp, psT, (size_t)c * RP + r);
    }
  }
}

// Fused build_B + split + splitT; runtime scale.
__global__ void build_B_split(const float* __restrict__ pm, int n,
                              const float* __restrict__ scale_p,
                              float2* __restrict__ BM,
                              unsigned short* __restrict__ SAp,
                              unsigned short* __restrict__ STp, size_t ps,
                              int RP, int CP) {
  __shared__ float vr[32][33], vi[32][33];
  float scale = scale_p[0];
  int tx = threadIdx.x & 31, ty = threadIdx.x >> 5;
  int r0 = blockIdx.y * 32, c0 = blockIdx.x * 32;
  for (int i = ty; i < 32; i += 8) {
    int r = r0 + i, c = c0 + tx;
    float sr = 0.f, si = 0.f;
    if (r < n && c < n) {
      float pij = pm[(size_t)r * n + c];
      float pji = pm[(size_t)c * n + r];
      sr = scale * (pij - pji);
      si = scale * (pij + pji);
      BM[(size_t)r * n + c] = make_float2(sr, si);
    }
    split4(sr, si, SAp, ps, (size_t)r * CP + c);
    vr[i][tx] = sr;
    vi[i][tx] = si;
  }
  __syncthreads();
  for (int i = ty; i < 32; i += 8) {
    int c = c0 + i, r = r0 + tx;
    split4(vr[tx][i], vi[tx][i], STp, ps, (size_t)c * RP + r);
  }
}

// ||A||_1 rows + fused finalize: last finishing block computes s and scale.
__global__ void anorm_rows(const float* __restrict__ pm, int n,
                           int* __restrict__ anrm, int* __restrict__ done,
                           int* __restrict__ sdev, float* __restrict__ scale) {
  int i = blockIdx.x;
  __shared__ float red[256];
  float s = 0.f;
  for (int j = threadIdx.x; j < n; j += 256) {
    float pij = pm[(size_t)i * n + j];
    float pji = pm[(size_t)j * n + i];
    float a = pij - pji, b = pij + pji;
    s += sqrtf(a * a + b * b);
  }
  red[threadIdx.x] = s;
  __syncthreads();
  for (int off = 128; off > 0; off >>= 1) {
    if (threadIdx.x < off) red[threadIdx.x] += red[threadIdx.x + off];
    __syncthreads();
  }
  if (threadIdx.x == 0) {
    atomicMax(anrm, __float_as_int(red[0] * 0.025f));
    __threadfence();
    int d = atomicAdd(done, 1);
    if (d == gridDim.x - 1) {
      float a = __int_as_float(atomicMax(anrm, 0));
      int sq = (int)ceilf(log2f(fmaxf(a, 1e-20f) / 1.4f));
      sq = min(max(sq, 1), SQ_SLOTS + 1);
      *sdev = sq;
      *scale = 0.025f * exp2f(-(float)sq);
    }
  }
}

// D3 = c9*I + c10*B + c11*B2 -> SA planes only.
__global__ void combo3_planes(const float2* __restrict__ Bp, const float2* __restrict__ B2p,
                              unsigned short* __restrict__ planes, size_t ps,
                              int M, int N, int padR, int ld,
                              float e0, float e1, float e2) {
  int idx = blockIdx.x * 256 + threadIdx.x;
  if (idx >= padR * ld) return;
  int r = idx / ld, c = idx - r * ld;
  float sr = 0.f, si = 0.f;
  if (r < M && c < N) {
    size_t o = (size_t)r * N + c;
    float2 b = Bp[o], b2 = B2p[o];
    sr = e1 * b.x + e2 * b2.x;
    si = e1 * b.y + e2 * b2.y;
    if (r == c) sr += e0;
  }
  split4(sr, si, planes, ps, idx);
}

// ---- CSR build ----
__global__ void hist_edges(const int* __restrict__ dst, const float* __restrict__ em,
                           int* __restrict__ cnt) {
  int e = blockIdx.x * 256 + threadIdx.x;
  if (e >= E) return;
  float m = em ? em[e] : 1.0f;
  if (m != 0.f) atomicAdd(&cnt[dst[e]], 1);
}

__global__ __launch_bounds__(1024) void scan_offsets(const int* __restrict__ cnt, int n,
                                                     int* __restrict__ off,
                                                     int* __restrict__ cur,
                                                     float* __restrict__ dis) {
  __shared__ int sums[1024];
  int t = threadIdx.x;
  int base = t * 4;
  int v[4];
  int s = 0;
#pragma unroll
  for (int j = 0; j < 4; j++) {
    int i = base + j;
    int ci = (i < n) ? cnt[i] : 0;
    if (i < n) dis[i] = 1.0f / sqrtf((float)ci + 1.0f);
    v[j] = s;
    s += ci;
  }
  sums[t] = s;
  __syncthreads();
  for (int d = 1; d < 1024; d <<= 1) {
    int x = (t >= d) ? sums[t - d] : 0;
    __syncthreads();
    sums[t] += x;
    __syncthreads();
  }
  int pre = (t > 0) ? sums[t - 1] : 0;
#pragma unroll
  for (int j = 0; j < 4; j++) {
    int i = base + j;
    if (i < n) { int o = pre + v[j]; off[i] = o; cur[i] = o; }
  }
  if (t == 1023) off[n] = sums[1023];
}

__global__ void fill_edges(const int* __restrict__ src, const int* __restrict__ dst,
                           const float* __restrict__ em, const float* __restrict__ dis,
                           int* __restrict__ cur, int* __restrict__ esrc,
                           float* __restrict__ ecoef) {
  int e = blockIdx.x * 256 + threadIdx.x;
  if (e >= E) return;
  float m = em ? em[e] : 1.0f;
  if (m == 0.f) return;
  int s = src[e], d = dst[e];
  int pos = atomicAdd(&cur[d], 1);
  esrc[pos] = s;
  ecoef[pos] = dis[s] * dis[d];
}

// Fused GCN aggregate + self-loop + bias (+relu) (+pool score).
template <int ACT, int SCORE>
__global__ void gcn_gather(const int* __restrict__ off, const int* __restrict__ esrc,
                           const float* __restrict__ ecoef, const float* __restrict__ Hm,
                           const float* __restrict__ dis, const float* __restrict__ bias,
                           float* __restrict__ out, int F, int M,
                           const float* __restrict__ w, float* __restrict__ score,
                           float* __restrict__ normout) {
  __shared__ float red[256];
  int i = blockIdx.x;
  if (SCORE && i == M) {
    float s = 0.f;
    for (int k = threadIdx.x; k < F; k += 256) s += w[k] * w[k];
    red[threadIdx.x] = s;
    __syncthreads();
    for (int o = 128; o > 0; o >>= 1) {
      if (threadIdx.x < o) red[threadIdx.x] += red[threadIdx.x + o];
      __syncthreads();
    }
    if (threadIdx.x == 0) normout[0] = sqrtf(red[0]);
    return;
  }
  int e0 = off[i], e1 = off[i + 1];
  float d2 = dis[i] * dis[i];
  float sdot = 0.f;
  for (int f = threadIdx.x; f < F; f += blockDim.x) {
    float acc = d2 * Hm[(size_t)i * F + f] + bias[f];
    for (int e = e0; e < e1; e++)
      acc += ecoef[e] * Hm[(size_t)esrc[e] * F + f];
    if (ACT == 1) acc = fmaxf(acc, 0.f);
    out[(size_t)i * F + f] = acc;
    if (SCORE) sdot += acc * w[f];
  }
  if (SCORE) {
    red[threadIdx.x] = sdot;
    __syncthreads();
    for (int o = 128; o > 0; o >>= 1) {
      if (threadIdx.x < o) red[threadIdx.x] += red[threadIdx.x + o];
      __syncthreads();
    }
    if (threadIdx.x == 0) score[i] = red[0];
  }
}

__global__ void enc1_fused(const int* __restrict__ off, const float* __restrict__ ecoef,
                           const float* __restrict__ dis, const float* __restrict__ w,
                           const float* __restrict__ b, float* __restrict__ xg1) {
  int i = blockIdx.x;
  int lane = threadIdx.x;
  float s = 0.f;
  for (int e = off[i] + lane; e < off[i + 1]; e += 64) s += ecoef[e];
#pragma unroll
  for (int d = 32; d > 0; d >>= 1) s += __shfl_xor(s, d, 64);
  float sc = s + dis[i] * dis[i];
  xg1[(size_t)i * UHD + lane] = fmaxf(sc * w[lane] + b[lane], 0.f);
}

__global__ void agg_gather_split(const int* __restrict__ off, const int* __restrict__ esrc,
                                 const float2* __restrict__ evo,
                                 unsigned short* __restrict__ planes, size_t ps,
                                 int F, int M) {
  int i = blockIdx.x;
  if (i >= M) {
    for (int f = threadIdx.x; f < F; f += blockDim.x)
      split4(0.f, 0.f, planes, ps, (size_t)i * F + f);
    return;
  }
  int e0 = off[i], e1 = off[i + 1];
  for (int f = threadIdx.x; f < F; f += blockDim.x) {
    float sr = 0.f, si = 0.f;
    for (int e = e0; e < e1; e++) {
      float2 v = evo[(size_t)esrc[e] * F + f];
      sr += v.x;
      si += v.y;
    }
    split4(sr, si, planes, ps, (size_t)i * F + f);
  }
}

__global__ __launch_bounds__(1024) void bitonic_topk(const float* __restrict__ score,
                                                     int n, int* __restrict__ perm, int k,
                                                     int* __restrict__ map,
                                                     int* __restrict__ cntz, int ncnt) {
  __shared__ unsigned long long keys[4096];
  int t = threadIdx.x;
  for (int i = t; i < 4096; i += 1024) {
    unsigned long long kk = 0ull;
    if (i < n) {
      float f = score[i];
      unsigned u = __float_as_uint(f);
      u = (f >= 0.0f) ? (u | 0x80000000u) : ~u;
      kk = ((unsigned long long)u << 32) | (unsigned)(~(unsigned)i);
    }
    keys[i] = kk;
  }
  __syncthreads();
  for (int size = 2; size <= 4096; size <<= 1) {
    for (int stride = size >> 1; stride > 0; stride >>= 1) {
      for (int i = t; i < 2048; i += 1024) {
        int pos = ((i & ~(stride - 1)) << 1) | (i & (stride - 1));
        int partner = pos + stride;
        bool desc = (pos & size) == 0;
        unsigned long long a = keys[pos], b = keys[partner];
        if ((a < b) == desc) { keys[pos] = b; keys[partner] = a; }
      }
      __syncthreads();
    }
  }
  for (int i = t; i < 4096; i += 1024) {
    int idx = (int)(~(unsigned)(keys[i] & 0xFFFFFFFFull));
    if (idx >= 0) map[idx] = (i < k) ? i : -1;
    if (i < k) perm[i] = idx;
  }
  for (int i = t; i < ncnt; i += 1024) cntz[i] = 0;
}

// Fused pool_gather + remap + histogram.
__global__ void pool_remap(const float* __restrict__ X, const int* __restrict__ perm,
                           const float* __restrict__ dot, const float* __restrict__ normbuf,
                           float* __restrict__ Xn, int F, int k,
                           const int* __restrict__ srcIn, const int* __restrict__ dstIn,
                           const float* __restrict__ emIn, const int* __restrict__ map,
                           int* __restrict__ srcOut, int* __restrict__ dstOut,
                           float* __restrict__ emOut, int* __restrict__ cnt) {
  int b = blockIdx.x;
  if (b < k) {
    int p = perm[b];
    float sc = tanhf(dot[p] / normbuf[0]);
    for (int f = threadIdx.x; f < F; f += blockDim.x)
      Xn[(size_t)b * F + f] = X[(size_t)p * F + f] * sc;
  } else {
    int e = (b - k) * 256 + threadIdx.x;
    if (e >= E) return;
    int ns = map[srcIn[e]], nd = map[dstIn[e]];
    float m = emIn ? emIn[e] : 1.0f;
    if (ns < 0 || nd < 0) m = 0.f;
    srcOut[e] = ns < 0 ? 0 : ns;
    dstOut[e] = nd < 0 ? 0 : nd;
    emOut[e] = m;
    if (m != 0.f) atomicAdd(&cnt[nd], 1);
  }
}

__global__ void col_mean(const float* __restrict__ X, float* __restrict__ out,
                         int rows, int cols) {
  int c = blockIdx.x;
  __shared__ float red[256];
  float s = 0.f;
  for (int r = threadIdx.x; r < rows; r += 256) s += X[(size_t)r * cols + c];
  red[threadIdx.x] = s;
  __syncthreads();
  for (int off = 128; off > 0; off >>= 1) {
    if (threadIdx.x < off) red[threadIdx.x] += red[threadIdx.x + off];
    __syncthreads();
  }
  if (threadIdx.x == 0) out[c] = red[0] / (float)rows;
}

// magph + col_means reading split-K PART directly (folds AGG1 reduce).
__global__ void magph_mean_part(const float2* __restrict__ Part, int S,
                                const float* __restrict__ xr,
                                const float* __restrict__ xi,
                                float* __restrict__ gm, float* __restrict__ gp,
                                int rows, int cols) {
  int c = blockIdx.x;
  __shared__ float rm[256], rp[256];
  size_t MN = (size_t)rows * cols;
  float sm = 0.f, sp = 0.f;
  for (int r = threadIdx.x; r < rows; r += 256) {
    size_t o = (size_t)r * cols + c;
    float re = xr[o], im = xi[o];
    for (int z = 0; z < S; z++) {
      float2 p = Part[z * MN + o];
      re += p.x;
      im += p.y;
    }
    sm += sqrtf(re * re + im * im);
    sp += atan2f(im, re);
  }
  rm[threadIdx.x] = sm;
  rp[threadIdx.x] = sp;
  __syncthreads();
  for (int off = 128; off > 0; off >>= 1) {
    if (threadIdx.x < off) {
      rm[threadIdx.x] += rm[threadIdx.x + off];
      rp[threadIdx.x] += rp[threadIdx.x + off];
    }
    __syncthreads();
  }
  if (threadIdx.x == 0) {
    gm[c] = rm[0] / (float)rows;
    gp[c] = rp[0] / (float)rows;
  }
}

// Fused p1+p2 MLP (two tiny vec-mats, one block).
__global__ void vecmat2(const float* __restrict__ v,
                        const float* __restrict__ W1, const float* __restrict__ b1,
                        const float* __restrict__ W2, const float* __restrict__ b2,
                        float* __restrict__ T2out) {
  __shared__ float vs[64], t1[64];
  int t = threadIdx.x;
  if (t < 64) vs[t] = v[t];
  __syncthreads();
  if (t < 64) {
    float acc = b1[t];
    for (int k = 0; k < 64; k++) acc += vs[k] * W1[(size_t)k * 64 + t];
    t1[t] = fmaxf(acc, 0.f);
  }
  __syncthreads();
  if (t < 32) {
    float acc = b2[t];
    for (int k = 0; k < 64; k++) acc += t1[k] * W2[(size_t)k * 32 + t];
    T2out[t] = fmaxf(acc, 0.f);
  }
}

// vec @ mat tanh; block 0 thread 0 inits ANRM and DONE.
__global__ void vecmat_tanh_wide(const float* __restrict__ v, const float* __restrict__ W,
                                 const float* __restrict__ b, float* __restrict__ out,
                                 int Kdim, int Ndim, int* __restrict__ anrm_init,
                                 int* __restrict__ done_init) {
  __shared__ float vs[64];
  if (threadIdx.x < Kdim) vs[threadIdx.x] = v[threadIdx.x];
  if (blockIdx.x == 0 && threadIdx.x == 0) { *anrm_init = 0; *done_init = 0; }
  __syncthreads();
  int j = blockIdx.x * 256 + threadIdx.x;
  if (j >= Ndim) return;
  float acc = b[j];
  for (int k = 0; k < Kdim; k++) acc += vs[k] * W[(size_t)k * Ndim + j];
  out[j] = tanhf(acc);
}

__global__ __launch_bounds__(256) void heads_fused(
    const float* __restrict__ GM, const float* __restrict__ GP,
    const float* __restrict__ mc1_w, const float* __restrict__ mc1_b,
    const float* __restrict__ mc2_w, const float* __restrict__ mc2_b,
    const float* __restrict__ pc1_w, const float* __restrict__ pc1_b,
    const float* __restrict__ pc2_w, const float* __restrict__ pc2_b,
    float* __restrict__ out) {
  __shared__ float g[256], h[128], acc[NC];
  int t = threadIdx.x;
  if (t < NC) acc[t] = 0.f;
  for (int pass = 0; pass < 2; pass++) {
    const float* gv = pass ? GP : GM;
    const float* w1 = pass ? pc1_w : mc1_w;
    const float* b1 = pass ? pc1_b : mc1_b;
    const float* w2 = pass ? pc2_w : mc2_w;
    const float* b2 = pass ? pc2_b : mc2_b;
    g[t] = gv[t];
    __syncthreads();
    if (t < 128) {
      float s = b1[t];
      for (int k = 0; k < 256; k++) s += g[k] * w1[(size_t)k * 128 + t];
      h[t] = fmaxf(s, 0.f);
    }
    __syncthreads();
    if (t < NC) {
      float s = b2[t];
      for (int k = 0; k < 128; k++) s += h[k] * w2[(size_t)k * NC + t];
      acc[t] += s;
    }
    __syncthreads();
  }
  if (t < NC) out[t] = acc[t];
}

// ---------------- host helpers ----------------
static inline int sk_chunk32(int K, int S) { return (((K + S - 1) / S) + 31) & ~31; }

// ---------------- host ----------------
extern "C" void kernel_launch(void* const* d_in, const int* in_sizes, int n_in,
                              void* d_out, int out_size, void* d_ws, size_t ws_size,
                              hipStream_t stream) {
  if (ws_size < WS_TOTAL) return;

  const float* x       = (const float*)d_in[0];
  const int*   ei      = (const int*)d_in[1];
  const float* gcn1_w  = (const float*)d_in[2];
  const float* gcn1_b  = (const float*)d_in[3];
  const float* pool1_w = (const float*)d_in[4];
  const float* gcn2_w  = (const float*)d_in[5];
  const float* gcn2_b  = (const float*)d_in[6];
  const float* pool2_w = (const float*)d_in[7];
  const float* inr_w   = (const float*)d_in[8];
  const float* inr_b   = (const float*)d_in[9];
  const float* ini_w   = (const float*)d_in[10];
  const float* ini_b   = (const float*)d_in[11];
  const float* enc1_w  = (const float*)d_in[12];
  const float* enc1_b  = (const float*)d_in[13];
  const float* enc2_w  = (const float*)d_in[14];
  const float* enc2_b  = (const float*)d_in[15];
  const float* p1_w    = (const float*)d_in[16];
  const float* p1_b    = (const float*)d_in[17];
  const float* p2_w    = (const float*)d_in[18];
  const float* p2_b    = (const float*)d_in[19];
  const float* p3_w    = (const float*)d_in[20];
  const float* p3_b    = (const float*)d_in[21];
  const float* rt_w    = (const float*)d_in[22];
  const float* rt_b    = (const float*)d_in[23];
  const float* it_w    = (const float*)d_in[24];
  const float* it_b    = (const float*)d_in[25];
  const float* msg_wr  = (const float*)d_in[26];
  const float* msg_wi  = (const float*)d_in[27];
  const float* mc1_w   = (const float*)d_in[28];
  const float* mc1_b   = (const float*)d_in[29];
  const float* mc2_w   = (const float*)d_in[30];
  const float* mc2_b   = (const float*)d_in[31];
  const float* pc1_w   = (const float*)d_in[32];
  const float* pc1_b   = (const float*)d_in[33];
  const float* pc2_w   = (const float*)d_in[34];
  const float* pc2_b   = (const float*)d_in[35];

  char* ws = (char*)d_ws;
  float*  H1    = (float*)(ws + O_H1);
  float*  OUT1  = (float*)(ws + O_OUT1);
  int*    CNT1  = (int*)(ws + O_DEG1);
  float*  DIS1  = (float*)(ws + O_DIS1);
  float*  SC1   = (float*)(ws + O_SC1);
  int*    PERM1 = (int*)(ws + O_PERM1);
  int*    MAP1  = (int*)(ws + O_MAP1);
  float*  H1P   = (float*)(ws + O_H1P);
  int*    SRC2  = (int*)(ws + O_SRC2);
  int*    DST2  = (int*)(ws + O_DST2);
  float*  EM2   = (float*)(ws + O_EM2);
  float*  H2    = (float*)(ws + O_H2);
  float*  OUT2  = (float*)(ws + O_OUT2);
  int*    CNT2  = (int*)(ws + O_DEG2);
  float*  DIS2  = (float*)(ws + O_DIS2);
  float*  SC2   = (float*)(ws + O_SC2);
  int*    PERM2 = (int*)(ws + O_PERM2);
  int*    MAP2  = (int*)(ws + O_MAP2);
  float*  H2P   = (float*)(ws + O_H2P);
  int*    SRC3  = (int*)(ws + O_SRC3);
  int*    DST3  = (int*)(ws + O_DST3);
  float*  EM3   = (float*)(ws + O_EM3);
  float*  XRb   = (float*)(ws + O_XR);
  float*  XIb   = (float*)(ws + O_XI);
  int*    CNT3  = (int*)(ws + O_DEG3);
  float*  DIS3  = (float*)(ws + O_DIS3);
  float*  XG1   = (float*)(ws + O_XG1);
  float*  XG2H  = (float*)(ws + O_XG2H);
  float*  XG2   = (float*)(ws + O_XG2);
  float*  EMB   = (float*)(ws + O_EMB);
  float*  T2    = (float*)(ws + O_T2);
  float*  NORM  = (float*)(ws + O_NORM);
  int*    ANRM  = (int*)(NORM + 2);
  int*    SDEV  = (int*)(NORM + 3);
  float*  SCALE = NORM + 4;
  int*    DONE  = (int*)(NORM + 5);
  float*  PMV   = (float*)(ws + O_PM);
  float2* BM    = (float2*)(ws + O_BM);
  float2* XC    = (float2*)(ws + O_XC);
  float2* EVO   = (float2*)(ws + O_EVO);
  float*  GM    = (float*)(ws + O_GM);
  float*  GP    = (float*)(ws + O_GP);
  unsigned short* SA = (unsigned short*)(ws + O_SA);
  unsigned short* ST = (unsigned short*)(ws + O_ST);
  float2* PART  = (float2*)(ws + O_PARTX);
  float2* B2v   = (float2*)(ws + O_B2);
  int*    COFF  = (int*)(ws + O_CSR_OFF);
  int*    CCUR  = (int*)(ws + O_CSR_CUR);
  int*    CSRC  = (int*)(ws + O_CSR_SRC);
  float*  CCOEF = (float*)(ws + O_CSR_CF);

  const int* SRC1 = ei;
  const int* DST1 = ei + E;
  const int eg = E / 256;

  // ---------- Stage A: gcn1 (CSR gather, fused pool1 score) ----------
  rmm64<0><<<dim3(HD / 64, N0 / 64), 256, 0, stream>>>(x, gcn1_w, nullptr, H1, N0, HD, DIN, 1, 0);
  hipMemsetAsync(CNT1, 0, F4(N0), stream);
  hist_edges<<<eg, 256, 0, stream>>>(DST1, nullptr, CNT1);
  scan_offsets<<<1, 1024, 0, stream>>>(CNT1, N0, COFF, CCUR, DIS1);
  fill_edges<<<eg, 256, 0, stream>>>(SRC1, DST1, nullptr, DIS1, CCUR, CSRC, CCOEF);
  gcn_gather<1, 1><<<N0 + 1, 256, 0, stream>>>(COFF, CSRC, CCOEF, H1, DIS1, gcn1_b,
                                               OUT1, HD, N0, pool1_w, SC1, NORM);

  // ---------- pool1 ----------
  bitonic_topk<<<1, 1024, 0, stream>>>(SC1, N0, PERM1, K1, MAP1, CNT2, K1);
  pool_remap<<<K1 + eg, 256, 0, stream>>>(OUT1, PERM1, SC1, NORM, H1P, HD, K1,
                                          SRC1, DST1, nullptr, MAP1, SRC2, DST2, EM2, CNT2);

  // ---------- Stage C: gcn2 (CSR gather, fused pool2 score) ----------
  rmm64<0><<<dim3(HD / 64, (K1 + 63) / 64), 256, 0, stream>>>(H1P, gcn2_w, nullptr, H2, K1, HD, HD, 1, 0);
  scan_offsets<<<1, 1024, 0, stream>>>(CNT2, K1, COFF, CCUR, DIS2);
  fill_edges<<<eg, 256, 0, stream>>>(SRC2, DST2, EM2, DIS2, CCUR, CSRC, CCOEF);
  gcn_gather<1, 1><<<K1 + 1, 256, 0, stream>>>(COFF, CSRC, CCOEF, H2, DIS2, gcn2_b,
                                               OUT2, HD, K1, pool2_w, SC2, NORM + 1);

  // ---------- pool2 ----------
  bitonic_topk<<<1, 1024, 0, stream>>>(SC2, K1, PERM2, K2, MAP2, CNT3, K2);
  pool_remap<<<K2 + eg, 256, 0, stream>>>(OUT2, PERM2, SC2, NORM + 1, H2P, HD, K2,
                                          SRC2, DST2, EM2, MAP2, SRC3, DST3, EM3, CNT3);

  // ---------- xr / xi (dual GEMM) ----------
  rmm64_dual<0><<<dim3(HD / 64, (K2 + 63) / 64, 2), 256, 0, stream>>>(
      H2P, H2P, inr_w, ini_w, inr_b, ini_b, XRb, XIb, K2, HD, HD, 1);

  // ---------- CSR3 (persists through expm) ----------
  scan_offsets<<<1, 1024, 0, stream>>>(CNT3, K2, COFF, CCUR, DIS3);
  fill_edges<<<eg, 256, 0, stream>>>(SRC3, DST3, EM3, DIS3, CCUR, CSRC, CCOEF);

  // ---------- encoder GCNs on pooled graph ----------
  enc1_fused<<<K2, 64, 0, stream>>>(COFF, CCOEF, DIS3, enc1_w, enc1_b, XG1);
  rmm64<0><<<dim3(UHD / 64, (K2 + 63) / 64), 256, 0, stream>>>(XG1, enc2_w, nullptr, XG2H, K2, UHD, UHD, 1, 0);
  gcn_gather<0, 0><<<K2, 64, 0, stream>>>(COFF, CSRC, CCOEF, XG2H, DIS3, enc2_b,
                                          XG2, UHD, K2, nullptr, nullptr, nullptr);
  col_mean<<<UHD, 256, 0, stream>>>(XG2, EMB, K2, UHD);

  // ---------- parameter MLP -> pm ; runtime squaring count s ----------
  vecmat2<<<1, 64, 0, stream>>>(EMB, p1_w, p1_b, p2_w, p2_b, T2);
  vecmat_tanh_wide<<<(PMN + 255) / 256, 256, 0, stream>>>(T2, p3_w, p3_b, PMV, UHD / 2, PMN, ANRM, DONE);
  anorm_rows<<<K2, 256, 0, stream>>>(PMV, K2, ANRM, DONE, SDEV, SCALE);

  // ---------- expm: PS deg-11 + gated squarings (last folded into EVO) ----
  const int sgrid = (PLD * PLD + 255) / 256;
  const dim3 tg22(PLD / 32, PLD / 32);
  const int chF = sk_chunk32(PLD, CSPLIT);   // 96
  const dim3 gBig(CSPLIT, 11, 11);
  const float c3 = 1.f / 6.f, c4 = 1.f / 24.f, c5 = 1.f / 120.f;
  const float c6 = 1.f / 720.f, c7 = 1.f / 5040.f, c8 = 1.f / 40320.f;
  const float c9 = 1.f / 362880.f, c10 = 1.f / 3628800.f, c11 = 1.f / 39916800.f;

  build_B_split<<<tg22, 256, 0, stream>>>(PMV, K2, SCALE, BM, SA, ST, PPS, PLD, PLD);
  cmm_bf16_sk<<<gBig, 256, 0, stream>>>(SA, PPS, PLD, ST, PPS, PLD, PART, K2, K2, PLD, chF, nullptr, 0);
  creduce_tiled<1, 1, 0><<<tg22, 256, 0, stream>>>(PART, CSPLIT, K2, K2, PLD, PLD,
      B2v, SA, PPS, nullptr, 0, 0.f, nullptr, 0.f, nullptr, 0.f, nullptr, 0);
  cmm_bf16_sk<<<gBig, 256, 0, stream>>>(SA, PPS, PLD, ST, PPS, PLD, PART, K2, K2, PLD, chF, nullptr, 0);
  creduce_tiled<0, 0, 1><<<tg22, 256, 0, stream>>>(PART, CSPLIT, K2, K2, PLD, PLD,
      nullptr, nullptr, 0, ST, PPS, 0.f, nullptr, 0.f, nullptr, 0.f, nullptr, 0);
  combo3_planes<<<sgrid, 256, 0, stream>>>(BM, B2v, SA, PPS, K2, K2, PLD, PLD, c9, c10, c11);
  cmm_bf16_sk<<<gBig, 256, 0, stream>>>(SA, PPS, PLD, ST, PPS, PLD, PART, K2, K2, PLD, chF, nullptr, 0);
  creduce_tiled<0, 1, 0><<<tg22, 256, 0, stream>>>(PART, CSPLIT, K2, K2, PLD, PLD,
      nullptr, SA, PPS, nullptr, 0, c6, BM, c7, B2v, c8, nullptr, 0);
  cmm_bf16_sk<<<gBig, 256, 0, stream>>>(SA, PPS, PLD, ST, PPS, PLD, PART, K2, K2, PLD, chF, nullptr, 0);
  creduce_tiled<0, 1, 0><<<tg22, 256, 0, stream>>>(PART, CSPLIT, K2, K2, PLD, PLD,
      nullptr, SA, PPS, nullptr, 0, c3, BM, c4, B2v, c5, nullptr, 0);
  cmm_bf16_sk<<<gBig, 256, 0, stream>>>(SA, PPS, PLD, ST, PPS, PLD, PART, K2, K2, PLD, chF, nullptr, 0);
  creduce_tiled<0, 1, 1><<<tg22, 256, 0, stream>>>(PART, CSPLIT, K2, K2, PLD, PLD,
      nullptr, SA, PPS, ST, PPS, 1.f, BM, 1.f, B2v, 0.5f, nullptr, 0);
  for (int t = 0; t < SQ_SLOTS; ++t) {
    cmm_bf16_sk<<<gBig, 256, 0, stream>>>(SA, PPS, PLD, ST, PPS, PLD, PART, K2, K2, PLD, chF, SDEV, t);
    creduce_tiled<0, 1, 1><<<tg22, 256, 0, stream>>>(PART, CSPLIT, K2, K2, PLD, PLD,
        nullptr, SA, PPS, ST, PPS, 0.f, nullptr, 0.f, nullptr, 0.f, SDEV, t);
  }
  // SA holds S = U^(1/2) planes.

  // ---------- quantum message passing: EVO = S@(S@XC) ----------
  rmm64_dual<1><<<dim3(HD / 64, (K2 + 63) / 64, 2), 256, 0, stream>>>(
      XRb, XIb, rt_w, it_w, rt_b, it_b, (float*)XC, (float*)XC + 1, K2, HD, HD, 2);
  {
    const int mn = K2 * HD;
    const int rg = (mn + 255) / 256;
    const dim3 gSkin(CSPLIT, HD / 64, 11);
    const size_t psX = (size_t)HD * PLD;
    split_planesT<<<dim3((PLD + 31) / 32, (HD + 31) / 32), 256, 0, stream>>>(
        XC, K2, HD, ST, HD, PLD, psX);
    cmm_bf16_sk<<<gSkin, 256, 0, stream>>>(SA, PPS, PLD, ST, psX, PLD, PART, K2, HD, PLD, chF, nullptr, 0);
    creduce_tiled<0, 0, 1><<<dim3(HD / 32, PLD / 32), 256, 0, stream>>>(
        PART, CSPLIT, K2, HD, PLD, HD, nullptr, nullptr, 0, ST, psX,
        0.f, nullptr, 0.f, nullptr, 0.f, nullptr, 0);
    cmm_bf16_sk<<<gSkin, 256, 0, stream>>>(SA, PPS, PLD, ST, psX, PLD, PART, K2, HD, PLD, chF, nullptr, 0);
    creduce<<<rg, 256, 0, stream>>>(PART, EVO, mn, HD, CSPLIT, 0.f, nullptr, 0.f, nullptr, 0.f);
    const size_t psG = (size_t)PLD * HD;
    agg_gather_split<<<PLD, 256, 0, stream>>>(COFF, CSRC, EVO, SA, psG, HD, K2);
    split_planesT2<<<dim3((HD + 31) / 32, (HD + 31) / 32), 256, 0, stream>>>(
        msg_wr, msg_wi, HD, HD, ST, HD, HD, (size_t)HD * HD);
    cmm_bf16_sk<<<gSkin, 256, 0, stream>>>(SA, psG, HD, ST, (size_t)HD * HD, HD, PART,
                                           K2, HD, HD, sk_chunk32(HD, CSPLIT), nullptr, 0);
    magph_mean_part<<<HD, 256, 0, stream>>>(PART, CSPLIT, XRb, XIb, GM, GP, K2, HD);
  }

  // ---------- fused classifier heads ----------
  heads_fused<<<1, 256, 0, stream>>>(GM, GP, mc1_w, mc1_b, mc2_w, mc2_b,
                                     pc1_w, pc1_b, pc2_w, pc2_b, (float*)d_out);
}